// Round 3
// baseline (2957.331 us; speedup 1.0000x reference)
//
#include <hip/hip_runtime.h>
#include <hip/hip_bf16.h>

#define FFT_PI 3.14159265358979323846f

typedef __hip_bfloat16 bf16;

__device__ inline float bf2f(unsigned short u) {
    union { unsigned int i; float f; } v; v.i = ((unsigned int)u) << 16; return v.f;
}
__device__ inline unsigned short f2bf(float f) {
    bf16 h = __float2bfloat16(f);
    union { bf16 h; unsigned short u; } v; v.h = h; return v.u;
}
__device__ inline float2 c_load(const ushort2* p) {
    ushort2 u = *p;
    return make_float2(bf2f(u.x), bf2f(u.y));
}
__device__ inline void c_store(ushort2* p, float2 z) {
    ushort2 u; u.x = f2bf(z.x); u.y = f2bf(z.y); *p = u;
}

// ---------------------------------------------------------------------------
// Tiled fp32 GEMM: C[M,N] = A[M,K] @ B[K,N] (+bias) (+accumulate)
// a_type: 0 = f32 contiguous, 2 = bf16 interleaved-complex real part
//         (lda in complex elems)
// out_type: 0 = f32 (ldc f32 elems), 2 = bf16-complex with zero imag
//         (ldc complex elems)
// B is f32 [K,N] row-major, bias f32.
// ---------------------------------------------------------------------------
__global__ __launch_bounds__(256) void gemm_kernel(
    const void* __restrict__ Av, int a_type, int lda,
    const float* __restrict__ Bw, int ldb,
    const float* __restrict__ bias,
    void* __restrict__ Cout, int out_type, int ldc,
    int K, int accumulate)
{
    __shared__ float As[16][65];
    __shared__ float Bs[16][65];
    const int tid = threadIdx.x;
    const int m0 = blockIdx.y * 64;
    const int n0 = blockIdx.x * 64;
    const int ty = tid >> 4, tx = tid & 15;
    float acc[4][4] = {{0.f}};

    const int ar = tid >> 2;          // 0..63 row in A tile
    const int ak = (tid & 3) << 2;    // 0,4,8,12
    const int bk = tid >> 4;          // 0..15
    const int bn = (tid & 15) << 2;   // 0..60

    for (int k0 = 0; k0 < K; k0 += 16) {
        float v0, v1, v2, v3;
        if (a_type == 0) {
            const float* p = (const float*)Av + (long)(m0 + ar) * lda + (k0 + ak);
            v0 = p[0]; v1 = p[1]; v2 = p[2]; v3 = p[3];
        } else {
            const unsigned short* p = (const unsigned short*)Av
                + 2 * ((long)(m0 + ar) * lda + (k0 + ak));
            v0 = bf2f(p[0]); v1 = bf2f(p[2]); v2 = bf2f(p[4]); v3 = bf2f(p[6]);
        }
        As[ak + 0][ar] = v0; As[ak + 1][ar] = v1;
        As[ak + 2][ar] = v2; As[ak + 3][ar] = v3;
        {
            const float* p = Bw + (long)(k0 + bk) * ldb + (n0 + bn);
            Bs[bk][bn + 0] = p[0];
            Bs[bk][bn + 1] = p[1];
            Bs[bk][bn + 2] = p[2];
            Bs[bk][bn + 3] = p[3];
        }
        __syncthreads();
#pragma unroll
        for (int kk = 0; kk < 16; kk++) {
            float a[4], b[4];
#pragma unroll
            for (int i = 0; i < 4; i++) a[i] = As[kk][ty * 4 + i];
#pragma unroll
            for (int j = 0; j < 4; j++) b[j] = Bs[kk][tx * 4 + j];
#pragma unroll
            for (int i = 0; i < 4; i++)
#pragma unroll
                for (int j = 0; j < 4; j++)
                    acc[i][j] += a[i] * b[j];
        }
        __syncthreads();
    }
#pragma unroll
    for (int i = 0; i < 4; i++) {
        const long gm = m0 + ty * 4 + i;
#pragma unroll
        for (int j = 0; j < 4; j++) {
            const int gn = n0 + tx * 4 + j;
            float v = acc[i][j];
            if (bias) v += bias[gn];
            if (out_type == 0) {
                float* c = (float*)Cout + gm * ldc + gn;
                if (accumulate) v += *c;
                *c = v;
            } else {
                ushort2* c = (ushort2*)Cout + gm * ldc + gn;
                ushort2 u; u.x = f2bf(v); u.y = 0;
                *c = u;
            }
        }
    }
}

// ---------------------------------------------------------------------------
// 512-point radix-2 Stockham FFT in LDS. 256 threads, 1 butterfly each/stage.
// sign = -1 forward, +1 inverse (no scaling).
// ---------------------------------------------------------------------------
__device__ inline float2* fft512_lds(float2* bx, float2* by, int t, float sign)
{
    int ls = 0;
    for (int n = 512; n >= 2; n >>= 1) {
        const int m = n >> 1;
        const int s = 1 << ls;
        const int p = t >> ls;
        const int q = t & (s - 1);
        float2 a = bx[q + s * p];
        float2 b = bx[q + s * (p + m)];
        float ang = sign * (2.0f * FFT_PI) * (float)p / (float)n;
        float sw, cw;
        __sincosf(ang, &sw, &cw);
        float2 sum = make_float2(a.x + b.x, a.y + b.y);
        float2 dif = make_float2(a.x - b.x, a.y - b.y);
        float2 tw  = make_float2(dif.x * cw - dif.y * sw, dif.x * sw + dif.y * cw);
        by[q + s * (2 * p)]     = sum;
        by[q + s * (2 * p + 1)] = tw;
        __syncthreads();
        float2* tmp = bx; bx = by; by = tmp;
        ls++;
    }
    return bx;
}

// in-place row FFT on bf16-complex buffer (line = blockIdx.x)
__global__ __launch_bounds__(256) void fft_rows_c2c_bf16(
    ushort2* __restrict__ data, float sign)
{
    __shared__ float2 b0[512], b1[512];
    ushort2* s = data + (long)blockIdx.x * 512;
    const int t = threadIdx.x;
    b0[t]       = c_load(s + t);
    b0[t + 256] = c_load(s + t + 256);
    __syncthreads();
    float2* r = fft512_lds(b0, b1, t, sign);
    c_store(s + t,       r[t]);
    c_store(s + t + 256, r[t + 256]);
}

// real f32 source -> bf16-complex dst, row FFT
__global__ __launch_bounds__(256) void fft_rows_r2c_f32(
    const float* __restrict__ src, ushort2* __restrict__ dst, float sign)
{
    __shared__ float2 b0[512], b1[512];
    const long line = blockIdx.x;
    const int t = threadIdx.x;
    const float* s = src + line * 512;
    b0[t]       = make_float2(s[t], 0.f);
    b0[t + 256] = make_float2(s[t + 256], 0.f);
    __syncthreads();
    float2* r = fft512_lds(b0, b1, t, sign);
    ushort2* d = dst + line * 512;
    c_store(d + t,       r[t]);
    c_store(d + t + 256, r[t + 256]);
}

// in-place column FFT (block = b*512 + d, element stride 512)
__global__ __launch_bounds__(256) void fft_cols_c2c_bf16(
    ushort2* __restrict__ data, float sign)
{
    __shared__ float2 b0[512], b1[512];
    const int b = blockIdx.x >> 9;
    const int d = blockIdx.x & 511;
    ushort2* base = data + (long)b * 262144 + d;
    const int t = threadIdx.x;
    b0[t]       = c_load(base + (long)t * 512);
    b0[t + 256] = c_load(base + (long)(t + 256) * 512);
    __syncthreads();
    float2* r = fft512_lds(b0, b1, t, sign);
    c_store(base + (long)t * 512,         r[t]);
    c_store(base + (long)(t + 256) * 512, r[t + 256]);
}

// gated row inverse FFT: z = sigmoid(g2)*tep, row-ifft (scale 1/512), in place
__global__ __launch_bounds__(256) void fft_rows_gated(
    const float* __restrict__ g2, ushort2* __restrict__ tep)
{
    __shared__ float2 b0[512], b1[512];
    const long line = blockIdx.x;
    const int t = threadIdx.x;
    ushort2* s = tep + line * 512;
    const float* g = g2 + line * 512;
#pragma unroll
    for (int o = 0; o < 2; o++) {
        const int i = t + o * 256;
        float sg = 1.0f / (1.0f + __expf(-g[i]));
        float2 z = c_load(s + i);
        b0[i] = make_float2(sg * z.x, sg * z.y);
    }
    __syncthreads();
    float2* r = fft512_lds(b0, b1, t, +1.f);
    const float sc = 1.0f / 512.0f;
    c_store(s + t,       make_float2(r[t].x * sc, r[t].y * sc));
    c_store(s + t + 256, make_float2(r[t + 256].x * sc, r[t + 256].y * sc));
}

// column inverse FFT + abs -> f32 real output (scale 1/512)
__global__ __launch_bounds__(256) void fft_cols_abs(
    const ushort2* __restrict__ src, float* __restrict__ dst)
{
    __shared__ float2 b0[512], b1[512];
    const int b = blockIdx.x >> 9;
    const int d = blockIdx.x & 511;
    const ushort2* base = src + (long)b * 262144 + d;
    const int t = threadIdx.x;
    b0[t]       = c_load(base + (long)t * 512);
    b0[t + 256] = c_load(base + (long)(t + 256) * 512);
    __syncthreads();
    float2* r = fft512_lds(b0, b1, t, +1.f);
    const float sc = 1.0f / 512.0f;
    float* db = dst + (long)b * 262144 + d;
    float2 z = r[t];
    db[(long)t * 512] = sqrtf(z.x * z.x + z.y * z.y) * sc;
    float2 z2 = r[t + 256];
    db[(long)(t + 256) * 512] = sqrtf(z2.x * z2.x + z2.y * z2.y) * sc;
}

// ---------------------------------------------------------------------------
// Per-(b,c) attention. Writes out_f (f32, 512 floats = 2048 B) OVER the
// block's own qf chunk (512 cplx-bf16 = 2048 B) — same-block data only.
// ---------------------------------------------------------------------------
__global__ __launch_bounds__(64) void attn_kernel(
    const ushort2* __restrict__ qf, const ushort2* __restrict__ kf,
    const ushort2* __restrict__ vf, const float* __restrict__ temp,
    float* __restrict__ out_f)
{
    __shared__ float2 Q[8][65];
    __shared__ float2 Ks[8][65];
    __shared__ float2 V[8][65];
    __shared__ float2 Z2[8][65];
    __shared__ float2 ATT[8][9];
    __shared__ float2 TW[64];

    const int bc = blockIdx.x;
    const int t = threadIdx.x;
    const long base = (long)bc * 512;

#pragma unroll
    for (int h = 0; h < 8; h++) {
        Q[h][t]  = c_load(qf + base + h * 64 + t);
        Ks[h][t] = c_load(kf + base + h * 64 + t);
        V[h][t]  = c_load(vf + base + h * 64 + t);
    }
    {
        float ang = (2.0f * FFT_PI / 64.0f) * (float)t;
        float s, c;
        __sincosf(ang, &s, &c);
        TW[t] = make_float2(c, s);   // e^{+i 2pi t/64}
    }
    __syncthreads();

#pragma unroll
    for (int h = 0; h < 8; h++) {
        float2 zq = Q[h][t], zk = Ks[h][t];
        float pq = zq.x * zq.x + zq.y * zq.y;
        float pk = zk.x * zk.x + zk.y * zk.y;
#pragma unroll
        for (int o = 32; o > 0; o >>= 1) {
            pq += __shfl_xor(pq, o, 64);
            pk += __shfl_xor(pk, o, 64);
        }
        float iq = 1.0f / fmaxf(sqrtf(pq), 1e-12f);
        float ik = 1.0f / fmaxf(sqrtf(pk), 1e-12f);
        Q[h][t]  = make_float2(zq.x * iq, zq.y * iq);
        Ks[h][t] = make_float2(zk.x * ik, zk.y * ik);
    }
    __syncthreads();

    {
        const int h = t >> 3, g = t & 7;
        float ar = 0.f, ai = 0.f;
        for (int w = 0; w < 64; w++) {
            float2 a = Q[h][w], b = Ks[g][w];
            ar += a.x * b.x - a.y * b.y;
            ai += a.x * b.y + a.y * b.x;
        }
        float tm = temp[h];
        ATT[h][g] = make_float2(ar * tm, ai * tm);
    }
    __syncthreads();

    if (t < 8) {
        const int h = t;
        float mr = -1e30f, mi = -1e30f;
        for (int g = 0; g < 8; g++) {
            mr = fmaxf(mr, ATT[h][g].x);
            mi = fmaxf(mi, ATT[h][g].y);
        }
        float er[8], ei[8];
        float sr = 0.f, si = 0.f;
        for (int g = 0; g < 8; g++) {
            er[g] = __expf(ATT[h][g].x - mr); sr += er[g];
            ei[g] = __expf(ATT[h][g].y - mi); si += ei[g];
        }
        float isr = 1.f / sr, isi = 1.f / si;
        for (int g = 0; g < 8; g++)
            ATT[h][g] = make_float2(er[g] * isr, ei[g] * isi);
    }
    __syncthreads();

    float2 o[8];
#pragma unroll
    for (int h = 0; h < 8; h++) {
        float orr = 0.f, oi = 0.f;
#pragma unroll
        for (int g = 0; g < 8; g++) {
            float2 a = ATT[h][g], b = V[g][t];
            orr += a.x * b.x - a.y * b.y;
            oi  += a.x * b.y + a.y * b.x;
        }
        o[h] = make_float2(orr, oi);
    }
    __syncthreads();
#pragma unroll
    for (int h = 0; h < 8; h++) Q[h][t] = o[h];
    __syncthreads();

    // inverse FFT along w (64)
#pragma unroll
    for (int h = 0; h < 8; h++) {
        float sr = 0.f, si = 0.f;
        for (int n = 0; n < 64; n++) {
            float2 z = Q[h][n];
            float2 w = TW[(n * t) & 63];
            sr += z.x * w.x - z.y * w.y;
            si += z.x * w.y + z.y * w.x;
        }
        Z2[h][t] = make_float2(sr, si);
    }
    __syncthreads();

    // inverse FFT along h (8) + abs + store
    float* outp = out_f + base;
#pragma unroll
    for (int kh = 0; kh < 8; kh++) {
        float sr = 0.f, si = 0.f;
#pragma unroll
        for (int n = 0; n < 8; n++) {
            float2 z = Z2[n][t];
            float2 w = TW[((n * kh) & 7) * 8];
            sr += z.x * w.x - z.y * w.y;
            si += z.x * w.y + z.y * w.x;
        }
        sr *= (1.0f / 512.0f);
        si *= (1.0f / 512.0f);
        outp[kh * 64 + t] = sqrtf(sr * sr + si * si);
    }
}

// ---------------------------------------------------------------------------
__global__ __launch_bounds__(256) void bn_relu_kernel(
    float* __restrict__ g,
    const float* __restrict__ gamma, const float* __restrict__ beta,
    const float* __restrict__ mean, const float* __restrict__ var)
{
    const long i = (long)blockIdx.x * 256 + threadIdx.x;
    const int c = (int)((i >> 9) & 511);
    float x = g[i];
    x = (x - mean[c]) * (1.0f / sqrtf(var[c] + 1e-5f)) * gamma[c] + beta[c];
    g[i] = fmaxf(x, 0.f);
}

__global__ __launch_bounds__(256) void addstore_kernel(
    const float* __restrict__ tmp, const float* __restrict__ conv2,
    float* __restrict__ out)
{
    const long i = (long)blockIdx.x * 256 + threadIdx.x;
    out[i] = tmp[i] + conv2[i];
}

// ---------------------------------------------------------------------------
extern "C" void kernel_launch(void* const* d_in, const int* in_sizes, int n_in,
                              void* d_out, int out_size, void* d_ws, size_t ws_size,
                              hipStream_t stream)
{
    const float* x     = (const float*)d_in[0];
    const float* W_in  = (const float*)d_in[1];
    const float* b_in  = (const float*)d_in[2];
    const float* W_q   = (const float*)d_in[3];
    const float* b_q   = (const float*)d_in[4];
    const float* W_k   = (const float*)d_in[5];
    const float* b_k   = (const float*)d_in[6];
    const float* W_v   = (const float*)d_in[7];
    const float* b_v   = (const float*)d_in[8];
    const float* temp  = (const float*)d_in[9];
    const float* W1a   = (const float*)d_in[10];
    const float* b1a   = (const float*)d_in[11];
    const float* gam   = (const float*)d_in[12];
    const float* bet   = (const float*)d_in[13];
    const float* mea   = (const float*)d_in[14];
    const float* var   = (const float*)d_in[15];
    const float* W1b   = (const float*)d_in[16];
    const float* b1b   = (const float*)d_in[17];
    const float* W_out = (const float*)d_in[18];
    const float* b_out = (const float*)d_in[19];

    // Workspace layout (160 MB):
    //   R0 [  0, 32) MB  conv2 f32
    //   R1 [ 32, 64) MB  q_f cplx-bf16 -> out_f f32 (after attn, in place)
    //   R2 [ 64, 96) MB  k_f cplx-bf16 -> g1 f32 -> out_l f32
    //   R3 [ 96,128) MB  v_f cplx-bf16 -> g2 f32 -> out2 f32
    //   R4 [128,160) MB  tep cplx-bf16 (gated ifft in place)
    char* wsb = (char*)d_ws;
    const long MB = 1024 * 1024;
    float*   conv2 = (float*)wsb;
    ushort2* Qb    = (ushort2*)(wsb + 32 * MB);
    ushort2* Kb    = (ushort2*)(wsb + 64 * MB);
    ushort2* Vb    = (ushort2*)(wsb + 96 * MB);
    ushort2* Tb    = (ushort2*)(wsb + 128 * MB);
    float*   outF  = (float*)Qb;
    float*   g1    = (float*)Kb;
    float*   outL  = (float*)Kb;
    float*   g2    = (float*)Vb;
    float*   out2  = (float*)Vb;

    const dim3 gg(8, 256), gb(256);
    const int LINES = 16384;
    const int EW = 32768;   // 8388608 / 256

    // 1. conv2 = x @ W_in + b_in  (f32)
    gemm_kernel<<<gg, gb, 0, stream>>>(x, 0, 512, W_in, 512, b_in, conv2, 0, 512, 512, 0);

    // 2. qf = fft2(conv2 @ W_q + b_q) -> Qb (in place)
    gemm_kernel<<<gg, gb, 0, stream>>>(conv2, 0, 512, W_q, 512, b_q, Qb, 2, 512, 512, 0);
    fft_rows_c2c_bf16<<<LINES, 256, 0, stream>>>(Qb, -1.f);
    fft_cols_c2c_bf16<<<LINES, 256, 0, stream>>>(Qb, -1.f);

    // 3. kf -> Kb
    gemm_kernel<<<gg, gb, 0, stream>>>(conv2, 0, 512, W_k, 512, b_k, Kb, 2, 512, 512, 0);
    fft_rows_c2c_bf16<<<LINES, 256, 0, stream>>>(Kb, -1.f);
    fft_cols_c2c_bf16<<<LINES, 256, 0, stream>>>(Kb, -1.f);

    // 4. vf -> Vb
    gemm_kernel<<<gg, gb, 0, stream>>>(conv2, 0, 512, W_v, 512, b_v, Vb, 2, 512, 512, 0);
    fft_rows_c2c_bf16<<<LINES, 256, 0, stream>>>(Vb, -1.f);
    fft_cols_c2c_bf16<<<LINES, 256, 0, stream>>>(Vb, -1.f);

    // 5. attention + ifft2(8,64) + abs -> out_f f32 over Qb
    attn_kernel<<<LINES, 64, 0, stream>>>(Qb, Kb, Vb, temp, outF);

    // 6. tep = fft2(conv2) -> Tb
    fft_rows_r2c_f32<<<LINES, 256, 0, stream>>>(conv2, Tb, -1.f);
    fft_cols_c2c_bf16<<<LINES, 256, 0, stream>>>(Tb, -1.f);

    // 7. g1 = tep.real @ W1a + b1a -> g1 (f32, over Kb; k_f dead)
    gemm_kernel<<<gg, gb, 0, stream>>>(Tb, 2, 512, W1a, 512, b1a, g1, 0, 512, 512, 0);

    // 8. BN(eval) + ReLU in place
    bn_relu_kernel<<<EW, 256, 0, stream>>>(g1, gam, bet, mea, var);

    // 9. g2 = g1bn @ W1b + b1b -> g2 (f32, over Vb; v_f dead)
    gemm_kernel<<<gg, gb, 0, stream>>>(g1, 0, 512, W1b, 512, b1b, g2, 0, 512, 512, 0);

    // 10. gated row-ifft: sigmoid(g2)*tep, row-ifft, in place in Tb
    fft_rows_gated<<<LINES, 256, 0, stream>>>(g2, Tb);

    // 11. col-ifft + abs -> out_l f32 (over Kb; g1 dead)
    fft_cols_abs<<<LINES, 256, 0, stream>>>(Tb, outL);

    // 12. out2 = out_f @ W_out[0:512] + out_l @ W_out[512:] + b_out -> f32 over Vb
    gemm_kernel<<<gg, gb, 0, stream>>>(outF, 0, 512, W_out, 512, b_out, out2, 0, 512, 512, 0);
    gemm_kernel<<<gg, gb, 0, stream>>>(outL, 0, 512, W_out + 512 * 512, 512, nullptr, out2, 0, 512, 512, 1);

    // 13. d_out = out2 + conv2  (f32)
    addstore_kernel<<<EW, 256, 0, stream>>>(out2, conv2, (float*)d_out);
}

// Round 4
// 1940.114 us; speedup vs baseline: 1.5243x; 1.5243x over previous
//
#include <hip/hip_runtime.h>
#include <hip/hip_bf16.h>

#define FFT_PI 3.14159265358979323846f

typedef __hip_bfloat16 bf16;
typedef short bf8_t __attribute__((ext_vector_type(8)));
typedef float f4_t __attribute__((ext_vector_type(4)));

__device__ inline float bf2f(unsigned short u) {
    union { unsigned int i; float f; } v; v.i = ((unsigned int)u) << 16; return v.f;
}
__device__ inline unsigned short f2bf(float f) {
    bf16 h = __float2bfloat16(f);
    union { bf16 h; unsigned short u; } v; v.h = h; return v.u;
}
__device__ inline float2 c_load(const ushort2* p) {
    ushort2 u = *p;
    return make_float2(bf2f(u.x), bf2f(u.y));
}
__device__ inline void c_store(ushort2* p, float2 z) {
    ushort2 u; u.x = f2bf(z.x); u.y = f2bf(z.y); *p = u;
}

// ---------------------------------------------------------------------------
// Transpose + f32->bf16 convert: src f32 [R][C] -> dst bf16 [C][R].
// grid (C/32, R/32), block (32,8).
// ---------------------------------------------------------------------------
__global__ __launch_bounds__(256) void transpose_cvt(
    const float* __restrict__ src, bf16* __restrict__ dst, int R, int C)
{
    __shared__ float tile[32][33];
    const int bx = blockIdx.x * 32;   // col base in src
    const int by = blockIdx.y * 32;   // row base in src
    const int tx = threadIdx.x, ty = threadIdx.y;
#pragma unroll
    for (int i = 0; i < 32; i += 8)
        tile[ty + i][tx] = src[(long)(by + ty + i) * C + bx + tx];
    __syncthreads();
#pragma unroll
    for (int i = 0; i < 32; i += 8)
        dst[(long)(bx + ty + i) * R + by + tx] = __float2bfloat16(tile[tx][ty + i]);
}

// ---------------------------------------------------------------------------
// MFMA bf16 GEMM: C[M,N] = A[M,K] @ B[K,N] (+bias) (+accumulate)
// A: a_type 1 = f32 contiguous; 2 = bf16 interleaved-complex real part
//    (lda in complex elems). Converted to bf16 during LDS staging.
// Bt: bf16 TRANSPOSED weights [N][K], ldb = K-stride of that buffer.
// out_type: 0 = f32 (ldc f32 elems), 2 = bf16-complex zero imag (ldc cplx).
// Tile 128x128, BK=32, 256 threads = 4 waves in 2x2 grid, 16x16x32 MFMA.
// grid: (N/128, M/128).
// ---------------------------------------------------------------------------
__global__ __launch_bounds__(256) void mfma_gemm(
    const void* __restrict__ Av, int a_type, int lda,
    const bf16* __restrict__ Bt, int ldb,
    const float* __restrict__ bias,
    void* __restrict__ Cout, int out_type, int ldc,
    int K, int accumulate)
{
    __shared__ short Asub[128 * 40];   // [m][k] pad 40 (80 B rows)
    __shared__ short Bsub[128 * 40];   // [n][k] pad 40

    const int tid = threadIdx.x;
    const int n0 = blockIdx.x * 128;
    const int m0 = blockIdx.y * 128;
    const int l  = tid & 63;
    const int wv = tid >> 6;
    const int wm = wv & 1, wn = wv >> 1;

    f4_t acc[4][4];
#pragma unroll
    for (int i = 0; i < 4; i++)
#pragma unroll
        for (int j = 0; j < 4; j++)
            acc[i][j] = (f4_t)0.f;

    const int srow = tid >> 2;         // 0..63
    const int sc8  = (tid & 3) * 8;    // 0,8,16,24

    for (int k0 = 0; k0 < K; k0 += 32) {
#pragma unroll
        for (int p = 0; p < 2; p++) {
            const int row = srow + p * 64;
            bf8_t av;
            if (a_type == 1) {
                const float4* src = (const float4*)((const float*)Av
                    + (long)(m0 + row) * lda + k0 + sc8);
                float4 u0 = src[0], u1 = src[1];
                av[0] = (short)f2bf(u0.x); av[1] = (short)f2bf(u0.y);
                av[2] = (short)f2bf(u0.z); av[3] = (short)f2bf(u0.w);
                av[4] = (short)f2bf(u1.x); av[5] = (short)f2bf(u1.y);
                av[6] = (short)f2bf(u1.z); av[7] = (short)f2bf(u1.w);
            } else {
                const ushort2* src = (const ushort2*)Av
                    + (long)(m0 + row) * lda + k0 + sc8;
#pragma unroll
                for (int j = 0; j < 8; j++) av[j] = (short)src[j].x;
            }
            *(bf8_t*)&Asub[row * 40 + sc8] = av;

            bf8_t bv = *(const bf8_t*)(Bt + (long)(n0 + row) * ldb + k0 + sc8);
            *(bf8_t*)&Bsub[row * 40 + sc8] = bv;
        }
        __syncthreads();

        bf8_t a_frag[4], b_frag[4];
        const int ko = (l >> 4) * 8;
        const int lr = l & 15;
#pragma unroll
        for (int fm = 0; fm < 4; fm++)
            a_frag[fm] = *(bf8_t*)&Asub[(wm * 64 + fm * 16 + lr) * 40 + ko];
#pragma unroll
        for (int fn = 0; fn < 4; fn++)
            b_frag[fn] = *(bf8_t*)&Bsub[(wn * 64 + fn * 16 + lr) * 40 + ko];
#pragma unroll
        for (int fm = 0; fm < 4; fm++)
#pragma unroll
            for (int fn = 0; fn < 4; fn++)
                acc[fm][fn] = __builtin_amdgcn_mfma_f32_16x16x32_bf16(
                    b_frag[fn], a_frag[fm], acc[fm][fn], 0, 0, 0);
        __syncthreads();
    }

    // epilogue: lane l, reg r holds C[m=l&15][n=(l>>4)*4+r] within fragment
    const int em = m0 + wm * 64 + (l & 15);
    const int en = n0 + wn * 64 + ((l >> 4) << 2);
#pragma unroll
    for (int fm = 0; fm < 4; fm++) {
        const long m = em + fm * 16;
#pragma unroll
        for (int fn = 0; fn < 4; fn++) {
            const int n = en + fn * 16;
            f4_t v = acc[fm][fn];
            if (bias) {
#pragma unroll
                for (int r = 0; r < 4; r++) v[r] += bias[n + r];
            }
            if (out_type == 0) {
                float4* c = (float4*)((float*)Cout + m * ldc + n);
                float4 o;
                o.x = v[0]; o.y = v[1]; o.z = v[2]; o.w = v[3];
                if (accumulate) {
                    float4 old = *c;
                    o.x += old.x; o.y += old.y; o.z += old.z; o.w += old.w;
                }
                *c = o;
            } else {
                union { ushort2 u2[4]; uint4 q; } t;
#pragma unroll
                for (int r = 0; r < 4; r++) { t.u2[r].x = f2bf(v[r]); t.u2[r].y = 0; }
                *(uint4*)((ushort2*)Cout + m * ldc + n) = t.q;
            }
        }
    }
}

// ---------------------------------------------------------------------------
// 512-point radix-2 Stockham FFT in LDS. 256 threads, 1 butterfly each/stage.
// ---------------------------------------------------------------------------
__device__ inline float2* fft512_lds(float2* bx, float2* by, int t, float sign)
{
    int ls = 0;
    for (int n = 512; n >= 2; n >>= 1) {
        const int m = n >> 1;
        const int s = 1 << ls;
        const int p = t >> ls;
        const int q = t & (s - 1);
        float2 a = bx[q + s * p];
        float2 b = bx[q + s * (p + m)];
        float ang = sign * (2.0f * FFT_PI) * (float)p / (float)n;
        float sw, cw;
        __sincosf(ang, &sw, &cw);
        float2 sum = make_float2(a.x + b.x, a.y + b.y);
        float2 dif = make_float2(a.x - b.x, a.y - b.y);
        float2 tw  = make_float2(dif.x * cw - dif.y * sw, dif.x * sw + dif.y * cw);
        by[q + s * (2 * p)]     = sum;
        by[q + s * (2 * p + 1)] = tw;
        __syncthreads();
        float2* tmp = bx; bx = by; by = tmp;
        ls++;
    }
    return bx;
}

__global__ __launch_bounds__(256) void fft_rows_c2c_bf16(
    ushort2* __restrict__ data, float sign)
{
    __shared__ float2 b0[512], b1[512];
    ushort2* s = data + (long)blockIdx.x * 512;
    const int t = threadIdx.x;
    b0[t]       = c_load(s + t);
    b0[t + 256] = c_load(s + t + 256);
    __syncthreads();
    float2* r = fft512_lds(b0, b1, t, sign);
    c_store(s + t,       r[t]);
    c_store(s + t + 256, r[t + 256]);
}

__global__ __launch_bounds__(256) void fft_rows_r2c_f32(
    const float* __restrict__ src, ushort2* __restrict__ dst, float sign)
{
    __shared__ float2 b0[512], b1[512];
    const long line = blockIdx.x;
    const int t = threadIdx.x;
    const float* s = src + line * 512;
    b0[t]       = make_float2(s[t], 0.f);
    b0[t + 256] = make_float2(s[t + 256], 0.f);
    __syncthreads();
    float2* r = fft512_lds(b0, b1, t, sign);
    ushort2* d = dst + line * 512;
    c_store(d + t,       r[t]);
    c_store(d + t + 256, r[t + 256]);
}

__global__ __launch_bounds__(256) void fft_cols_c2c_bf16(
    ushort2* __restrict__ data, float sign)
{
    __shared__ float2 b0[512], b1[512];
    const int b = blockIdx.x >> 9;
    const int d = blockIdx.x & 511;
    ushort2* base = data + (long)b * 262144 + d;
    const int t = threadIdx.x;
    b0[t]       = c_load(base + (long)t * 512);
    b0[t + 256] = c_load(base + (long)(t + 256) * 512);
    __syncthreads();
    float2* r = fft512_lds(b0, b1, t, sign);
    c_store(base + (long)t * 512,         r[t]);
    c_store(base + (long)(t + 256) * 512, r[t + 256]);
}

__global__ __launch_bounds__(256) void fft_rows_gated(
    const float* __restrict__ g2, ushort2* __restrict__ tep)
{
    __shared__ float2 b0[512], b1[512];
    const long line = blockIdx.x;
    const int t = threadIdx.x;
    ushort2* s = tep + line * 512;
    const float* g = g2 + line * 512;
#pragma unroll
    for (int o = 0; o < 2; o++) {
        const int i = t + o * 256;
        float sg = 1.0f / (1.0f + __expf(-g[i]));
        float2 z = c_load(s + i);
        b0[i] = make_float2(sg * z.x, sg * z.y);
    }
    __syncthreads();
    float2* r = fft512_lds(b0, b1, t, +1.f);
    const float sc = 1.0f / 512.0f;
    c_store(s + t,       make_float2(r[t].x * sc, r[t].y * sc));
    c_store(s + t + 256, make_float2(r[t + 256].x * sc, r[t + 256].y * sc));
}

__global__ __launch_bounds__(256) void fft_cols_abs(
    const ushort2* __restrict__ src, float* __restrict__ dst)
{
    __shared__ float2 b0[512], b1[512];
    const int b = blockIdx.x >> 9;
    const int d = blockIdx.x & 511;
    const ushort2* base = src + (long)b * 262144 + d;
    const int t = threadIdx.x;
    b0[t]       = c_load(base + (long)t * 512);
    b0[t + 256] = c_load(base + (long)(t + 256) * 512);
    __syncthreads();
    float2* r = fft512_lds(b0, b1, t, +1.f);
    const float sc = 1.0f / 512.0f;
    float* db = dst + (long)b * 262144 + d;
    float2 z = r[t];
    db[(long)t * 512] = sqrtf(z.x * z.x + z.y * z.y) * sc;
    float2 z2 = r[t + 256];
    db[(long)(t + 256) * 512] = sqrtf(z2.x * z2.x + z2.y * z2.y) * sc;
}

// ---------------------------------------------------------------------------
// Per-(b,c) attention (unchanged from R3). Writes f32 out_f over own qf chunk.
// ---------------------------------------------------------------------------
__global__ __launch_bounds__(64) void attn_kernel(
    const ushort2* __restrict__ qf, const ushort2* __restrict__ kf,
    const ushort2* __restrict__ vf, const float* __restrict__ temp,
    float* __restrict__ out_f)
{
    __shared__ float2 Q[8][65];
    __shared__ float2 Ks[8][65];
    __shared__ float2 V[8][65];
    __shared__ float2 Z2[8][65];
    __shared__ float2 ATT[8][9];
    __shared__ float2 TW[64];

    const int bc = blockIdx.x;
    const int t = threadIdx.x;
    const long base = (long)bc * 512;

#pragma unroll
    for (int h = 0; h < 8; h++) {
        Q[h][t]  = c_load(qf + base + h * 64 + t);
        Ks[h][t] = c_load(kf + base + h * 64 + t);
        V[h][t]  = c_load(vf + base + h * 64 + t);
    }
    {
        float ang = (2.0f * FFT_PI / 64.0f) * (float)t;
        float s, c;
        __sincosf(ang, &s, &c);
        TW[t] = make_float2(c, s);
    }
    __syncthreads();

#pragma unroll
    for (int h = 0; h < 8; h++) {
        float2 zq = Q[h][t], zk = Ks[h][t];
        float pq = zq.x * zq.x + zq.y * zq.y;
        float pk = zk.x * zk.x + zk.y * zk.y;
#pragma unroll
        for (int o = 32; o > 0; o >>= 1) {
            pq += __shfl_xor(pq, o, 64);
            pk += __shfl_xor(pk, o, 64);
        }
        float iq = 1.0f / fmaxf(sqrtf(pq), 1e-12f);
        float ik = 1.0f / fmaxf(sqrtf(pk), 1e-12f);
        Q[h][t]  = make_float2(zq.x * iq, zq.y * iq);
        Ks[h][t] = make_float2(zk.x * ik, zk.y * ik);
    }
    __syncthreads();

    {
        const int h = t >> 3, g = t & 7;
        float ar = 0.f, ai = 0.f;
        for (int w = 0; w < 64; w++) {
            float2 a = Q[h][w], b = Ks[g][w];
            ar += a.x * b.x - a.y * b.y;
            ai += a.x * b.y + a.y * b.x;
        }
        float tm = temp[h];
        ATT[h][g] = make_float2(ar * tm, ai * tm);
    }
    __syncthreads();

    if (t < 8) {
        const int h = t;
        float mr = -1e30f, mi = -1e30f;
        for (int g = 0; g < 8; g++) {
            mr = fmaxf(mr, ATT[h][g].x);
            mi = fmaxf(mi, ATT[h][g].y);
        }
        float er[8], ei[8];
        float sr = 0.f, si = 0.f;
        for (int g = 0; g < 8; g++) {
            er[g] = __expf(ATT[h][g].x - mr); sr += er[g];
            ei[g] = __expf(ATT[h][g].y - mi); si += ei[g];
        }
        float isr = 1.f / sr, isi = 1.f / si;
        for (int g = 0; g < 8; g++)
            ATT[h][g] = make_float2(er[g] * isr, ei[g] * isi);
    }
    __syncthreads();

    float2 o[8];
#pragma unroll
    for (int h = 0; h < 8; h++) {
        float orr = 0.f, oi = 0.f;
#pragma unroll
        for (int g = 0; g < 8; g++) {
            float2 a = ATT[h][g], b = V[g][t];
            orr += a.x * b.x - a.y * b.y;
            oi  += a.x * b.y + a.y * b.x;
        }
        o[h] = make_float2(orr, oi);
    }
    __syncthreads();
#pragma unroll
    for (int h = 0; h < 8; h++) Q[h][t] = o[h];
    __syncthreads();

#pragma unroll
    for (int h = 0; h < 8; h++) {
        float sr = 0.f, si = 0.f;
        for (int n = 0; n < 64; n++) {
            float2 z = Q[h][n];
            float2 w = TW[(n * t) & 63];
            sr += z.x * w.x - z.y * w.y;
            si += z.x * w.y + z.y * w.x;
        }
        Z2[h][t] = make_float2(sr, si);
    }
    __syncthreads();

    float* outp = out_f + base;
#pragma unroll
    for (int kh = 0; kh < 8; kh++) {
        float sr = 0.f, si = 0.f;
#pragma unroll
        for (int n = 0; n < 8; n++) {
            float2 z = Z2[n][t];
            float2 w = TW[((n * kh) & 7) * 8];
            sr += z.x * w.x - z.y * w.y;
            si += z.x * w.y + z.y * w.x;
        }
        sr *= (1.0f / 512.0f);
        si *= (1.0f / 512.0f);
        outp[kh * 64 + t] = sqrtf(sr * sr + si * si);
    }
}

// ---------------------------------------------------------------------------
__global__ __launch_bounds__(256) void bn_relu_kernel(
    float* __restrict__ g,
    const float* __restrict__ gamma, const float* __restrict__ beta,
    const float* __restrict__ mean, const float* __restrict__ var)
{
    const long i = (long)blockIdx.x * 256 + threadIdx.x;
    const int c = (int)((i >> 9) & 511);
    float x = g[i];
    x = (x - mean[c]) * (1.0f / sqrtf(var[c] + 1e-5f)) * gamma[c] + beta[c];
    g[i] = fmaxf(x, 0.f);
}

__global__ __launch_bounds__(256) void addstore_kernel(
    const float* __restrict__ tmp, const float* __restrict__ conv2,
    float* __restrict__ out)
{
    const long i = (long)blockIdx.x * 256 + threadIdx.x;
    out[i] = tmp[i] + conv2[i];
}

// ---------------------------------------------------------------------------
extern "C" void kernel_launch(void* const* d_in, const int* in_sizes, int n_in,
                              void* d_out, int out_size, void* d_ws, size_t ws_size,
                              hipStream_t stream)
{
    const float* x     = (const float*)d_in[0];
    const float* W_in  = (const float*)d_in[1];
    const float* b_in  = (const float*)d_in[2];
    const float* W_q   = (const float*)d_in[3];
    const float* b_q   = (const float*)d_in[4];
    const float* W_k   = (const float*)d_in[5];
    const float* b_k   = (const float*)d_in[6];
    const float* W_v   = (const float*)d_in[7];
    const float* b_v   = (const float*)d_in[8];
    const float* temp  = (const float*)d_in[9];
    const float* W1a   = (const float*)d_in[10];
    const float* b1a   = (const float*)d_in[11];
    const float* gam   = (const float*)d_in[12];
    const float* bet   = (const float*)d_in[13];
    const float* mea   = (const float*)d_in[14];
    const float* var   = (const float*)d_in[15];
    const float* W1b   = (const float*)d_in[16];
    const float* b1b   = (const float*)d_in[17];
    const float* W_out = (const float*)d_in[18];
    const float* b_out = (const float*)d_in[19];

    // Workspace (165 MB):
    //   R0 [  0, 32) conv2 f32
    //   R1 [ 32, 64) q_f cplx-bf16 -> out_f f32 (attn, in place)
    //   R2 [ 64, 96) k_f -> g1 f32 -> out_l f32
    //   R3 [ 96,128) v_f -> g2 f32 -> out2 f32
    //   R4 [128,160) tep cplx-bf16 (gated ifft in place)
    //   R5 [160,165) transposed bf16 weights
    char* wsb = (char*)d_ws;
    const long MB = 1024 * 1024;
    float*   conv2 = (float*)wsb;
    ushort2* Qb    = (ushort2*)(wsb + 32 * MB);
    ushort2* Kb    = (ushort2*)(wsb + 64 * MB);
    ushort2* Vb    = (ushort2*)(wsb + 96 * MB);
    ushort2* Tb    = (ushort2*)(wsb + 128 * MB);
    bf16*    Wt    = (bf16*)(wsb + 160 * MB);
    bf16* WT_in  = Wt;                 // [512][512]
    bf16* WT_q   = Wt + 262144;
    bf16* WT_k   = Wt + 2 * 262144;
    bf16* WT_v   = Wt + 3 * 262144;
    bf16* WT_1a  = Wt + 4 * 262144;
    bf16* WT_1b  = Wt + 5 * 262144;
    bf16* WT_out = Wt + 6 * 262144;    // [512][1024]
    float*   outF  = (float*)Qb;
    float*   g1    = (float*)Kb;
    float*   outL  = (float*)Kb;
    float*   g2    = (float*)Vb;
    float*   out2  = (float*)Vb;

    const dim3 tgrid(16, 16), tblk(32, 8);
    const dim3 ggrid(4, 128), gblk(256);
    const int LINES = 16384;
    const int EW = 32768;

    // 0. transpose+convert weights to bf16 [N][K]
    transpose_cvt<<<tgrid, tblk, 0, stream>>>(W_in, WT_in, 512, 512);
    transpose_cvt<<<tgrid, tblk, 0, stream>>>(W_q,  WT_q,  512, 512);
    transpose_cvt<<<tgrid, tblk, 0, stream>>>(W_k,  WT_k,  512, 512);
    transpose_cvt<<<tgrid, tblk, 0, stream>>>(W_v,  WT_v,  512, 512);
    transpose_cvt<<<tgrid, tblk, 0, stream>>>(W1a,  WT_1a, 512, 512);
    transpose_cvt<<<tgrid, tblk, 0, stream>>>(W1b,  WT_1b, 512, 512);
    transpose_cvt<<<dim3(16, 32), tblk, 0, stream>>>(W_out, WT_out, 1024, 512);

    // 1. conv2 = x @ W_in + b_in (f32 out)
    mfma_gemm<<<ggrid, gblk, 0, stream>>>(x, 1, 512, WT_in, 512, b_in,
                                          conv2, 0, 512, 512, 0);

    // 2. qf = fft2(conv2 @ W_q + b_q)
    mfma_gemm<<<ggrid, gblk, 0, stream>>>(conv2, 1, 512, WT_q, 512, b_q,
                                          Qb, 2, 512, 512, 0);
    fft_rows_c2c_bf16<<<LINES, 256, 0, stream>>>(Qb, -1.f);
    fft_cols_c2c_bf16<<<LINES, 256, 0, stream>>>(Qb, -1.f);

    // 3. kf
    mfma_gemm<<<ggrid, gblk, 0, stream>>>(conv2, 1, 512, WT_k, 512, b_k,
                                          Kb, 2, 512, 512, 0);
    fft_rows_c2c_bf16<<<LINES, 256, 0, stream>>>(Kb, -1.f);
    fft_cols_c2c_bf16<<<LINES, 256, 0, stream>>>(Kb, -1.f);

    // 4. vf
    mfma_gemm<<<ggrid, gblk, 0, stream>>>(conv2, 1, 512, WT_v, 512, b_v,
                                          Vb, 2, 512, 512, 0);
    fft_rows_c2c_bf16<<<LINES, 256, 0, stream>>>(Vb, -1.f);
    fft_cols_c2c_bf16<<<LINES, 256, 0, stream>>>(Vb, -1.f);

    // 5. attention -> out_f f32 over Qb
    attn_kernel<<<LINES, 64, 0, stream>>>(Qb, Kb, Vb, temp, outF);

    // 6. tep = fft2(conv2) -> Tb
    fft_rows_r2c_f32<<<LINES, 256, 0, stream>>>(conv2, Tb, -1.f);
    fft_cols_c2c_bf16<<<LINES, 256, 0, stream>>>(Tb, -1.f);

    // 7. g1 = tep.real @ W1a + b1a (A = cplx-bf16 real part)
    mfma_gemm<<<ggrid, gblk, 0, stream>>>(Tb, 2, 512, WT_1a, 512, b1a,
                                          g1, 0, 512, 512, 0);

    // 8. BN + ReLU in place
    bn_relu_kernel<<<EW, 256, 0, stream>>>(g1, gam, bet, mea, var);

    // 9. g2 = g1 @ W1b + b1b
    mfma_gemm<<<ggrid, gblk, 0, stream>>>(g1, 1, 512, WT_1b, 512, b1b,
                                          g2, 0, 512, 512, 0);

    // 10. gated row-ifft in place in Tb
    fft_rows_gated<<<LINES, 256, 0, stream>>>(g2, Tb);

    // 11. col-ifft + abs -> out_l f32 (over Kb)
    fft_cols_abs<<<LINES, 256, 0, stream>>>(Tb, outL);

    // 12. out2 = out_f @ W_out[:512] + out_l @ W_out[512:] + b_out
    mfma_gemm<<<ggrid, gblk, 0, stream>>>(outF, 1, 512, WT_out, 1024, b_out,
                                          out2, 0, 512, 512, 0);
    mfma_gemm<<<ggrid, gblk, 0, stream>>>(outL, 1, 512, WT_out + 512, 1024, nullptr,
                                          out2, 0, 512, 512, 1);

    // 13. d_out = out2 + conv2
    addstore_kernel<<<EW, 256, 0, stream>>>(out2, conv2, (float*)d_out);
}

// Round 5
// 1140.750 us; speedup vs baseline: 2.5924x; 1.7007x over previous
//
#include <hip/hip_runtime.h>
#include <hip/hip_bf16.h>

#define FFT_PI 3.14159265358979323846f

typedef __hip_bfloat16 bf16;
typedef short bf8_t __attribute__((ext_vector_type(8)));
typedef float f4_t __attribute__((ext_vector_type(4)));

__device__ inline float bf2f(unsigned short u) {
    union { unsigned int i; float f; } v; v.i = ((unsigned int)u) << 16; return v.f;
}
__device__ inline unsigned short f2bf(float f) {
    bf16 h = __float2bfloat16(f);
    union { bf16 h; unsigned short u; } v; v.h = h; return v.u;
}
__device__ inline float2 c_load(const ushort2* p) {
    ushort2 u = *p;
    return make_float2(bf2f(u.x), bf2f(u.y));
}
__device__ inline void c_store(ushort2* p, float2 z) {
    ushort2 u; u.x = f2bf(z.x); u.y = f2bf(z.y); *p = u;
}
__device__ inline int brev6(int t) {
    return ((t & 1) << 5) | ((t & 2) << 3) | ((t & 4) << 1) |
           ((t & 8) >> 1) | ((t & 16) >> 3) | ((t & 32) >> 5);
}

// ---------------------------------------------------------------------------
// Transpose + f32->bf16 convert: src f32 [R][C] -> dst bf16 [C][R].
// ---------------------------------------------------------------------------
__global__ __launch_bounds__(256) void transpose_cvt(
    const float* __restrict__ src, bf16* __restrict__ dst, int R, int C)
{
    __shared__ float tile[32][33];
    const int bx = blockIdx.x * 32;
    const int by = blockIdx.y * 32;
    const int tx = threadIdx.x, ty = threadIdx.y;
#pragma unroll
    for (int i = 0; i < 32; i += 8)
        tile[ty + i][tx] = src[(long)(by + ty + i) * C + bx + tx];
    __syncthreads();
#pragma unroll
    for (int i = 0; i < 32; i += 8)
        dst[(long)(bx + ty + i) * R + by + tx] = __float2bfloat16(tile[tx][ty + i]);
}

// ---------------------------------------------------------------------------
// MFMA bf16 GEMM (unchanged from R4). Tile 128x128, BK=32, 4 waves.
// ---------------------------------------------------------------------------
__global__ __launch_bounds__(256) void mfma_gemm(
    const void* __restrict__ Av, int a_type, int lda,
    const bf16* __restrict__ Bt, int ldb,
    const float* __restrict__ bias,
    void* __restrict__ Cout, int out_type, int ldc,
    int K, int accumulate)
{
    __shared__ short Asub[128 * 40];
    __shared__ short Bsub[128 * 40];

    const int tid = threadIdx.x;
    const int n0 = blockIdx.x * 128;
    const int m0 = blockIdx.y * 128;
    const int l  = tid & 63;
    const int wv = tid >> 6;
    const int wm = wv & 1, wn = wv >> 1;

    f4_t acc[4][4];
#pragma unroll
    for (int i = 0; i < 4; i++)
#pragma unroll
        for (int j = 0; j < 4; j++)
            acc[i][j] = (f4_t)0.f;

    const int srow = tid >> 2;
    const int sc8  = (tid & 3) * 8;

    for (int k0 = 0; k0 < K; k0 += 32) {
#pragma unroll
        for (int p = 0; p < 2; p++) {
            const int row = srow + p * 64;
            bf8_t av;
            if (a_type == 1) {
                const float4* src = (const float4*)((const float*)Av
                    + (long)(m0 + row) * lda + k0 + sc8);
                float4 u0 = src[0], u1 = src[1];
                av[0] = (short)f2bf(u0.x); av[1] = (short)f2bf(u0.y);
                av[2] = (short)f2bf(u0.z); av[3] = (short)f2bf(u0.w);
                av[4] = (short)f2bf(u1.x); av[5] = (short)f2bf(u1.y);
                av[6] = (short)f2bf(u1.z); av[7] = (short)f2bf(u1.w);
            } else {
                const ushort2* src = (const ushort2*)Av
                    + (long)(m0 + row) * lda + k0 + sc8;
#pragma unroll
                for (int j = 0; j < 8; j++) av[j] = (short)src[j].x;
            }
            *(bf8_t*)&Asub[row * 40 + sc8] = av;

            bf8_t bv = *(const bf8_t*)(Bt + (long)(n0 + row) * ldb + k0 + sc8);
            *(bf8_t*)&Bsub[row * 40 + sc8] = bv;
        }
        __syncthreads();

        bf8_t a_frag[4], b_frag[4];
        const int ko = (l >> 4) * 8;
        const int lr = l & 15;
#pragma unroll
        for (int fm = 0; fm < 4; fm++)
            a_frag[fm] = *(bf8_t*)&Asub[(wm * 64 + fm * 16 + lr) * 40 + ko];
#pragma unroll
        for (int fn = 0; fn < 4; fn++)
            b_frag[fn] = *(bf8_t*)&Bsub[(wn * 64 + fn * 16 + lr) * 40 + ko];
#pragma unroll
        for (int fm = 0; fm < 4; fm++)
#pragma unroll
            for (int fn = 0; fn < 4; fn++)
                acc[fm][fn] = __builtin_amdgcn_mfma_f32_16x16x32_bf16(
                    b_frag[fn], a_frag[fm], acc[fm][fn], 0, 0, 0);
        __syncthreads();
    }

    const int em = m0 + wm * 64 + (l & 15);
    const int en = n0 + wn * 64 + ((l >> 4) << 2);
#pragma unroll
    for (int fm = 0; fm < 4; fm++) {
        const long m = em + fm * 16;
#pragma unroll
        for (int fn = 0; fn < 4; fn++) {
            const int n = en + fn * 16;
            f4_t v = acc[fm][fn];
            if (bias) {
#pragma unroll
                for (int r = 0; r < 4; r++) v[r] += bias[n + r];
            }
            if (out_type == 0) {
                float4* c = (float4*)((float*)Cout + m * ldc + n);
                float4 o;
                o.x = v[0]; o.y = v[1]; o.z = v[2]; o.w = v[3];
                if (accumulate) {
                    float4 old = *c;
                    o.x += old.x; o.y += old.y; o.z += old.z; o.w += old.w;
                }
                *c = o;
            } else {
                union { ushort2 u2[4]; uint4 q; } t;
#pragma unroll
                for (int r = 0; r < 4; r++) { t.u2[r].x = f2bf(v[r]); t.u2[r].y = 0; }
                *(uint4*)((ushort2*)Cout + m * ldc + n) = t.q;
            }
        }
    }
}

// ---------------------------------------------------------------------------
// 512-point radix-2 Stockham FFT in LDS (row kernels).
// ---------------------------------------------------------------------------
__device__ inline float2* fft512_lds(float2* bx, float2* by, int t, float sign)
{
    int ls = 0;
    for (int n = 512; n >= 2; n >>= 1) {
        const int m = n >> 1;
        const int s = 1 << ls;
        const int p = t >> ls;
        const int q = t & (s - 1);
        float2 a = bx[q + s * p];
        float2 b = bx[q + s * (p + m)];
        float ang = sign * (2.0f * FFT_PI) * (float)p / (float)n;
        float sw, cw;
        __sincosf(ang, &sw, &cw);
        float2 sum = make_float2(a.x + b.x, a.y + b.y);
        float2 dif = make_float2(a.x - b.x, a.y - b.y);
        float2 tw  = make_float2(dif.x * cw - dif.y * sw, dif.x * sw + dif.y * cw);
        by[q + s * (2 * p)]     = sum;
        by[q + s * (2 * p + 1)] = tw;
        __syncthreads();
        float2* tmp = bx; bx = by; by = tmp;
        ls++;
    }
    return bx;
}

__global__ __launch_bounds__(256) void fft_rows_c2c_bf16(
    ushort2* __restrict__ data, float sign)
{
    __shared__ float2 b0[512], b1[512];
    ushort2* s = data + (long)blockIdx.x * 512;
    const int t = threadIdx.x;
    b0[t]       = c_load(s + t);
    b0[t + 256] = c_load(s + t + 256);
    __syncthreads();
    float2* r = fft512_lds(b0, b1, t, sign);
    c_store(s + t,       r[t]);
    c_store(s + t + 256, r[t + 256]);
}

__global__ __launch_bounds__(256) void fft_rows_r2c_f32(
    const float* __restrict__ src, ushort2* __restrict__ dst, float sign)
{
    __shared__ float2 b0[512], b1[512];
    const long line = blockIdx.x;
    const int t = threadIdx.x;
    const float* s = src + line * 512;
    b0[t]       = make_float2(s[t], 0.f);
    b0[t + 256] = make_float2(s[t + 256], 0.f);
    __syncthreads();
    float2* r = fft512_lds(b0, b1, t, sign);
    ushort2* d = dst + line * 512;
    c_store(d + t,       r[t]);
    c_store(d + t + 256, r[t + 256]);
}

__global__ __launch_bounds__(256) void fft_rows_gated(
    const float* __restrict__ g2, ushort2* __restrict__ tep)
{
    __shared__ float2 b0[512], b1[512];
    const long line = blockIdx.x;
    const int t = threadIdx.x;
    ushort2* s = tep + line * 512;
    const float* g = g2 + line * 512;
#pragma unroll
    for (int o = 0; o < 2; o++) {
        const int i = t + o * 256;
        float sg = 1.0f / (1.0f + __expf(-g[i]));
        float2 z = c_load(s + i);
        b0[i] = make_float2(sg * z.x, sg * z.y);
    }
    __syncthreads();
    float2* r = fft512_lds(b0, b1, t, +1.f);
    const float sc = 1.0f / 512.0f;
    c_store(s + t,       make_float2(r[t].x * sc, r[t].y * sc));
    c_store(s + t + 256, make_float2(r[t + 256].x * sc, r[t + 256].y * sc));
}

// ---------------------------------------------------------------------------
// Column FFT, 4 columns (d-indices) per block. data[b][c][d], FFT along c.
// block = 256 threads; blockIdx = b*128 + dgroup. LDS [4][514] pad: column
// bases land on distinct bank offsets (0,4,8,12) -> no cross-column conflict.
// ---------------------------------------------------------------------------
__global__ __launch_bounds__(256) void fft_cols4_c2c_bf16(
    ushort2* __restrict__ data, float sign)
{
    __shared__ float2 bA[4][514], bB[4][514];
    const int b  = blockIdx.x >> 7;
    const int c0 = (blockIdx.x & 127) * 4;
    ushort2* base = data + (long)b * 262144 + c0;
    const int t = threadIdx.x;

#pragma unroll
    for (int rr = 0; rr < 2; rr++) {
        const int row = 2 * t + rr;
        uint4 raw = *(const uint4*)(base + (long)row * 512);
        const ushort2* p = (const ushort2*)&raw;
#pragma unroll
        for (int j = 0; j < 4; j++) bA[j][row] = c_load(p + j);
    }
    __syncthreads();

    float2 (*bx)[514] = bA;
    float2 (*by)[514] = bB;
    int ls = 0;
    for (int n = 512; n >= 2; n >>= 1) {
        const int m = n >> 1;
        const int s = 1 << ls;
        const int p = t >> ls;
        const int q = t & (s - 1);
        float ang = sign * (2.0f * FFT_PI) * (float)p / (float)n;
        float sw, cw;
        __sincosf(ang, &sw, &cw);
        const int i0 = q + s * p, i1 = q + s * (p + m);
        const int o0 = q + s * (2 * p), o1 = q + s * (2 * p + 1);
#pragma unroll
        for (int j = 0; j < 4; j++) {
            float2 a = bx[j][i0];
            float2 bb = bx[j][i1];
            float2 sum = make_float2(a.x + bb.x, a.y + bb.y);
            float2 dif = make_float2(a.x - bb.x, a.y - bb.y);
            by[j][o0] = sum;
            by[j][o1] = make_float2(dif.x * cw - dif.y * sw, dif.x * sw + dif.y * cw);
        }
        __syncthreads();
        float2 (*tmp)[514] = bx; bx = by; by = tmp;
        ls++;
    }

#pragma unroll
    for (int rr = 0; rr < 2; rr++) {
        const int row = 2 * t + rr;
        union { ushort2 u2[4]; uint4 q; } o;
#pragma unroll
        for (int j = 0; j < 4; j++) {
            float2 z = bx[j][row];
            o.u2[j].x = f2bf(z.x); o.u2[j].y = f2bf(z.y);
        }
        *(uint4*)(base + (long)row * 512) = o.q;
    }
}

// Column inverse FFT + abs -> f32, 4 columns per block (scale 1/512).
__global__ __launch_bounds__(256) void fft_cols4_abs(
    const ushort2* __restrict__ src, float* __restrict__ dst)
{
    __shared__ float2 bA[4][514], bB[4][514];
    const int b  = blockIdx.x >> 7;
    const int c0 = (blockIdx.x & 127) * 4;
    const ushort2* base = src + (long)b * 262144 + c0;
    const int t = threadIdx.x;

#pragma unroll
    for (int rr = 0; rr < 2; rr++) {
        const int row = 2 * t + rr;
        uint4 raw = *(const uint4*)(base + (long)row * 512);
        const ushort2* p = (const ushort2*)&raw;
#pragma unroll
        for (int j = 0; j < 4; j++) bA[j][row] = c_load(p + j);
    }
    __syncthreads();

    float2 (*bx)[514] = bA;
    float2 (*by)[514] = bB;
    int ls = 0;
    for (int n = 512; n >= 2; n >>= 1) {
        const int m = n >> 1;
        const int s = 1 << ls;
        const int p = t >> ls;
        const int q = t & (s - 1);
        float ang = (2.0f * FFT_PI) * (float)p / (float)n;   // inverse sign +
        float sw, cw;
        __sincosf(ang, &sw, &cw);
        const int i0 = q + s * p, i1 = q + s * (p + m);
        const int o0 = q + s * (2 * p), o1 = q + s * (2 * p + 1);
#pragma unroll
        for (int j = 0; j < 4; j++) {
            float2 a = bx[j][i0];
            float2 bb = bx[j][i1];
            by[j][o0] = make_float2(a.x + bb.x, a.y + bb.y);
            float2 dif = make_float2(a.x - bb.x, a.y - bb.y);
            by[j][o1] = make_float2(dif.x * cw - dif.y * sw, dif.x * sw + dif.y * cw);
        }
        __syncthreads();
        float2 (*tmp)[514] = bx; bx = by; by = tmp;
        ls++;
    }

    const float sc = 1.0f / 512.0f;
#pragma unroll
    for (int rr = 0; rr < 2; rr++) {
        const int row = 2 * t + rr;
        float4 o;
        float* op = (float*)&o;
#pragma unroll
        for (int j = 0; j < 4; j++) {
            float2 z = bx[j][row];
            op[j] = sqrtf(z.x * z.x + z.y * z.y) * sc;
        }
        *(float4*)(dst + (long)b * 262144 + (long)row * 512 + c0) = o;
    }
}

// ---------------------------------------------------------------------------
// attn v2: q/k/v in registers (lane = w). Cross-lane radix-2 DIF inverse FFT
// along w (6 shfl stages, bit-reversed out), constant-twiddle 8-pt DFT along
// h in registers. LDS only for scores + softmax.
// ---------------------------------------------------------------------------
__global__ __launch_bounds__(64) void attn_kernel(
    const ushort2* __restrict__ qf, const ushort2* __restrict__ kf,
    const ushort2* __restrict__ vf, const float* __restrict__ temp,
    float* __restrict__ out_f)
{
    __shared__ float2 QS[8][66];
    __shared__ float2 KS[8][66];
    __shared__ float2 ATT[8][9];

    const int bc = blockIdx.x;
    const int t = threadIdx.x;
    const long base = (long)bc * 512;

    float2 q[8], k[8], v[8];
#pragma unroll
    for (int h = 0; h < 8; h++) {
        q[h] = c_load(qf + base + h * 64 + t);
        k[h] = c_load(kf + base + h * 64 + t);
        v[h] = c_load(vf + base + h * 64 + t);
    }

    // L2-normalize q,k per h over w (wave reductions)
#pragma unroll
    for (int h = 0; h < 8; h++) {
        float pq = q[h].x * q[h].x + q[h].y * q[h].y;
        float pk = k[h].x * k[h].x + k[h].y * k[h].y;
#pragma unroll
        for (int o = 32; o > 0; o >>= 1) {
            pq += __shfl_xor(pq, o, 64);
            pk += __shfl_xor(pk, o, 64);
        }
        float iq = 1.0f / fmaxf(sqrtf(pq), 1e-12f);
        float ik = 1.0f / fmaxf(sqrtf(pk), 1e-12f);
        q[h].x *= iq; q[h].y *= iq;
        k[h].x *= ik; k[h].y *= ik;
        QS[h][t] = q[h];
        KS[h][t] = k[h];
    }
    __syncthreads();

    // scores: lane = (h = t>>3, g = t&7)
    {
        const int h = t >> 3, g = t & 7;
        float ar = 0.f, ai = 0.f;
        for (int w = 0; w < 64; w++) {
            float2 a = QS[h][w], b = KS[g][w];
            ar += a.x * b.x - a.y * b.y;
            ai += a.x * b.y + a.y * b.x;
        }
        float tm = temp[h];
        ATT[h][g] = make_float2(ar * tm, ai * tm);
    }
    __syncthreads();

    // split softmax over g (8 lanes active)
    if (t < 8) {
        const int h = t;
        float mr = -1e30f, mi = -1e30f;
        for (int g = 0; g < 8; g++) {
            mr = fmaxf(mr, ATT[h][g].x);
            mi = fmaxf(mi, ATT[h][g].y);
        }
        float er[8], ei[8];
        float sr = 0.f, si = 0.f;
        for (int g = 0; g < 8; g++) {
            er[g] = __expf(ATT[h][g].x - mr); sr += er[g];
            ei[g] = __expf(ATT[h][g].y - mi); si += ei[g];
        }
        float isr = 1.f / sr, isi = 1.f / si;
        for (int g = 0; g < 8; g++)
            ATT[h][g] = make_float2(er[g] * isr, ei[g] * isi);
    }
    __syncthreads();

    // PV: o[h] = sum_g ATT[h][g] * v[g]   (ATT reads are wave-uniform)
    float2 o[8];
#pragma unroll
    for (int h = 0; h < 8; h++) {
        float orr = 0.f, oi = 0.f;
#pragma unroll
        for (int g = 0; g < 8; g++) {
            float2 a = ATT[h][g], b = v[g];
            orr += a.x * b.x - a.y * b.y;
            oi  += a.x * b.y + a.y * b.x;
        }
        o[h] = make_float2(orr, oi);
    }

    // inverse FFT along w: cross-lane radix-2 DIF, 6 stages.
    // top lane: a+b ; bottom lane: (a_partner - b_self) * W_{2m}^{t&(m-1)},
    // W = e^{+i*2pi/(2m)}. Output lane t holds freq brev6(t).
#pragma unroll
    for (int m = 32; m >= 1; m >>= 1) {
        float ang = (FFT_PI / (float)m) * (float)(t & (m - 1));
        float sw, cw;
        __sincosf(ang, &sw, &cw);
        const bool low = (t & m) == 0;
#pragma unroll
        for (int h = 0; h < 8; h++) {
            float px = __shfl_xor(o[h].x, m, 64);
            float py = __shfl_xor(o[h].y, m, 64);
            float nx, ny;
            if (low) {
                nx = o[h].x + px;
                ny = o[h].y + py;
            } else {
                float dx = px - o[h].x;
                float dy = py - o[h].y;
                nx = dx * cw - dy * sw;
                ny = dx * sw + dy * cw;
            }
            o[h].x = nx; o[h].y = ny;
        }
    }
    const int wr = brev6(t);

    // inverse 8-pt DFT along h (constant twiddles) + abs + store
    const float r2 = 0.70710678118654752f;
    const float W8x[8] = {1.f,  r2, 0.f, -r2, -1.f, -r2,  0.f,  r2};
    const float W8y[8] = {0.f,  r2, 1.f,  r2,  0.f, -r2, -1.f, -r2};
    float* outp = out_f + base;
#pragma unroll
    for (int kh = 0; kh < 8; kh++) {
        float sr = 0.f, si = 0.f;
#pragma unroll
        for (int n = 0; n < 8; n++) {
            const int idx = (n * kh) & 7;
            float wx = W8x[idx], wy = W8y[idx];
            sr += o[n].x * wx - o[n].y * wy;
            si += o[n].x * wy + o[n].y * wx;
        }
        outp[kh * 64 + wr] = sqrtf(sr * sr + si * si) * (1.0f / 512.0f);
    }
}

// ---------------------------------------------------------------------------
__global__ __launch_bounds__(256) void bn_relu_kernel(
    float* __restrict__ g,
    const float* __restrict__ gamma, const float* __restrict__ beta,
    const float* __restrict__ mean, const float* __restrict__ var)
{
    const long i = (long)blockIdx.x * 256 + threadIdx.x;
    const int c = (int)((i >> 9) & 511);
    float x = g[i];
    x = (x - mean[c]) * (1.0f / sqrtf(var[c] + 1e-5f)) * gamma[c] + beta[c];
    g[i] = fmaxf(x, 0.f);
}

__global__ __launch_bounds__(256) void addstore_kernel(
    const float* __restrict__ tmp, const float* __restrict__ conv2,
    float* __restrict__ out)
{
    const long i = (long)blockIdx.x * 256 + threadIdx.x;
    out[i] = tmp[i] + conv2[i];
}

// ---------------------------------------------------------------------------
extern "C" void kernel_launch(void* const* d_in, const int* in_sizes, int n_in,
                              void* d_out, int out_size, void* d_ws, size_t ws_size,
                              hipStream_t stream)
{
    const float* x     = (const float*)d_in[0];
    const float* W_in  = (const float*)d_in[1];
    const float* b_in  = (const float*)d_in[2];
    const float* W_q   = (const float*)d_in[3];
    const float* b_q   = (const float*)d_in[4];
    const float* W_k   = (const float*)d_in[5];
    const float* b_k   = (const float*)d_in[6];
    const float* W_v   = (const float*)d_in[7];
    const float* b_v   = (const float*)d_in[8];
    const float* temp  = (const float*)d_in[9];
    const float* W1a   = (const float*)d_in[10];
    const float* b1a   = (const float*)d_in[11];
    const float* gam   = (const float*)d_in[12];
    const float* bet   = (const float*)d_in[13];
    const float* mea   = (const float*)d_in[14];
    const float* var   = (const float*)d_in[15];
    const float* W1b   = (const float*)d_in[16];
    const float* b1b   = (const float*)d_in[17];
    const float* W_out = (const float*)d_in[18];
    const float* b_out = (const float*)d_in[19];

    char* wsb = (char*)d_ws;
    const long MB = 1024 * 1024;
    float*   conv2 = (float*)wsb;
    ushort2* Qb    = (ushort2*)(wsb + 32 * MB);
    ushort2* Kb    = (ushort2*)(wsb + 64 * MB);
    ushort2* Vb    = (ushort2*)(wsb + 96 * MB);
    ushort2* Tb    = (ushort2*)(wsb + 128 * MB);
    bf16*    Wt    = (bf16*)(wsb + 160 * MB);
    bf16* WT_in  = Wt;
    bf16* WT_q   = Wt + 262144;
    bf16* WT_k   = Wt + 2 * 262144;
    bf16* WT_v   = Wt + 3 * 262144;
    bf16* WT_1a  = Wt + 4 * 262144;
    bf16* WT_1b  = Wt + 5 * 262144;
    bf16* WT_out = Wt + 6 * 262144;
    float*   outF  = (float*)Qb;
    float*   g1    = (float*)Kb;
    float*   outL  = (float*)Kb;
    float*   g2    = (float*)Vb;
    float*   out2  = (float*)Vb;

    const dim3 tgrid(16, 16), tblk(32, 8);
    const dim3 ggrid(4, 128), gblk(256);
    const int LINES = 16384;
    const int CB = 4096;            // 32 b * 128 col-groups
    const int EW = 32768;

    transpose_cvt<<<tgrid, tblk, 0, stream>>>(W_in, WT_in, 512, 512);
    transpose_cvt<<<tgrid, tblk, 0, stream>>>(W_q,  WT_q,  512, 512);
    transpose_cvt<<<tgrid, tblk, 0, stream>>>(W_k,  WT_k,  512, 512);
    transpose_cvt<<<tgrid, tblk, 0, stream>>>(W_v,  WT_v,  512, 512);
    transpose_cvt<<<tgrid, tblk, 0, stream>>>(W1a,  WT_1a, 512, 512);
    transpose_cvt<<<tgrid, tblk, 0, stream>>>(W1b,  WT_1b, 512, 512);
    transpose_cvt<<<dim3(16, 32), tblk, 0, stream>>>(W_out, WT_out, 1024, 512);

    // 1. conv2 = x @ W_in + b_in
    mfma_gemm<<<ggrid, gblk, 0, stream>>>(x, 1, 512, WT_in, 512, b_in,
                                          conv2, 0, 512, 512, 0);

    // 2-4. q/k/v projections + fft2
    mfma_gemm<<<ggrid, gblk, 0, stream>>>(conv2, 1, 512, WT_q, 512, b_q,
                                          Qb, 2, 512, 512, 0);
    fft_rows_c2c_bf16<<<LINES, 256, 0, stream>>>(Qb, -1.f);
    fft_cols4_c2c_bf16<<<CB, 256, 0, stream>>>(Qb, -1.f);

    mfma_gemm<<<ggrid, gblk, 0, stream>>>(conv2, 1, 512, WT_k, 512, b_k,
                                          Kb, 2, 512, 512, 0);
    fft_rows_c2c_bf16<<<LINES, 256, 0, stream>>>(Kb, -1.f);
    fft_cols4_c2c_bf16<<<CB, 256, 0, stream>>>(Kb, -1.f);

    mfma_gemm<<<ggrid, gblk, 0, stream>>>(conv2, 1, 512, WT_v, 512, b_v,
                                          Vb, 2, 512, 512, 0);
    fft_rows_c2c_bf16<<<LINES, 256, 0, stream>>>(Vb, -1.f);
    fft_cols4_c2c_bf16<<<CB, 256, 0, stream>>>(Vb, -1.f);

    // 5. attention -> out_f f32 over Qb
    attn_kernel<<<LINES, 64, 0, stream>>>(Qb, Kb, Vb, temp, outF);

    // 6. tep = fft2(conv2) -> Tb
    fft_rows_r2c_f32<<<LINES, 256, 0, stream>>>(conv2, Tb, -1.f);
    fft_cols4_c2c_bf16<<<CB, 256, 0, stream>>>(Tb, -1.f);

    // 7-9. gated branch
    mfma_gemm<<<ggrid, gblk, 0, stream>>>(Tb, 2, 512, WT_1a, 512, b1a,
                                          g1, 0, 512, 512, 0);
    bn_relu_kernel<<<EW, 256, 0, stream>>>(g1, gam, bet, mea, var);
    mfma_gemm<<<ggrid, gblk, 0, stream>>>(g1, 1, 512, WT_1b, 512, b1b,
                                          g2, 0, 512, 512, 0);

    // 10-11. gated ifft2 + abs -> out_l
    fft_rows_gated<<<LINES, 256, 0, stream>>>(g2, Tb);
    fft_cols4_abs<<<CB, 256, 0, stream>>>(Tb, outL);

    // 12. out2 = out_f @ W_out[:512] + out_l @ W_out[512:] + b_out
    mfma_gemm<<<ggrid, gblk, 0, stream>>>(outF, 1, 512, WT_out, 1024, b_out,
                                          out2, 0, 512, 512, 0);
    mfma_gemm<<<ggrid, gblk, 0, stream>>>(outL, 1, 512, WT_out + 512, 1024, nullptr,
                                          out2, 0, 512, 512, 1);

    // 13. d_out = out2 + conv2
    addstore_kernel<<<EW, 256, 0, stream>>>(out2, conv2, (float*)d_out);
}

// Round 6
// 1029.148 us; speedup vs baseline: 2.8736x; 1.1084x over previous
//
#include <hip/hip_runtime.h>
#include <hip/hip_bf16.h>

#define FFT_PI 3.14159265358979323846f

typedef __hip_bfloat16 bf16;
typedef short bf8_t __attribute__((ext_vector_type(8)));
typedef float f4_t __attribute__((ext_vector_type(4)));

__device__ inline float bf2f(unsigned short u) {
    union { unsigned int i; float f; } v; v.i = ((unsigned int)u) << 16; return v.f;
}
__device__ inline unsigned short f2bf(float f) {
    bf16 h = __float2bfloat16(f);
    union { bf16 h; unsigned short u; } v; v.h = h; return v.u;
}
__device__ inline float2 c_load(const ushort2* p) {
    ushort2 u = *p;
    return make_float2(bf2f(u.x), bf2f(u.y));
}
__device__ inline void c_store(ushort2* p, float2 z) {
    ushort2 u; u.x = f2bf(z.x); u.y = f2bf(z.y); *p = u;
}
__device__ inline int brev6(int t) {
    return ((t & 1) << 5) | ((t & 2) << 3) | ((t & 4) << 1) |
           ((t & 8) >> 1) | ((t & 16) >> 3) | ((t & 32) >> 5);
}

// ---------------------------------------------------------------------------
// Transpose + f32->bf16 convert: src f32 [R][C] -> dst bf16 [C][R].
// ---------------------------------------------------------------------------
__global__ __launch_bounds__(256) void transpose_cvt(
    const float* __restrict__ src, bf16* __restrict__ dst, int R, int C)
{
    __shared__ float tile[32][33];
    const int bx = blockIdx.x * 32;
    const int by = blockIdx.y * 32;
    const int tx = threadIdx.x, ty = threadIdx.y;
#pragma unroll
    for (int i = 0; i < 32; i += 8)
        tile[ty + i][tx] = src[(long)(by + ty + i) * C + bx + tx];
    __syncthreads();
#pragma unroll
    for (int i = 0; i < 32; i += 8)
        dst[(long)(bx + ty + i) * R + by + tx] = __float2bfloat16(tile[tx][ty + i]);
}

// ---------------------------------------------------------------------------
// MFMA bf16 GEMM, tile 128x128, BK=32, 4 waves.
// A source: a_type 0 = bf16 [m][k]; 1 = f32 [m][k]; 2 = cplx-bf16 real part.
//   Two A buffers: k < ksplit reads Av, else Av2 at (k - ksplit). lda shared.
// B: bf16 transposed [n][k], ldb = k-stride. For multi-output (fused QKV),
//   n-tiles are grouped per `nper` cols: sel = n0/nper picks C/bias pointer.
// out_type: 0 f32 | 1 bf16 | 2 cplx-bf16 (imag 0) | 3 BN+ReLU->bf16
//   (e0..e3 = mean,var,gamma,beta indexed by m&511) | 4 residual: +=bf16
//   res (e0) -> f32.
// ---------------------------------------------------------------------------
__global__ __launch_bounds__(256) void mfma_gemm(
    const void* __restrict__ Av, const void* __restrict__ Av2,
    int a_type, int lda, int ksplit,
    const bf16* __restrict__ Bt, int ldb,
    const float* __restrict__ bias0, const float* __restrict__ bias1,
    const float* __restrict__ bias2,
    void* __restrict__ C0, void* __restrict__ C1, void* __restrict__ C2,
    int nper, int out_type, int ldc, int K,
    const float* __restrict__ e0, const float* __restrict__ e1,
    const float* __restrict__ e2, const float* __restrict__ e3)
{
    __shared__ short Asub[128 * 40];
    __shared__ short Bsub[128 * 40];

    const int tid = threadIdx.x;
    const int n0 = blockIdx.x * 128;
    const int m0 = blockIdx.y * 128;
    const int l  = tid & 63;
    const int wv = tid >> 6;
    const int wm = wv & 1, wn = wv >> 1;

    f4_t acc[4][4];
#pragma unroll
    for (int i = 0; i < 4; i++)
#pragma unroll
        for (int j = 0; j < 4; j++)
            acc[i][j] = (f4_t)0.f;

    const int srow = tid >> 2;
    const int sc8  = (tid & 3) * 8;

    for (int k0 = 0; k0 < K; k0 += 32) {
        const void* As = (k0 < ksplit) ? Av : Av2;
        const int kk = (k0 < ksplit) ? k0 : (k0 - ksplit);
#pragma unroll
        for (int p = 0; p < 2; p++) {
            const int row = srow + p * 64;
            bf8_t av;
            if (a_type == 0) {
                av = *(const bf8_t*)((const bf16*)As
                    + (long)(m0 + row) * lda + kk + sc8);
            } else if (a_type == 1) {
                const float4* src = (const float4*)((const float*)As
                    + (long)(m0 + row) * lda + kk + sc8);
                float4 u0 = src[0], u1 = src[1];
                av[0] = (short)f2bf(u0.x); av[1] = (short)f2bf(u0.y);
                av[2] = (short)f2bf(u0.z); av[3] = (short)f2bf(u0.w);
                av[4] = (short)f2bf(u1.x); av[5] = (short)f2bf(u1.y);
                av[6] = (short)f2bf(u1.z); av[7] = (short)f2bf(u1.w);
            } else {
                const ushort2* src = (const ushort2*)As
                    + (long)(m0 + row) * lda + kk + sc8;
#pragma unroll
                for (int j = 0; j < 8; j++) av[j] = (short)src[j].x;
            }
            *(bf8_t*)&Asub[row * 40 + sc8] = av;

            bf8_t bv = *(const bf8_t*)(Bt + (long)(n0 + row) * ldb + k0 + sc8);
            *(bf8_t*)&Bsub[row * 40 + sc8] = bv;
        }
        __syncthreads();

        bf8_t a_frag[4], b_frag[4];
        const int ko = (l >> 4) * 8;
        const int lr = l & 15;
#pragma unroll
        for (int fm = 0; fm < 4; fm++)
            a_frag[fm] = *(bf8_t*)&Asub[(wm * 64 + fm * 16 + lr) * 40 + ko];
#pragma unroll
        for (int fn = 0; fn < 4; fn++)
            b_frag[fn] = *(bf8_t*)&Bsub[(wn * 64 + fn * 16 + lr) * 40 + ko];
#pragma unroll
        for (int fm = 0; fm < 4; fm++)
#pragma unroll
            for (int fn = 0; fn < 4; fn++)
                acc[fm][fn] = __builtin_amdgcn_mfma_f32_16x16x32_bf16(
                    b_frag[fn], a_frag[fm], acc[fm][fn], 0, 0, 0);
        __syncthreads();
    }

    const int sel = n0 / nper;
    const int nb  = sel * nper;
    const float* biasl = (sel == 0) ? bias0 : ((sel == 1) ? bias1 : bias2);
    void* Cl = (sel == 0) ? C0 : ((sel == 1) ? C1 : C2);

    const int em = m0 + wm * 64 + (l & 15);
    const int en = n0 + wn * 64 + ((l >> 4) << 2);
#pragma unroll
    for (int fm = 0; fm < 4; fm++) {
        const long m = em + fm * 16;
        float bnm = 0.f, bnr = 1.f, bng = 1.f, bnb = 0.f;
        if (out_type == 3) {
            const int c = (int)(m & 511);
            bnm = e0[c];
            bnr = 1.0f / sqrtf(e1[c] + 1e-5f);
            bng = e2[c];
            bnb = e3[c];
        }
#pragma unroll
        for (int fn = 0; fn < 4; fn++) {
            const int n = en + fn * 16;
            const int nl = n - nb;
            f4_t v = acc[fm][fn];
            if (biasl) {
#pragma unroll
                for (int r = 0; r < 4; r++) v[r] += biasl[nl + r];
            }
            if (out_type == 0) {
                float4 o; o.x = v[0]; o.y = v[1]; o.z = v[2]; o.w = v[3];
                *(float4*)((float*)Cl + m * ldc + nl) = o;
            } else if (out_type == 1) {
                union { unsigned short u[4]; ushort4 q; } o;
#pragma unroll
                for (int r = 0; r < 4; r++) o.u[r] = f2bf(v[r]);
                *(ushort4*)((bf16*)Cl + m * ldc + nl) = o.q;
            } else if (out_type == 2) {
                union { ushort2 u2[4]; uint4 q; } o;
#pragma unroll
                for (int r = 0; r < 4; r++) { o.u2[r].x = f2bf(v[r]); o.u2[r].y = 0; }
                *(uint4*)((ushort2*)Cl + m * ldc + nl) = o.q;
            } else if (out_type == 3) {
                union { unsigned short u[4]; ushort4 q; } o;
#pragma unroll
                for (int r = 0; r < 4; r++)
                    o.u[r] = f2bf(fmaxf((v[r] - bnm) * bnr * bng + bnb, 0.f));
                *(ushort4*)((bf16*)Cl + m * ldc + nl) = o.q;
            } else {
                union { unsigned short u[4]; ushort4 q; } rsd;
                rsd.q = *(const ushort4*)((const unsigned short*)e0 + m * ldc + nl);
                float4 o;
                o.x = v[0] + bf2f(rsd.u[0]);
                o.y = v[1] + bf2f(rsd.u[1]);
                o.z = v[2] + bf2f(rsd.u[2]);
                o.w = v[3] + bf2f(rsd.u[3]);
                *(float4*)((float*)Cl + m * ldc + nl) = o;
            }
        }
    }
}

// ---------------------------------------------------------------------------
// 512-point radix-2 Stockham FFT in LDS (row kernels).
// ---------------------------------------------------------------------------
__device__ inline float2* fft512_lds(float2* bx, float2* by, int t, float sign)
{
    int ls = 0;
    for (int n = 512; n >= 2; n >>= 1) {
        const int m = n >> 1;
        const int s = 1 << ls;
        const int p = t >> ls;
        const int q = t & (s - 1);
        float2 a = bx[q + s * p];
        float2 b = bx[q + s * (p + m)];
        float ang = sign * (2.0f * FFT_PI) * (float)p / (float)n;
        float sw, cw;
        __sincosf(ang, &sw, &cw);
        float2 sum = make_float2(a.x + b.x, a.y + b.y);
        float2 dif = make_float2(a.x - b.x, a.y - b.y);
        float2 tw  = make_float2(dif.x * cw - dif.y * sw, dif.x * sw + dif.y * cw);
        by[q + s * (2 * p)]     = sum;
        by[q + s * (2 * p + 1)] = tw;
        __syncthreads();
        float2* tmp = bx; bx = by; by = tmp;
        ls++;
    }
    return bx;
}

__global__ __launch_bounds__(256) void fft_rows_c2c_bf16(
    ushort2* __restrict__ data, float sign)
{
    __shared__ float2 b0[512], b1[512];
    ushort2* s = data + (long)blockIdx.x * 512;
    const int t = threadIdx.x;
    b0[t]       = c_load(s + t);
    b0[t + 256] = c_load(s + t + 256);
    __syncthreads();
    float2* r = fft512_lds(b0, b1, t, sign);
    c_store(s + t,       r[t]);
    c_store(s + t + 256, r[t + 256]);
}

// real bf16 source -> cplx-bf16 dst, row FFT
__global__ __launch_bounds__(256) void fft_rows_r2c_bf16src(
    const bf16* __restrict__ src, ushort2* __restrict__ dst, float sign)
{
    __shared__ float2 b0[512], b1[512];
    const long line = blockIdx.x;
    const int t = threadIdx.x;
    const bf16* s = src + line * 512;
    b0[t]       = make_float2(__bfloat162float(s[t]), 0.f);
    b0[t + 256] = make_float2(__bfloat162float(s[t + 256]), 0.f);
    __syncthreads();
    float2* r = fft512_lds(b0, b1, t, sign);
    ushort2* d = dst + line * 512;
    c_store(d + t,       r[t]);
    c_store(d + t + 256, r[t + 256]);
}

// gated row inverse FFT: z = sigmoid(g2)*tep (g2 bf16), scale 1/512, in place
__global__ __launch_bounds__(256) void fft_rows_gated(
    const bf16* __restrict__ g2, ushort2* __restrict__ tep)
{
    __shared__ float2 b0[512], b1[512];
    const long line = blockIdx.x;
    const int t = threadIdx.x;
    ushort2* s = tep + line * 512;
    const bf16* g = g2 + line * 512;
#pragma unroll
    for (int o = 0; o < 2; o++) {
        const int i = t + o * 256;
        float sg = 1.0f / (1.0f + __expf(-__bfloat162float(g[i])));
        float2 z = c_load(s + i);
        b0[i] = make_float2(sg * z.x, sg * z.y);
    }
    __syncthreads();
    float2* r = fft512_lds(b0, b1, t, +1.f);
    const float sc = 1.0f / 512.0f;
    c_store(s + t,       make_float2(r[t].x * sc, r[t].y * sc));
    c_store(s + t + 256, make_float2(r[t + 256].x * sc, r[t + 256].y * sc));
}

// ---------------------------------------------------------------------------
// Column FFT, 4 columns per block (as R5).
// ---------------------------------------------------------------------------
__global__ __launch_bounds__(256) void fft_cols4_c2c_bf16(
    ushort2* __restrict__ data, float sign)
{
    __shared__ float2 bA[4][514], bB[4][514];
    const int b  = blockIdx.x >> 7;
    const int c0 = (blockIdx.x & 127) * 4;
    ushort2* base = data + (long)b * 262144 + c0;
    const int t = threadIdx.x;

#pragma unroll
    for (int rr = 0; rr < 2; rr++) {
        const int row = 2 * t + rr;
        uint4 raw = *(const uint4*)(base + (long)row * 512);
        const ushort2* p = (const ushort2*)&raw;
#pragma unroll
        for (int j = 0; j < 4; j++) bA[j][row] = c_load(p + j);
    }
    __syncthreads();

    float2 (*bx)[514] = bA;
    float2 (*by)[514] = bB;
    int ls = 0;
    for (int n = 512; n >= 2; n >>= 1) {
        const int m = n >> 1;
        const int s = 1 << ls;
        const int p = t >> ls;
        const int q = t & (s - 1);
        float ang = sign * (2.0f * FFT_PI) * (float)p / (float)n;
        float sw, cw;
        __sincosf(ang, &sw, &cw);
        const int i0 = q + s * p, i1 = q + s * (p + m);
        const int o0 = q + s * (2 * p), o1 = q + s * (2 * p + 1);
#pragma unroll
        for (int j = 0; j < 4; j++) {
            float2 a = bx[j][i0];
            float2 bb = bx[j][i1];
            by[j][o0] = make_float2(a.x + bb.x, a.y + bb.y);
            float2 dif = make_float2(a.x - bb.x, a.y - bb.y);
            by[j][o1] = make_float2(dif.x * cw - dif.y * sw, dif.x * sw + dif.y * cw);
        }
        __syncthreads();
        float2 (*tmp)[514] = bx; bx = by; by = tmp;
        ls++;
    }

#pragma unroll
    for (int rr = 0; rr < 2; rr++) {
        const int row = 2 * t + rr;
        union { ushort2 u2[4]; uint4 q; } o;
#pragma unroll
        for (int j = 0; j < 4; j++) {
            float2 z = bx[j][row];
            o.u2[j].x = f2bf(z.x); o.u2[j].y = f2bf(z.y);
        }
        *(uint4*)(base + (long)row * 512) = o.q;
    }
}

// Column inverse FFT + abs -> bf16 real, 4 columns per block (scale 1/512).
__global__ __launch_bounds__(256) void fft_cols4_abs(
    const ushort2* __restrict__ src, bf16* __restrict__ dst)
{
    __shared__ float2 bA[4][514], bB[4][514];
    const int b  = blockIdx.x >> 7;
    const int c0 = (blockIdx.x & 127) * 4;
    const ushort2* base = src + (long)b * 262144 + c0;
    const int t = threadIdx.x;

#pragma unroll
    for (int rr = 0; rr < 2; rr++) {
        const int row = 2 * t + rr;
        uint4 raw = *(const uint4*)(base + (long)row * 512);
        const ushort2* p = (const ushort2*)&raw;
#pragma unroll
        for (int j = 0; j < 4; j++) bA[j][row] = c_load(p + j);
    }
    __syncthreads();

    float2 (*bx)[514] = bA;
    float2 (*by)[514] = bB;
    int ls = 0;
    for (int n = 512; n >= 2; n >>= 1) {
        const int m = n >> 1;
        const int s = 1 << ls;
        const int p = t >> ls;
        const int q = t & (s - 1);
        float ang = (2.0f * FFT_PI) * (float)p / (float)n;
        float sw, cw;
        __sincosf(ang, &sw, &cw);
        const int i0 = q + s * p, i1 = q + s * (p + m);
        const int o0 = q + s * (2 * p), o1 = q + s * (2 * p + 1);
#pragma unroll
        for (int j = 0; j < 4; j++) {
            float2 a = bx[j][i0];
            float2 bb = bx[j][i1];
            by[j][o0] = make_float2(a.x + bb.x, a.y + bb.y);
            float2 dif = make_float2(a.x - bb.x, a.y - bb.y);
            by[j][o1] = make_float2(dif.x * cw - dif.y * sw, dif.x * sw + dif.y * cw);
        }
        __syncthreads();
        float2 (*tmp)[514] = bx; bx = by; by = tmp;
        ls++;
    }

    const float sc = 1.0f / 512.0f;
#pragma unroll
    for (int rr = 0; rr < 2; rr++) {
        const int row = 2 * t + rr;
        union { unsigned short u[4]; ushort4 q; } o;
#pragma unroll
        for (int j = 0; j < 4; j++) {
            float2 z = bx[j][row];
            o.u[j] = f2bf(sqrtf(z.x * z.x + z.y * z.y) * sc);
        }
        *(ushort4*)(dst + (long)b * 262144 + (long)row * 512 + c0) = o.q;
    }
}

// ---------------------------------------------------------------------------
// attn v2 (R5 core), output now bf16 (written over own qf chunk).
// ---------------------------------------------------------------------------
__global__ __launch_bounds__(64) void attn_kernel(
    const ushort2* __restrict__ qf, const ushort2* __restrict__ kf,
    const ushort2* __restrict__ vf, const float* __restrict__ temp,
    bf16* __restrict__ out_f)
{
    __shared__ float2 QS[8][66];
    __shared__ float2 KS[8][66];
    __shared__ float2 ATT[8][9];

    const int bc = blockIdx.x;
    const int t = threadIdx.x;
    const long base = (long)bc * 512;

    float2 q[8], k[8], v[8];
#pragma unroll
    for (int h = 0; h < 8; h++) {
        q[h] = c_load(qf + base + h * 64 + t);
        k[h] = c_load(kf + base + h * 64 + t);
        v[h] = c_load(vf + base + h * 64 + t);
    }

#pragma unroll
    for (int h = 0; h < 8; h++) {
        float pq = q[h].x * q[h].x + q[h].y * q[h].y;
        float pk = k[h].x * k[h].x + k[h].y * k[h].y;
#pragma unroll
        for (int o = 32; o > 0; o >>= 1) {
            pq += __shfl_xor(pq, o, 64);
            pk += __shfl_xor(pk, o, 64);
        }
        float iq = 1.0f / fmaxf(sqrtf(pq), 1e-12f);
        float ik = 1.0f / fmaxf(sqrtf(pk), 1e-12f);
        q[h].x *= iq; q[h].y *= iq;
        k[h].x *= ik; k[h].y *= ik;
        QS[h][t] = q[h];
        KS[h][t] = k[h];
    }
    __syncthreads();

    {
        const int h = t >> 3, g = t & 7;
        float ar = 0.f, ai = 0.f;
        for (int w = 0; w < 64; w++) {
            float2 a = QS[h][w], b = KS[g][w];
            ar += a.x * b.x - a.y * b.y;
            ai += a.x * b.y + a.y * b.x;
        }
        float tm = temp[h];
        ATT[h][g] = make_float2(ar * tm, ai * tm);
    }
    __syncthreads();

    if (t < 8) {
        const int h = t;
        float mr = -1e30f, mi = -1e30f;
        for (int g = 0; g < 8; g++) {
            mr = fmaxf(mr, ATT[h][g].x);
            mi = fmaxf(mi, ATT[h][g].y);
        }
        float er[8], ei[8];
        float sr = 0.f, si = 0.f;
        for (int g = 0; g < 8; g++) {
            er[g] = __expf(ATT[h][g].x - mr); sr += er[g];
            ei[g] = __expf(ATT[h][g].y - mi); si += ei[g];
        }
        float isr = 1.f / sr, isi = 1.f / si;
        for (int g = 0; g < 8; g++)
            ATT[h][g] = make_float2(er[g] * isr, ei[g] * isi);
    }
    __syncthreads();

    float2 o[8];
#pragma unroll
    for (int h = 0; h < 8; h++) {
        float orr = 0.f, oi = 0.f;
#pragma unroll
        for (int g = 0; g < 8; g++) {
            float2 a = ATT[h][g], b = v[g];
            orr += a.x * b.x - a.y * b.y;
            oi  += a.x * b.y + a.y * b.x;
        }
        o[h] = make_float2(orr, oi);
    }

#pragma unroll
    for (int m = 32; m >= 1; m >>= 1) {
        float ang = (FFT_PI / (float)m) * (float)(t & (m - 1));
        float sw, cw;
        __sincosf(ang, &sw, &cw);
        const bool low = (t & m) == 0;
#pragma unroll
        for (int h = 0; h < 8; h++) {
            float px = __shfl_xor(o[h].x, m, 64);
            float py = __shfl_xor(o[h].y, m, 64);
            float nx, ny;
            if (low) {
                nx = o[h].x + px;
                ny = o[h].y + py;
            } else {
                float dx = px - o[h].x;
                float dy = py - o[h].y;
                nx = dx * cw - dy * sw;
                ny = dx * sw + dy * cw;
            }
            o[h].x = nx; o[h].y = ny;
        }
    }
    const int wr = brev6(t);

    const float r2 = 0.70710678118654752f;
    const float W8x[8] = {1.f,  r2, 0.f, -r2, -1.f, -r2,  0.f,  r2};
    const float W8y[8] = {0.f,  r2, 1.f,  r2,  0.f, -r2, -1.f, -r2};
    bf16* outp = out_f + base;
#pragma unroll
    for (int kh = 0; kh < 8; kh++) {
        float sr = 0.f, si = 0.f;
#pragma unroll
        for (int n = 0; n < 8; n++) {
            const int idx = (n * kh) & 7;
            float wx = W8x[idx], wy = W8y[idx];
            sr += o[n].x * wx - o[n].y * wy;
            si += o[n].x * wy + o[n].y * wx;
        }
        outp[kh * 64 + wr] =
            __float2bfloat16(sqrtf(sr * sr + si * si) * (1.0f / 512.0f));
    }
}

// ---------------------------------------------------------------------------
extern "C" void kernel_launch(void* const* d_in, const int* in_sizes, int n_in,
                              void* d_out, int out_size, void* d_ws, size_t ws_size,
                              hipStream_t stream)
{
    const float* x     = (const float*)d_in[0];
    const float* W_in  = (const float*)d_in[1];
    const float* b_in  = (const float*)d_in[2];
    const float* W_q   = (const float*)d_in[3];
    const float* b_q   = (const float*)d_in[4];
    const float* W_k   = (const float*)d_in[5];
    const float* b_k   = (const float*)d_in[6];
    const float* W_v   = (const float*)d_in[7];
    const float* b_v   = (const float*)d_in[8];
    const float* temp  = (const float*)d_in[9];
    const float* W1a   = (const float*)d_in[10];
    const float* b1a   = (const float*)d_in[11];
    const float* gam   = (const float*)d_in[12];
    const float* bet   = (const float*)d_in[13];
    const float* mea   = (const float*)d_in[14];
    const float* var   = (const float*)d_in[15];
    const float* W1b   = (const float*)d_in[16];
    const float* b1b   = (const float*)d_in[17];
    const float* W_out = (const float*)d_in[18];
    const float* b_out = (const float*)d_in[19];

    // Workspace:
    //   [  0, 32) conv2 bf16 (16 MB used)
    //   [ 32, 64) q_f cplx-bf16 -> out_f bf16 (attn, in place)
    //   [ 64, 96) k_f -> g1 bf16 -> out_l bf16
    //   [ 96,128) v_f -> g2 bf16
    //   [128,160) tep cplx-bf16 (gated ifft in place)
    //   [160,165) transposed bf16 weights (WT_q/k/v contiguous = [1536][512])
    char* wsb = (char*)d_ws;
    const long MB = 1024 * 1024;
    bf16*    conv2b = (bf16*)wsb;
    ushort2* Qb    = (ushort2*)(wsb + 32 * MB);
    ushort2* Kb    = (ushort2*)(wsb + 64 * MB);
    ushort2* Vb    = (ushort2*)(wsb + 96 * MB);
    ushort2* Tb    = (ushort2*)(wsb + 128 * MB);
    bf16*    Wt    = (bf16*)(wsb + 160 * MB);
    bf16* WT_in  = Wt;
    bf16* WT_q   = Wt + 262144;
    bf16* WT_k   = Wt + 2 * 262144;
    bf16* WT_v   = Wt + 3 * 262144;
    bf16* WT_1a  = Wt + 4 * 262144;
    bf16* WT_1b  = Wt + 5 * 262144;
    bf16* WT_out = Wt + 6 * 262144;
    bf16* outF = (bf16*)Qb;
    bf16* g1b  = (bf16*)Kb;
    bf16* outL = (bf16*)Kb;
    bf16* g2b  = (bf16*)Vb;

    const dim3 tgrid(16, 16), tblk(32, 8);
    const dim3 ggrid(4, 128), gblk(256);
    const int BIG = 1 << 30;
    const int LINES = 16384;
    const int CB = 4096;

    transpose_cvt<<<tgrid, tblk, 0, stream>>>(W_in, WT_in, 512, 512);
    transpose_cvt<<<tgrid, tblk, 0, stream>>>(W_q,  WT_q,  512, 512);
    transpose_cvt<<<tgrid, tblk, 0, stream>>>(W_k,  WT_k,  512, 512);
    transpose_cvt<<<tgrid, tblk, 0, stream>>>(W_v,  WT_v,  512, 512);
    transpose_cvt<<<tgrid, tblk, 0, stream>>>(W1a,  WT_1a, 512, 512);
    transpose_cvt<<<tgrid, tblk, 0, stream>>>(W1b,  WT_1b, 512, 512);
    transpose_cvt<<<dim3(16, 32), tblk, 0, stream>>>(W_out, WT_out, 1024, 512);

    // 1. conv2 = x @ W_in + b_in -> bf16
    mfma_gemm<<<ggrid, gblk, 0, stream>>>(
        x, x, 1, 512, BIG, WT_in, 512, b_in, nullptr, nullptr,
        conv2b, nullptr, nullptr, BIG, 1, 512, 512,
        nullptr, nullptr, nullptr, nullptr);

    // 2. fused q/k/v projections (one dispatch, 3 outputs), then fft2 each
    mfma_gemm<<<dim3(12, 128), gblk, 0, stream>>>(
        conv2b, conv2b, 0, 512, BIG, WT_q, 512, b_q, b_k, b_v,
        Qb, Kb, Vb, 512, 2, 512, 512,
        nullptr, nullptr, nullptr, nullptr);
    fft_rows_c2c_bf16<<<LINES, 256, 0, stream>>>(Qb, -1.f);
    fft_cols4_c2c_bf16<<<CB, 256, 0, stream>>>(Qb, -1.f);
    fft_rows_c2c_bf16<<<LINES, 256, 0, stream>>>(Kb, -1.f);
    fft_cols4_c2c_bf16<<<CB, 256, 0, stream>>>(Kb, -1.f);
    fft_rows_c2c_bf16<<<LINES, 256, 0, stream>>>(Vb, -1.f);
    fft_cols4_c2c_bf16<<<CB, 256, 0, stream>>>(Vb, -1.f);

    // 3. attention -> out_f bf16 over Qb
    attn_kernel<<<LINES, 64, 0, stream>>>(Qb, Kb, Vb, temp, outF);

    // 4. tep = fft2(conv2) -> Tb
    fft_rows_r2c_bf16src<<<LINES, 256, 0, stream>>>(conv2b, Tb, -1.f);
    fft_cols4_c2c_bf16<<<CB, 256, 0, stream>>>(Tb, -1.f);

    // 5. g1 = BN_ReLU(tep.real @ W1a + b1a) -> bf16 (fused epilogue)
    mfma_gemm<<<ggrid, gblk, 0, stream>>>(
        Tb, Tb, 2, 512, BIG, WT_1a, 512, b1a, nullptr, nullptr,
        g1b, nullptr, nullptr, BIG, 3, 512, 512,
        mea, var, gam, bet);

    // 6. g2 = g1 @ W1b + b1b -> bf16
    mfma_gemm<<<ggrid, gblk, 0, stream>>>(
        g1b, g1b, 0, 512, BIG, WT_1b, 512, b1b, nullptr, nullptr,
        g2b, nullptr, nullptr, BIG, 1, 512, 512,
        nullptr, nullptr, nullptr, nullptr);

    // 7. gated ifft2 + abs -> out_l bf16 (over Kb)
    fft_rows_gated<<<LINES, 256, 0, stream>>>(g2b, Tb);
    fft_cols4_abs<<<CB, 256, 0, stream>>>(Tb, outL);

    // 8. d_out = [out_f | out_l] @ W_out + b_out + conv2  (K=1024, fused residual)
    mfma_gemm<<<ggrid, gblk, 0, stream>>>(
        outF, outL, 0, 512, 512, WT_out, 1024, b_out, nullptr, nullptr,
        d_out, nullptr, nullptr, BIG, 4, 512, 1024,
        (const float*)conv2b, nullptr, nullptr, nullptr);
}

// Round 7
// 929.760 us; speedup vs baseline: 3.1807x; 1.1069x over previous
//
#include <hip/hip_runtime.h>
#include <hip/hip_bf16.h>

#define FFT_PI 3.14159265358979323846f
#define FOFF(i) ((i) + ((i) >> 3))   // padded LDS offset (max 574 < 576)

typedef __hip_bfloat16 bf16;
typedef short bf8_t __attribute__((ext_vector_type(8)));
typedef float f4_t __attribute__((ext_vector_type(4)));

__device__ inline float bf2f(unsigned short u) {
    union { unsigned int i; float f; } v; v.i = ((unsigned int)u) << 16; return v.f;
}
__device__ inline unsigned short f2bf(float f) {
    bf16 h = __float2bfloat16(f);
    union { bf16 h; unsigned short u; } v; v.h = h; return v.u;
}
__device__ inline float2 c_load(const ushort2* p) {
    ushort2 u = *p;
    return make_float2(bf2f(u.x), bf2f(u.y));
}
__device__ inline int brev6(int t) {
    return ((t & 1) << 5) | ((t & 2) << 3) | ((t & 4) << 1) |
           ((t & 8) >> 1) | ((t & 16) >> 3) | ((t & 32) >> 5);
}
__device__ inline float2 cadd(float2 a, float2 b){ return make_float2(a.x+b.x, a.y+b.y); }
__device__ inline float2 csub(float2 a, float2 b){ return make_float2(a.x-b.x, a.y-b.y); }
__device__ inline float2 cmul(float2 a, float2 b){
    return make_float2(a.x*b.x - a.y*b.y, a.x*b.y + a.y*b.x);
}
__device__ inline float2 cmuli(float2 a, float s){ return make_float2(-s*a.y, s*a.x); }

// ---------------------------------------------------------------------------
// Transpose + f32->bf16 convert: src f32 [R][C] -> dst bf16 [C][R].
// ---------------------------------------------------------------------------
__global__ __launch_bounds__(256) void transpose_cvt(
    const float* __restrict__ src, bf16* __restrict__ dst, int R, int C)
{
    __shared__ float tile[32][33];
    const int bx = blockIdx.x * 32;
    const int by = blockIdx.y * 32;
    const int tx = threadIdx.x, ty = threadIdx.y;
#pragma unroll
    for (int i = 0; i < 32; i += 8)
        tile[ty + i][tx] = src[(long)(by + ty + i) * C + bx + tx];
    __syncthreads();
#pragma unroll
    for (int i = 0; i < 32; i += 8)
        dst[(long)(bx + ty + i) * R + by + tx] = __float2bfloat16(tile[tx][ty + i]);
}

// ---------------------------------------------------------------------------
// MFMA bf16 GEMM (unchanged from R6). Tile 128x128, BK=32, 4 waves.
// ---------------------------------------------------------------------------
__global__ __launch_bounds__(256) void mfma_gemm(
    const void* __restrict__ Av, const void* __restrict__ Av2,
    int a_type, int lda, int ksplit,
    const bf16* __restrict__ Bt, int ldb,
    const float* __restrict__ bias0, const float* __restrict__ bias1,
    const float* __restrict__ bias2,
    void* __restrict__ C0, void* __restrict__ C1, void* __restrict__ C2,
    int nper, int out_type, int ldc, int K,
    const float* __restrict__ e0, const float* __restrict__ e1,
    const float* __restrict__ e2, const float* __restrict__ e3)
{
    __shared__ short Asub[128 * 40];
    __shared__ short Bsub[128 * 40];

    const int tid = threadIdx.x;
    const int n0 = blockIdx.x * 128;
    const int m0 = blockIdx.y * 128;
    const int l  = tid & 63;
    const int wv = tid >> 6;
    const int wm = wv & 1, wn = wv >> 1;

    f4_t acc[4][4];
#pragma unroll
    for (int i = 0; i < 4; i++)
#pragma unroll
        for (int j = 0; j < 4; j++)
            acc[i][j] = (f4_t)0.f;

    const int srow = tid >> 2;
    const int sc8  = (tid & 3) * 8;

    for (int k0 = 0; k0 < K; k0 += 32) {
        const void* As = (k0 < ksplit) ? Av : Av2;
        const int kk = (k0 < ksplit) ? k0 : (k0 - ksplit);
#pragma unroll
        for (int p = 0; p < 2; p++) {
            const int row = srow + p * 64;
            bf8_t av;
            if (a_type == 0) {
                av = *(const bf8_t*)((const bf16*)As
                    + (long)(m0 + row) * lda + kk + sc8);
            } else if (a_type == 1) {
                const float4* src = (const float4*)((const float*)As
                    + (long)(m0 + row) * lda + kk + sc8);
                float4 u0 = src[0], u1 = src[1];
                av[0] = (short)f2bf(u0.x); av[1] = (short)f2bf(u0.y);
                av[2] = (short)f2bf(u0.z); av[3] = (short)f2bf(u0.w);
                av[4] = (short)f2bf(u1.x); av[5] = (short)f2bf(u1.y);
                av[6] = (short)f2bf(u1.z); av[7] = (short)f2bf(u1.w);
            } else {
                const ushort2* src = (const ushort2*)As
                    + (long)(m0 + row) * lda + kk + sc8;
#pragma unroll
                for (int j = 0; j < 8; j++) av[j] = (short)src[j].x;
            }
            *(bf8_t*)&Asub[row * 40 + sc8] = av;

            bf8_t bv = *(const bf8_t*)(Bt + (long)(n0 + row) * ldb + k0 + sc8);
            *(bf8_t*)&Bsub[row * 40 + sc8] = bv;
        }
        __syncthreads();

        bf8_t a_frag[4], b_frag[4];
        const int ko = (l >> 4) * 8;
        const int lr = l & 15;
#pragma unroll
        for (int fm = 0; fm < 4; fm++)
            a_frag[fm] = *(bf8_t*)&Asub[(wm * 64 + fm * 16 + lr) * 40 + ko];
#pragma unroll
        for (int fn = 0; fn < 4; fn++)
            b_frag[fn] = *(bf8_t*)&Bsub[(wn * 64 + fn * 16 + lr) * 40 + ko];
#pragma unroll
        for (int fm = 0; fm < 4; fm++)
#pragma unroll
            for (int fn = 0; fn < 4; fn++)
                acc[fm][fn] = __builtin_amdgcn_mfma_f32_16x16x32_bf16(
                    b_frag[fn], a_frag[fm], acc[fm][fn], 0, 0, 0);
        __syncthreads();
    }

    const int sel = n0 / nper;
    const int nb  = sel * nper;
    const float* biasl = (sel == 0) ? bias0 : ((sel == 1) ? bias1 : bias2);
    void* Cl = (sel == 0) ? C0 : ((sel == 1) ? C1 : C2);

    const int em = m0 + wm * 64 + (l & 15);
    const int en = n0 + wn * 64 + ((l >> 4) << 2);
#pragma unroll
    for (int fm = 0; fm < 4; fm++) {
        const long m = em + fm * 16;
        float bnm = 0.f, bnr = 1.f, bng = 1.f, bnb = 0.f;
        if (out_type == 3) {
            const int c = (int)(m & 511);
            bnm = e0[c];
            bnr = 1.0f / sqrtf(e1[c] + 1e-5f);
            bng = e2[c];
            bnb = e3[c];
        }
#pragma unroll
        for (int fn = 0; fn < 4; fn++) {
            const int n = en + fn * 16;
            const int nl = n - nb;
            f4_t v = acc[fm][fn];
            if (biasl) {
#pragma unroll
                for (int r = 0; r < 4; r++) v[r] += biasl[nl + r];
            }
            if (out_type == 0) {
                float4 o; o.x = v[0]; o.y = v[1]; o.z = v[2]; o.w = v[3];
                *(float4*)((float*)Cl + m * ldc + nl) = o;
            } else if (out_type == 1) {
                union { unsigned short u[4]; ushort4 q; } o;
#pragma unroll
                for (int r = 0; r < 4; r++) o.u[r] = f2bf(v[r]);
                *(ushort4*)((bf16*)Cl + m * ldc + nl) = o.q;
            } else if (out_type == 2) {
                union { ushort2 u2[4]; uint4 q; } o;
#pragma unroll
                for (int r = 0; r < 4; r++) { o.u2[r].x = f2bf(v[r]); o.u2[r].y = 0; }
                *(uint4*)((ushort2*)Cl + m * ldc + nl) = o.q;
            } else if (out_type == 3) {
                union { unsigned short u[4]; ushort4 q; } o;
#pragma unroll
                for (int r = 0; r < 4; r++)
                    o.u[r] = f2bf(fmaxf((v[r] - bnm) * bnr * bng + bnb, 0.f));
                *(ushort4*)((bf16*)Cl + m * ldc + nl) = o.q;
            } else {
                union { unsigned short u[4]; ushort4 q; } rsd;
                rsd.q = *(const ushort4*)((const unsigned short*)e0 + m * ldc + nl);
                float4 o;
                o.x = v[0] + bf2f(rsd.u[0]);
                o.y = v[1] + bf2f(rsd.u[1]);
                o.z = v[2] + bf2f(rsd.u[2]);
                o.w = v[3] + bf2f(rsd.u[3]);
                *(float4*)((float*)Cl + m * ldc + nl) = o;
            }
        }
    }
}

// ---------------------------------------------------------------------------
// Radix-8 512-point Stockham FFT. 64 lanes per transform, 3 stages.
// Stockham step (radix R, len n, m=n/R, stride s):
//   out[q + s*(R*p + k)] = DFT8(x[q + s*(p + r*m)])_k * W_n^{p*k}
// (reduces to the HW-verified radix-2 recurrence at R=2).
// Buffers are padded: element i at offset FOFF(i)=i+(i>>3), size 576.
// Result always ends in `by0` (B1).
// ---------------------------------------------------------------------------
__device__ inline void dft8(float2* x, float sgn)
{
    const float c45 = 0.70710678118654752f;
    float2 e0, e1, e2, e3, o0, o1, o2, o3;
    {
        float2 u0 = cadd(x[0], x[4]), u1 = csub(x[0], x[4]);
        float2 u2 = cadd(x[2], x[6]), u3 = cmuli(csub(x[2], x[6]), sgn);
        e0 = cadd(u0, u2); e1 = cadd(u1, u3); e2 = csub(u0, u2); e3 = csub(u1, u3);
    }
    {
        float2 u0 = cadd(x[1], x[5]), u1 = csub(x[1], x[5]);
        float2 u2 = cadd(x[3], x[7]), u3 = cmuli(csub(x[3], x[7]), sgn);
        o0 = cadd(u0, u2); o1 = cadd(u1, u3); o2 = csub(u0, u2); o3 = csub(u1, u3);
    }
    const float2 w1 = make_float2(c45, sgn * c45);
    const float2 w3 = make_float2(-c45, sgn * c45);
    o1 = cmul(o1, w1);
    o2 = cmuli(o2, sgn);
    o3 = cmul(o3, w3);
    x[0] = cadd(e0, o0); x[4] = csub(e0, o0);
    x[1] = cadd(e1, o1); x[5] = csub(e1, o1);
    x[2] = cadd(e2, o2); x[6] = csub(e2, o2);
    x[3] = cadd(e3, o3); x[7] = csub(e3, o3);
}

__device__ inline void fft512_r8(float2* bx0, float2* by0, int lane, float sign)
{
    float2* bx = bx0;
    float2* by = by0;
#pragma unroll
    for (int st = 0; st < 3; st++) {
        int n, m, sstr, p, q;
        if (st == 0)      { n = 512; m = 64; sstr = 1;  p = lane;      q = 0; }
        else if (st == 1) { n = 64;  m = 8;  sstr = 8;  p = lane >> 3; q = lane & 7; }
        else              { n = 8;   m = 1;  sstr = 64; p = 0;         q = lane; }
        float2 x[8];
#pragma unroll
        for (int r = 0; r < 8; r++) x[r] = bx[FOFF(q + sstr * (p + r * m))];
        dft8(x, sign);
        if (p) {
            float ang = sign * (2.0f * FFT_PI) * (float)p / (float)n;
            float sw, cw;
            __sincosf(ang, &sw, &cw);
            float2 w = make_float2(cw, sw), wk = w;
#pragma unroll
            for (int k = 1; k < 8; k++) { x[k] = cmul(x[k], wk); wk = cmul(wk, w); }
        }
#pragma unroll
        for (int k = 0; k < 8; k++) by[FOFF(q + sstr * (8 * p + k))] = x[k];
        __syncthreads();
        float2* t = bx; bx = by; by = t;
    }
}

// in-place row FFT on cplx-bf16, 4 lines/block (grid = lines/4)
__global__ __launch_bounds__(256) void fft8_rows_c2c(
    ushort2* __restrict__ data, float sign)
{
    __shared__ float2 B0[4][576], B1[4][576];
    const int li = threadIdx.x >> 6, lane = threadIdx.x & 63;
    ushort2* s = data + ((long)blockIdx.x * 4 + li) * 512;
    {
        uint4 r0 = *(const uint4*)(s + lane * 8);
        uint4 r1 = *(const uint4*)(s + lane * 8 + 4);
        float2* dst = &B0[li][9 * lane];   // FOFF(8*lane+j) = 9*lane+j
        const ushort2* pp = (const ushort2*)&r0;
#pragma unroll
        for (int j = 0; j < 4; j++) dst[j] = c_load(pp + j);
        pp = (const ushort2*)&r1;
#pragma unroll
        for (int j = 0; j < 4; j++) dst[4 + j] = c_load(pp + j);
    }
    __syncthreads();
    fft512_r8(B0[li], B1[li], lane, sign);
    {
        float2* src = &B1[li][9 * lane];
        union { ushort2 u[4]; uint4 q; } o0, o1;
#pragma unroll
        for (int j = 0; j < 4; j++) {
            float2 z = src[j]; o0.u[j].x = f2bf(z.x); o0.u[j].y = f2bf(z.y);
        }
#pragma unroll
        for (int j = 0; j < 4; j++) {
            float2 z = src[4 + j]; o1.u[j].x = f2bf(z.x); o1.u[j].y = f2bf(z.y);
        }
        *(uint4*)(s + lane * 8) = o0.q;
        *(uint4*)(s + lane * 8 + 4) = o1.q;
    }
}

// real-bf16 src -> cplx-bf16 dst, forward row FFT
__global__ __launch_bounds__(256) void fft8_rows_r2c(
    const bf16* __restrict__ srcb, ushort2* __restrict__ dst)
{
    __shared__ float2 B0[4][576], B1[4][576];
    const int li = threadIdx.x >> 6, lane = threadIdx.x & 63;
    const long line = (long)blockIdx.x * 4 + li;
    {
        uint4 raw = *(const uint4*)((const unsigned short*)srcb + line * 512 + lane * 8);
        const unsigned short* pp = (const unsigned short*)&raw;
        float2* d = &B0[li][9 * lane];
#pragma unroll
        for (int j = 0; j < 8; j++) d[j] = make_float2(bf2f(pp[j]), 0.f);
    }
    __syncthreads();
    fft512_r8(B0[li], B1[li], lane, -1.f);
    {
        ushort2* s = dst + line * 512;
        float2* src = &B1[li][9 * lane];
        union { ushort2 u[4]; uint4 q; } o0, o1;
#pragma unroll
        for (int j = 0; j < 4; j++) {
            float2 z = src[j]; o0.u[j].x = f2bf(z.x); o0.u[j].y = f2bf(z.y);
        }
#pragma unroll
        for (int j = 0; j < 4; j++) {
            float2 z = src[4 + j]; o1.u[j].x = f2bf(z.x); o1.u[j].y = f2bf(z.y);
        }
        *(uint4*)(s + lane * 8) = o0.q;
        *(uint4*)(s + lane * 8 + 4) = o1.q;
    }
}

// gated row inverse FFT: sigmoid(g2)*tep, ifft, scale 1/512, in place
__global__ __launch_bounds__(256) void fft8_rows_gated(
    const bf16* __restrict__ g2, ushort2* __restrict__ tep)
{
    __shared__ float2 B0[4][576], B1[4][576];
    const int li = threadIdx.x >> 6, lane = threadIdx.x & 63;
    const long line = (long)blockIdx.x * 4 + li;
    ushort2* s = tep + line * 512;
    {
        uint4 rg = *(const uint4*)((const unsigned short*)g2 + line * 512 + lane * 8);
        uint4 r0 = *(const uint4*)(s + lane * 8);
        uint4 r1 = *(const uint4*)(s + lane * 8 + 4);
        const unsigned short* gp = (const unsigned short*)&rg;
        float2* d = &B0[li][9 * lane];
        const ushort2* pp = (const ushort2*)&r0;
#pragma unroll
        for (int j = 0; j < 4; j++) {
            float sg = 1.0f / (1.0f + __expf(-bf2f(gp[j])));
            float2 z = c_load(pp + j);
            d[j] = make_float2(sg * z.x, sg * z.y);
        }
        pp = (const ushort2*)&r1;
#pragma unroll
        for (int j = 0; j < 4; j++) {
            float sg = 1.0f / (1.0f + __expf(-bf2f(gp[4 + j])));
            float2 z = c_load(pp + j);
            d[4 + j] = make_float2(sg * z.x, sg * z.y);
        }
    }
    __syncthreads();
    fft512_r8(B0[li], B1[li], lane, +1.f);
    {
        const float sc = 1.0f / 512.0f;
        float2* src = &B1[li][9 * lane];
        union { ushort2 u[4]; uint4 q; } o0, o1;
#pragma unroll
        for (int j = 0; j < 4; j++) {
            float2 z = src[j];
            o0.u[j].x = f2bf(z.x * sc); o0.u[j].y = f2bf(z.y * sc);
        }
#pragma unroll
        for (int j = 0; j < 4; j++) {
            float2 z = src[4 + j];
            o1.u[j].x = f2bf(z.x * sc); o1.u[j].y = f2bf(z.y * sc);
        }
        *(uint4*)(s + lane * 8) = o0.q;
        *(uint4*)(s + lane * 8 + 4) = o1.q;
    }
}

// in-place column FFT, 4 columns/block (grid = 32 b * 128 colgroups)
__global__ __launch_bounds__(256) void fft8_cols_c2c(
    ushort2* __restrict__ data, float sign)
{
    __shared__ float2 B0[4][576], B1[4][576];
    const int b  = blockIdx.x >> 7;
    const int c0 = (blockIdx.x & 127) * 4;
    ushort2* base = data + (long)b * 262144 + c0;
    const int t = threadIdx.x;

#pragma unroll
    for (int rr = 0; rr < 2; rr++) {
        const int row = t + rr * 256;
        uint4 raw = *(const uint4*)(base + (long)row * 512);
        const ushort2* pp = (const ushort2*)&raw;
        const int fo = FOFF(row);
#pragma unroll
        for (int j = 0; j < 4; j++) B0[j][fo] = c_load(pp + j);
    }
    __syncthreads();
    fft512_r8(B0[t >> 6], B1[t >> 6], t & 63, sign);
#pragma unroll
    for (int rr = 0; rr < 2; rr++) {
        const int row = t + rr * 256;
        const int fo = FOFF(row);
        union { ushort2 u[4]; uint4 q; } o;
#pragma unroll
        for (int j = 0; j < 4; j++) {
            float2 z = B1[j][fo];
            o.u[j].x = f2bf(z.x); o.u[j].y = f2bf(z.y);
        }
        *(uint4*)(base + (long)row * 512) = o.q;
    }
}

// column inverse FFT + abs -> bf16 real (scale 1/512), 4 columns/block
__global__ __launch_bounds__(256) void fft8_cols_abs(
    const ushort2* __restrict__ src, bf16* __restrict__ dst)
{
    __shared__ float2 B0[4][576], B1[4][576];
    const int b  = blockIdx.x >> 7;
    const int c0 = (blockIdx.x & 127) * 4;
    const ushort2* base = src + (long)b * 262144 + c0;
    const int t = threadIdx.x;

#pragma unroll
    for (int rr = 0; rr < 2; rr++) {
        const int row = t + rr * 256;
        uint4 raw = *(const uint4*)(base + (long)row * 512);
        const ushort2* pp = (const ushort2*)&raw;
        const int fo = FOFF(row);
#pragma unroll
        for (int j = 0; j < 4; j++) B0[j][fo] = c_load(pp + j);
    }
    __syncthreads();
    fft512_r8(B0[t >> 6], B1[t >> 6], t & 63, +1.f);
    const float sc = 1.0f / 512.0f;
#pragma unroll
    for (int rr = 0; rr < 2; rr++) {
        const int row = t + rr * 256;
        const int fo = FOFF(row);
        union { unsigned short u[4]; ushort4 q; } o;
#pragma unroll
        for (int j = 0; j < 4; j++) {
            float2 z = B1[j][fo];
            o.u[j] = f2bf(sqrtf(z.x * z.x + z.y * z.y) * sc);
        }
        *(ushort4*)(dst + (long)b * 262144 + (long)row * 512 + c0) = o.q;
    }
}

// ---------------------------------------------------------------------------
// attn v3: 4 (b,c) per 256-thread block (1 wave each). Output staged through
// LDS for coalesced 16B stores.
// ---------------------------------------------------------------------------
__global__ __launch_bounds__(256) void attn_kernel(
    const ushort2* __restrict__ qf, const ushort2* __restrict__ kf,
    const ushort2* __restrict__ vf, const float* __restrict__ temp,
    bf16* __restrict__ out_f)
{
    __shared__ float2 QS[4][8][66];
    __shared__ float2 KS[4][8][66];
    __shared__ float2 ATT[4][8][9];

    const int li = threadIdx.x >> 6, lane = threadIdx.x & 63;
    const int bc = blockIdx.x * 4 + li;
    const long base = (long)bc * 512;

    float2 q[8], k[8], v[8];
#pragma unroll
    for (int h = 0; h < 8; h++) {
        q[h] = c_load(qf + base + h * 64 + lane);
        k[h] = c_load(kf + base + h * 64 + lane);
        v[h] = c_load(vf + base + h * 64 + lane);
    }

#pragma unroll
    for (int h = 0; h < 8; h++) {
        float pq = q[h].x * q[h].x + q[h].y * q[h].y;
        float pk = k[h].x * k[h].x + k[h].y * k[h].y;
#pragma unroll
        for (int o = 32; o > 0; o >>= 1) {
            pq += __shfl_xor(pq, o, 64);
            pk += __shfl_xor(pk, o, 64);
        }
        float iq = 1.0f / fmaxf(sqrtf(pq), 1e-12f);
        float ik = 1.0f / fmaxf(sqrtf(pk), 1e-12f);
        q[h].x *= iq; q[h].y *= iq;
        k[h].x *= ik; k[h].y *= ik;
        QS[li][h][lane] = q[h];
        KS[li][h][lane] = k[h];
    }
    __syncthreads();

    {
        const int h = lane >> 3, g = lane & 7;
        float ar = 0.f, ai = 0.f;
        for (int w = 0; w < 64; w++) {
            float2 a = QS[li][h][w], b = KS[li][g][w];
            ar += a.x * b.x - a.y * b.y;
            ai += a.x * b.y + a.y * b.x;
        }
        float tm = temp[h];
        ATT[li][h][g] = make_float2(ar * tm, ai * tm);
    }
    __syncthreads();

    if (lane < 8) {
        const int h = lane;
        float mr = -1e30f, mi = -1e30f;
        for (int g = 0; g < 8; g++) {
            mr = fmaxf(mr, ATT[li][h][g].x);
            mi = fmaxf(mi, ATT[li][h][g].y);
        }
        float er[8], ei[8];
        float sr = 0.f, si = 0.f;
        for (int g = 0; g < 8; g++) {
            er[g] = __expf(ATT[li][h][g].x - mr); sr += er[g];
            ei[g] = __expf(ATT[li][h][g].y - mi); si += ei[g];
        }
        float isr = 1.f / sr, isi = 1.f / si;
        for (int g = 0; g < 8; g++)
            ATT[li][h][g] = make_float2(er[g] * isr, ei[g] * isi);
    }
    __syncthreads();

    float2 o[8];
#pragma unroll
    for (int h = 0; h < 8; h++) {
        float orr = 0.f, oi = 0.f;
#pragma unroll
        for (int g = 0; g < 8; g++) {
            float2 a = ATT[li][h][g], b = v[g];
            orr += a.x * b.x - a.y * b.y;
            oi  += a.x * b.y + a.y * b.x;
        }
        o[h] = make_float2(orr, oi);
    }

    // cross-lane radix-2 DIF inverse FFT along w (bit-reversed output)
#pragma unroll
    for (int m = 32; m >= 1; m >>= 1) {
        float ang = (FFT_PI / (float)m) * (float)(lane & (m - 1));
        float sw, cw;
        __sincosf(ang, &sw, &cw);
        const bool low = (lane & m) == 0;
#pragma unroll
        for (int h = 0; h < 8; h++) {
            float px = __shfl_xor(o[h].x, m, 64);
            float py = __shfl_xor(o[h].y, m, 64);
            float nx, ny;
            if (low) {
                nx = o[h].x + px;
                ny = o[h].y + py;
            } else {
                float dx = px - o[h].x;
                float dy = py - o[h].y;
                nx = dx * cw - dy * sw;
                ny = dx * sw + dy * cw;
            }
            o[h].x = nx; o[h].y = ny;
        }
    }
    const int wr = brev6(lane);

    // inverse 8-pt DFT along h + abs -> staging LDS (reuse QS[li])
    const float r2 = 0.70710678118654752f;
    const float W8x[8] = {1.f,  r2, 0.f, -r2, -1.f, -r2,  0.f,  r2};
    const float W8y[8] = {0.f,  r2, 1.f,  r2,  0.f, -r2, -1.f, -r2};
    unsigned short* stg = (unsigned short*)&QS[li][0][0];
#pragma unroll
    for (int kh = 0; kh < 8; kh++) {
        float sr = 0.f, si = 0.f;
#pragma unroll
        for (int n = 0; n < 8; n++) {
            const int idx = (n * kh) & 7;
            float wx = W8x[idx], wy = W8y[idx];
            sr += o[n].x * wx - o[n].y * wy;
            si += o[n].x * wy + o[n].y * wx;
        }
        stg[kh * 64 + wr] = f2bf(sqrtf(sr * sr + si * si) * (1.0f / 512.0f));
    }
    __syncthreads();
    uint4 ov = *(uint4*)(stg + lane * 8);
    *(uint4*)((unsigned short*)out_f + base + lane * 8) = ov;
}

// ---------------------------------------------------------------------------
extern "C" void kernel_launch(void* const* d_in, const int* in_sizes, int n_in,
                              void* d_out, int out_size, void* d_ws, size_t ws_size,
                              hipStream_t stream)
{
    const float* x     = (const float*)d_in[0];
    const float* W_in  = (const float*)d_in[1];
    const float* b_in  = (const float*)d_in[2];
    const float* W_q   = (const float*)d_in[3];
    const float* b_q   = (const float*)d_in[4];
    const float* W_k   = (const float*)d_in[5];
    const float* b_k   = (const float*)d_in[6];
    const float* W_v   = (const float*)d_in[7];
    const float* b_v   = (const float*)d_in[8];
    const float* temp  = (const float*)d_in[9];
    const float* W1a   = (const float*)d_in[10];
    const float* b1a   = (const float*)d_in[11];
    const float* gam   = (const float*)d_in[12];
    const float* bet   = (const float*)d_in[13];
    const float* mea   = (const float*)d_in[14];
    const float* var   = (const float*)d_in[15];
    const float* W1b   = (const float*)d_in[16];
    const float* b1b   = (const float*)d_in[17];
    const float* W_out = (const float*)d_in[18];
    const float* b_out = (const float*)d_in[19];

    char* wsb = (char*)d_ws;
    const long MB = 1024 * 1024;
    bf16*    conv2b = (bf16*)wsb;
    ushort2* Qb    = (ushort2*)(wsb + 32 * MB);
    ushort2* Kb    = (ushort2*)(wsb + 64 * MB);
    ushort2* Vb    = (ushort2*)(wsb + 96 * MB);
    ushort2* Tb    = (ushort2*)(wsb + 128 * MB);
    bf16*    Wt    = (bf16*)(wsb + 160 * MB);
    bf16* WT_in  = Wt;
    bf16* WT_q   = Wt + 262144;
    bf16* WT_k   = Wt + 2 * 262144;
    bf16* WT_v   = Wt + 3 * 262144;
    bf16* WT_1a  = Wt + 4 * 262144;
    bf16* WT_1b  = Wt + 5 * 262144;
    bf16* WT_out = Wt + 6 * 262144;
    bf16* outF = (bf16*)Qb;
    bf16* g1b  = (bf16*)Kb;
    bf16* outL = (bf16*)Kb;
    bf16* g2b  = (bf16*)Vb;

    const dim3 tgrid(16, 16), tblk(32, 8);
    const dim3 ggrid(4, 128), gblk(256);
    const int BIG = 1 << 30;
    const int RB = 4096;   // 16384 lines / 4 per block
    const int CB = 4096;   // 32 b * 128 colgroups

    transpose_cvt<<<tgrid, tblk, 0, stream>>>(W_in, WT_in, 512, 512);
    transpose_cvt<<<tgrid, tblk, 0, stream>>>(W_q,  WT_q,  512, 512);
    transpose_cvt<<<tgrid, tblk, 0, stream>>>(W_k,  WT_k,  512, 512);
    transpose_cvt<<<tgrid, tblk, 0, stream>>>(W_v,  WT_v,  512, 512);
    transpose_cvt<<<tgrid, tblk, 0, stream>>>(W1a,  WT_1a, 512, 512);
    transpose_cvt<<<tgrid, tblk, 0, stream>>>(W1b,  WT_1b, 512, 512);
    transpose_cvt<<<dim3(16, 32), tblk, 0, stream>>>(W_out, WT_out, 1024, 512);

    // 1. conv2 = x @ W_in + b_in -> bf16
    mfma_gemm<<<ggrid, gblk, 0, stream>>>(
        x, x, 1, 512, BIG, WT_in, 512, b_in, nullptr, nullptr,
        conv2b, nullptr, nullptr, BIG, 1, 512, 512,
        nullptr, nullptr, nullptr, nullptr);

    // 2. fused q/k/v projections, then fft2 each
    mfma_gemm<<<dim3(12, 128), gblk, 0, stream>>>(
        conv2b, conv2b, 0, 512, BIG, WT_q, 512, b_q, b_k, b_v,
        Qb, Kb, Vb, 512, 2, 512, 512,
        nullptr, nullptr, nullptr, nullptr);
    fft8_rows_c2c<<<RB, 256, 0, stream>>>(Qb, -1.f);
    fft8_cols_c2c<<<CB, 256, 0, stream>>>(Qb, -1.f);
    fft8_rows_c2c<<<RB, 256, 0, stream>>>(Kb, -1.f);
    fft8_cols_c2c<<<CB, 256, 0, stream>>>(Kb, -1.f);
    fft8_rows_c2c<<<RB, 256, 0, stream>>>(Vb, -1.f);
    fft8_cols_c2c<<<CB, 256, 0, stream>>>(Vb, -1.f);

    // 3. attention -> out_f bf16 over Qb
    attn_kernel<<<RB, 256, 0, stream>>>(Qb, Kb, Vb, temp, outF);

    // 4. tep = fft2(conv2) -> Tb
    fft8_rows_r2c<<<RB, 256, 0, stream>>>(conv2b, Tb);
    fft8_cols_c2c<<<CB, 256, 0, stream>>>(Tb, -1.f);

    // 5. g1 = BN_ReLU(tep.real @ W1a + b1a) -> bf16
    mfma_gemm<<<ggrid, gblk, 0, stream>>>(
        Tb, Tb, 2, 512, BIG, WT_1a, 512, b1a, nullptr, nullptr,
        g1b, nullptr, nullptr, BIG, 3, 512, 512,
        mea, var, gam, bet);

    // 6. g2 = g1 @ W1b + b1b -> bf16
    mfma_gemm<<<ggrid, gblk, 0, stream>>>(
        g1b, g1b, 0, 512, BIG, WT_1b, 512, b1b, nullptr, nullptr,
        g2b, nullptr, nullptr, BIG, 1, 512, 512,
        nullptr, nullptr, nullptr, nullptr);

    // 7. gated ifft2 + abs -> out_l bf16 (over Kb)
    fft8_rows_gated<<<RB, 256, 0, stream>>>(g2b, Tb);
    fft8_cols_abs<<<CB, 256, 0, stream>>>(Tb, outL);

    // 8. d_out = [out_f | out_l] @ W_out + b_out + conv2 (K=1024, fused residual)
    mfma_gemm<<<ggrid, gblk, 0, stream>>>(
        outF, outL, 0, 512, 512, WT_out, 1024, b_out, nullptr, nullptr,
        d_out, nullptr, nullptr, BIG, 4, 512, 1024,
        (const float*)conv2b, nullptr, nullptr, nullptr);
}

// Round 8
// 838.745 us; speedup vs baseline: 3.5259x; 1.1085x over previous
//
#include <hip/hip_runtime.h>
#include <hip/hip_bf16.h>

#define FFT_PI 3.14159265358979323846f
#define FOFF(i) ((i) + ((i) >> 3))   // padded LDS offset (max 574 < 576)

typedef __hip_bfloat16 bf16;
typedef short bf8_t __attribute__((ext_vector_type(8)));
typedef float f4_t __attribute__((ext_vector_type(4)));

__device__ inline float bf2f(unsigned short u) {
    union { unsigned int i; float f; } v; v.i = ((unsigned int)u) << 16; return v.f;
}
__device__ inline unsigned short f2bf(float f) {
    bf16 h = __float2bfloat16(f);
    union { bf16 h; unsigned short u; } v; v.h = h; return v.u;
}
__device__ inline float2 c_load(const ushort2* p) {
    ushort2 u = *p;
    return make_float2(bf2f(u.x), bf2f(u.y));
}
__device__ inline int brev6(int t) {
    return ((t & 1) << 5) | ((t & 2) << 3) | ((t & 4) << 1) |
           ((t & 8) >> 1) | ((t & 16) >> 3) | ((t & 32) >> 5);
}
__device__ inline float2 cadd(float2 a, float2 b){ return make_float2(a.x+b.x, a.y+b.y); }
__device__ inline float2 csub(float2 a, float2 b){ return make_float2(a.x-b.x, a.y-b.y); }
__device__ inline float2 cmul(float2 a, float2 b){
    return make_float2(a.x*b.x - a.y*b.y, a.x*b.y + a.y*b.x);
}
__device__ inline float2 cmuli(float2 a, float s){ return make_float2(-s*a.y, s*a.x); }

// ---------------------------------------------------------------------------
// Merged transpose+convert for all 7 weights. grid (16, 32, 7), block (32,8).
// dst_z = Wt + z*262144 (W_out at z=6 spans 2 slots). z<6: R=512 (guard y<16).
// ---------------------------------------------------------------------------
__global__ __launch_bounds__(256) void transpose_cvt_all(
    const float* __restrict__ s0, const float* __restrict__ s1,
    const float* __restrict__ s2, const float* __restrict__ s3,
    const float* __restrict__ s4, const float* __restrict__ s5,
    const float* __restrict__ s6, bf16* __restrict__ Wt)
{
    const int z = blockIdx.z;
    const int R = (z == 6) ? 1024 : 512;
    if (blockIdx.y * 32 >= R) return;
    const float* src = (z == 0) ? s0 : (z == 1) ? s1 : (z == 2) ? s2 :
                       (z == 3) ? s3 : (z == 4) ? s4 : (z == 5) ? s5 : s6;
    bf16* dst = Wt + (long)z * 262144;
    const int C = 512;

    __shared__ float tile[32][33];
    const int bx = blockIdx.x * 32;
    const int by = blockIdx.y * 32;
    const int tx = threadIdx.x, ty = threadIdx.y;
#pragma unroll
    for (int i = 0; i < 32; i += 8)
        tile[ty + i][tx] = src[(long)(by + ty + i) * C + bx + tx];
    __syncthreads();
#pragma unroll
    for (int i = 0; i < 32; i += 8)
        dst[(long)(bx + ty + i) * R + by + tx] = __float2bfloat16(tile[tx][ty + i]);
}

// ---------------------------------------------------------------------------
// MFMA bf16 GEMM (structure unchanged from R7). Tile 128x128, BK=32, 4 waves.
// ---------------------------------------------------------------------------
__global__ __launch_bounds__(256) void mfma_gemm(
    const void* __restrict__ Av, const void* __restrict__ Av2,
    int a_type, int lda, int ksplit,
    const bf16* __restrict__ Bt, int ldb,
    const float* __restrict__ bias0, const float* __restrict__ bias1,
    const float* __restrict__ bias2,
    void* __restrict__ C0, void* __restrict__ C1, void* __restrict__ C2,
    int nper, int out_type, int ldc, int K,
    const float* __restrict__ e0, const float* __restrict__ e1,
    const float* __restrict__ e2, const float* __restrict__ e3)
{
    __shared__ short Asub[128 * 40];
    __shared__ short Bsub[128 * 40];

    const int tid = threadIdx.x;
    const int n0 = blockIdx.x * 128;
    const int m0 = blockIdx.y * 128;
    const int l  = tid & 63;
    const int wv = tid >> 6;
    const int wm = wv & 1, wn = wv >> 1;

    f4_t acc[4][4];
#pragma unroll
    for (int i = 0; i < 4; i++)
#pragma unroll
        for (int j = 0; j < 4; j++)
            acc[i][j] = (f4_t)0.f;

    const int srow = tid >> 2;
    const int sc8  = (tid & 3) * 8;

    for (int k0 = 0; k0 < K; k0 += 32) {
        const void* As = (k0 < ksplit) ? Av : Av2;
        const int kk = (k0 < ksplit) ? k0 : (k0 - ksplit);
#pragma unroll
        for (int p = 0; p < 2; p++) {
            const int row = srow + p * 64;
            bf8_t av;
            if (a_type == 0) {
                av = *(const bf8_t*)((const bf16*)As
                    + (long)(m0 + row) * lda + kk + sc8);
            } else if (a_type == 1) {
                const float4* src = (const float4*)((const float*)As
                    + (long)(m0 + row) * lda + kk + sc8);
                float4 u0 = src[0], u1 = src[1];
                av[0] = (short)f2bf(u0.x); av[1] = (short)f2bf(u0.y);
                av[2] = (short)f2bf(u0.z); av[3] = (short)f2bf(u0.w);
                av[4] = (short)f2bf(u1.x); av[5] = (short)f2bf(u1.y);
                av[6] = (short)f2bf(u1.z); av[7] = (short)f2bf(u1.w);
            } else {
                const ushort2* src = (const ushort2*)As
                    + (long)(m0 + row) * lda + kk + sc8;
#pragma unroll
                for (int j = 0; j < 8; j++) av[j] = (short)src[j].x;
            }
            *(bf8_t*)&Asub[row * 40 + sc8] = av;

            bf8_t bv = *(const bf8_t*)(Bt + (long)(n0 + row) * ldb + k0 + sc8);
            *(bf8_t*)&Bsub[row * 40 + sc8] = bv;
        }
        __syncthreads();

        bf8_t a_frag[4], b_frag[4];
        const int ko = (l >> 4) * 8;
        const int lr = l & 15;
#pragma unroll
        for (int fm = 0; fm < 4; fm++)
            a_frag[fm] = *(bf8_t*)&Asub[(wm * 64 + fm * 16 + lr) * 40 + ko];
#pragma unroll
        for (int fn = 0; fn < 4; fn++)
            b_frag[fn] = *(bf8_t*)&Bsub[(wn * 64 + fn * 16 + lr) * 40 + ko];
#pragma unroll
        for (int fm = 0; fm < 4; fm++)
#pragma unroll
            for (int fn = 0; fn < 4; fn++)
                acc[fm][fn] = __builtin_amdgcn_mfma_f32_16x16x32_bf16(
                    b_frag[fn], a_frag[fm], acc[fm][fn], 0, 0, 0);
        __syncthreads();
    }

    const int sel = n0 / nper;
    const int nb  = sel * nper;
    const float* biasl = (sel == 0) ? bias0 : ((sel == 1) ? bias1 : bias2);
    void* Cl = (sel == 0) ? C0 : ((sel == 1) ? C1 : C2);

    const int em = m0 + wm * 64 + (l & 15);
    const int en = n0 + wn * 64 + ((l >> 4) << 2);
#pragma unroll
    for (int fm = 0; fm < 4; fm++) {
        const long m = em + fm * 16;
        float bnm = 0.f, bnr = 1.f, bng = 1.f, bnb = 0.f;
        if (out_type == 3) {
            const int c = (int)(m & 511);
            bnm = e0[c];
            bnr = 1.0f / sqrtf(e1[c] + 1e-5f);
            bng = e2[c];
            bnb = e3[c];
        }
#pragma unroll
        for (int fn = 0; fn < 4; fn++) {
            const int n = en + fn * 16;
            const int nl = n - nb;
            f4_t v = acc[fm][fn];
            if (biasl) {
#pragma unroll
                for (int r = 0; r < 4; r++) v[r] += biasl[nl + r];
            }
            if (out_type == 0) {
                float4 o; o.x = v[0]; o.y = v[1]; o.z = v[2]; o.w = v[3];
                *(float4*)((float*)Cl + m * ldc + nl) = o;
            } else if (out_type == 1) {
                union { unsigned short u[4]; ushort4 q; } o;
#pragma unroll
                for (int r = 0; r < 4; r++) o.u[r] = f2bf(v[r]);
                *(ushort4*)((bf16*)Cl + m * ldc + nl) = o.q;
            } else if (out_type == 2) {
                union { ushort2 u2[4]; uint4 q; } o;
#pragma unroll
                for (int r = 0; r < 4; r++) { o.u2[r].x = f2bf(v[r]); o.u2[r].y = 0; }
                *(uint4*)((ushort2*)Cl + m * ldc + nl) = o.q;
            } else if (out_type == 3) {
                union { unsigned short u[4]; ushort4 q; } o;
#pragma unroll
                for (int r = 0; r < 4; r++)
                    o.u[r] = f2bf(fmaxf((v[r] - bnm) * bnr * bng + bnb, 0.f));
                *(ushort4*)((bf16*)Cl + m * ldc + nl) = o.q;
            } else {
                union { unsigned short u[4]; ushort4 q; } rsd;
                rsd.q = *(const ushort4*)((const unsigned short*)e0 + m * ldc + nl);
                float4 o;
                o.x = v[0] + bf2f(rsd.u[0]);
                o.y = v[1] + bf2f(rsd.u[1]);
                o.z = v[2] + bf2f(rsd.u[2]);
                o.w = v[3] + bf2f(rsd.u[3]);
                *(float4*)((float*)Cl + m * ldc + nl) = o;
            }
        }
    }
}

// ---------------------------------------------------------------------------
// Radix-8 512-point Stockham FFT (verified R7). Result ends in by0.
// ---------------------------------------------------------------------------
__device__ inline void dft8(float2* x, float sgn)
{
    const float c45 = 0.70710678118654752f;
    float2 e0, e1, e2, e3, o0, o1, o2, o3;
    {
        float2 u0 = cadd(x[0], x[4]), u1 = csub(x[0], x[4]);
        float2 u2 = cadd(x[2], x[6]), u3 = cmuli(csub(x[2], x[6]), sgn);
        e0 = cadd(u0, u2); e1 = cadd(u1, u3); e2 = csub(u0, u2); e3 = csub(u1, u3);
    }
    {
        float2 u0 = cadd(x[1], x[5]), u1 = csub(x[1], x[5]);
        float2 u2 = cadd(x[3], x[7]), u3 = cmuli(csub(x[3], x[7]), sgn);
        o0 = cadd(u0, u2); o1 = cadd(u1, u3); o2 = csub(u0, u2); o3 = csub(u1, u3);
    }
    const float2 w1 = make_float2(c45, sgn * c45);
    const float2 w3 = make_float2(-c45, sgn * c45);
    o1 = cmul(o1, w1);
    o2 = cmuli(o2, sgn);
    o3 = cmul(o3, w3);
    x[0] = cadd(e0, o0); x[4] = csub(e0, o0);
    x[1] = cadd(e1, o1); x[5] = csub(e1, o1);
    x[2] = cadd(e2, o2); x[6] = csub(e2, o2);
    x[3] = cadd(e3, o3); x[7] = csub(e3, o3);
}

__device__ inline void fft512_r8(float2* bx0, float2* by0, int lane, float sign)
{
    float2* bx = bx0;
    float2* by = by0;
#pragma unroll
    for (int st = 0; st < 3; st++) {
        int n, m, sstr, p, q;
        if (st == 0)      { n = 512; m = 64; sstr = 1;  p = lane;      q = 0; }
        else if (st == 1) { n = 64;  m = 8;  sstr = 8;  p = lane >> 3; q = lane & 7; }
        else              { n = 8;   m = 1;  sstr = 64; p = 0;         q = lane; }
        float2 x[8];
#pragma unroll
        for (int r = 0; r < 8; r++) x[r] = bx[FOFF(q + sstr * (p + r * m))];
        dft8(x, sign);
        if (p) {
            float ang = sign * (2.0f * FFT_PI) * (float)p / (float)n;
            float sw, cw;
            __sincosf(ang, &sw, &cw);
            float2 w = make_float2(cw, sw), wk = w;
#pragma unroll
            for (int k = 1; k < 8; k++) { x[k] = cmul(x[k], wk); wk = cmul(wk, w); }
        }
#pragma unroll
        for (int k = 0; k < 8; k++) by[FOFF(q + sstr * (8 * p + k))] = x[k];
        __syncthreads();
        float2* t = bx; bx = by; by = t;
    }
}

// in-place row FFT on cplx-bf16, 4 lines/block. Fused over 3 buffers
// (Q/K/V contiguous, 8388608 ushort2 apart): buf = blockIdx.x >> 12.
__global__ __launch_bounds__(256) void fft8_rows_c2c3(
    ushort2* __restrict__ data, float sign)
{
    __shared__ float2 B0[4][576], B1[4][576];
    const int buf = blockIdx.x >> 12;
    const int lb  = blockIdx.x & 4095;
    const int li = threadIdx.x >> 6, lane = threadIdx.x & 63;
    ushort2* s = data + (long)buf * 8388608 + ((long)lb * 4 + li) * 512;
    {
        uint4 r0 = *(const uint4*)(s + lane * 8);
        uint4 r1 = *(const uint4*)(s + lane * 8 + 4);
        float2* dst = &B0[li][9 * lane];
        const ushort2* pp = (const ushort2*)&r0;
#pragma unroll
        for (int j = 0; j < 4; j++) dst[j] = c_load(pp + j);
        pp = (const ushort2*)&r1;
#pragma unroll
        for (int j = 0; j < 4; j++) dst[4 + j] = c_load(pp + j);
    }
    __syncthreads();
    fft512_r8(B0[li], B1[li], lane, sign);
    {
        float2* src = &B1[li][9 * lane];
        union { ushort2 u[4]; uint4 q; } o0, o1;
#pragma unroll
        for (int j = 0; j < 4; j++) {
            float2 z = src[j]; o0.u[j].x = f2bf(z.x); o0.u[j].y = f2bf(z.y);
        }
#pragma unroll
        for (int j = 0; j < 4; j++) {
            float2 z = src[4 + j]; o1.u[j].x = f2bf(z.x); o1.u[j].y = f2bf(z.y);
        }
        *(uint4*)(s + lane * 8) = o0.q;
        *(uint4*)(s + lane * 8 + 4) = o1.q;
    }
}

// real-bf16 src -> cplx-bf16 dst, forward row FFT (tep)
__global__ __launch_bounds__(256) void fft8_rows_r2c(
    const bf16* __restrict__ srcb, ushort2* __restrict__ dst)
{
    __shared__ float2 B0[4][576], B1[4][576];
    const int li = threadIdx.x >> 6, lane = threadIdx.x & 63;
    const long line = (long)blockIdx.x * 4 + li;
    {
        uint4 raw = *(const uint4*)((const unsigned short*)srcb + line * 512 + lane * 8);
        const unsigned short* pp = (const unsigned short*)&raw;
        float2* d = &B0[li][9 * lane];
#pragma unroll
        for (int j = 0; j < 8; j++) d[j] = make_float2(bf2f(pp[j]), 0.f);
    }
    __syncthreads();
    fft512_r8(B0[li], B1[li], lane, -1.f);
    {
        ushort2* s = dst + line * 512;
        float2* src = &B1[li][9 * lane];
        union { ushort2 u[4]; uint4 q; } o0, o1;
#pragma unroll
        for (int j = 0; j < 4; j++) {
            float2 z = src[j]; o0.u[j].x = f2bf(z.x); o0.u[j].y = f2bf(z.y);
        }
#pragma unroll
        for (int j = 0; j < 4; j++) {
            float2 z = src[4 + j]; o1.u[j].x = f2bf(z.x); o1.u[j].y = f2bf(z.y);
        }
        *(uint4*)(s + lane * 8) = o0.q;
        *(uint4*)(s + lane * 8 + 4) = o1.q;
    }
}

// gated row inverse FFT: sigmoid(g2)*tep, ifft, scale 1/512, in place
__global__ __launch_bounds__(256) void fft8_rows_gated(
    const bf16* __restrict__ g2, ushort2* __restrict__ tep)
{
    __shared__ float2 B0[4][576], B1[4][576];
    const int li = threadIdx.x >> 6, lane = threadIdx.x & 63;
    const long line = (long)blockIdx.x * 4 + li;
    ushort2* s = tep + line * 512;
    {
        uint4 rg = *(const uint4*)((const unsigned short*)g2 + line * 512 + lane * 8);
        uint4 r0 = *(const uint4*)(s + lane * 8);
        uint4 r1 = *(const uint4*)(s + lane * 8 + 4);
        const unsigned short* gp = (const unsigned short*)&rg;
        float2* d = &B0[li][9 * lane];
        const ushort2* pp = (const ushort2*)&r0;
#pragma unroll
        for (int j = 0; j < 4; j++) {
            float sg = 1.0f / (1.0f + __expf(-bf2f(gp[j])));
            float2 z = c_load(pp + j);
            d[j] = make_float2(sg * z.x, sg * z.y);
        }
        pp = (const ushort2*)&r1;
#pragma unroll
        for (int j = 0; j < 4; j++) {
            float sg = 1.0f / (1.0f + __expf(-bf2f(gp[4 + j])));
            float2 z = c_load(pp + j);
            d[4 + j] = make_float2(sg * z.x, sg * z.y);
        }
    }
    __syncthreads();
    fft512_r8(B0[li], B1[li], lane, +1.f);
    {
        const float sc = 1.0f / 512.0f;
        float2* src = &B1[li][9 * lane];
        union { ushort2 u[4]; uint4 q; } o0, o1;
#pragma unroll
        for (int j = 0; j < 4; j++) {
            float2 z = src[j];
            o0.u[j].x = f2bf(z.x * sc); o0.u[j].y = f2bf(z.y * sc);
        }
#pragma unroll
        for (int j = 0; j < 4; j++) {
            float2 z = src[4 + j];
            o1.u[j].x = f2bf(z.x * sc); o1.u[j].y = f2bf(z.y * sc);
        }
        *(uint4*)(s + lane * 8) = o0.q;
        *(uint4*)(s + lane * 8 + 4) = o1.q;
    }
}

// in-place column FFT, 4 columns/block, fused over 4 buffers (Q/K/V/T).
// buf==3 (tep) additionally writes real parts to tepReal (bf16).
__global__ __launch_bounds__(256) void fft8_cols_c2c4(
    ushort2* __restrict__ data, bf16* __restrict__ tepReal, float sign)
{
    __shared__ float2 B0[4][576], B1[4][576];
    const int buf = blockIdx.x >> 12;
    const int rem = blockIdx.x & 4095;
    const int b  = rem >> 7;
    const int c0 = (rem & 127) * 4;
    ushort2* base = data + (long)buf * 8388608 + (long)b * 262144 + c0;
    const int t = threadIdx.x;

#pragma unroll
    for (int rr = 0; rr < 2; rr++) {
        const int row = t + rr * 256;
        uint4 raw = *(const uint4*)(base + (long)row * 512);
        const ushort2* pp = (const ushort2*)&raw;
        const int fo = FOFF(row);
#pragma unroll
        for (int j = 0; j < 4; j++) B0[j][fo] = c_load(pp + j);
    }
    __syncthreads();
    fft512_r8(B0[t >> 6], B1[t >> 6], t & 63, sign);
#pragma unroll
    for (int rr = 0; rr < 2; rr++) {
        const int row = t + rr * 256;
        const int fo = FOFF(row);
        union { ushort2 u[4]; uint4 q; } o;
        union { unsigned short u[4]; ushort4 q; } orl;
#pragma unroll
        for (int j = 0; j < 4; j++) {
            float2 z = B1[j][fo];
            o.u[j].x = f2bf(z.x); o.u[j].y = f2bf(z.y);
            orl.u[j] = o.u[j].x;
        }
        *(uint4*)(base + (long)row * 512) = o.q;
        if (buf == 3)
            *(ushort4*)(tepReal + (long)b * 262144 + (long)row * 512 + c0) = orl.q;
    }
}

// column inverse FFT + abs -> bf16 real (scale 1/512), 4 columns/block
__global__ __launch_bounds__(256) void fft8_cols_abs(
    const ushort2* __restrict__ src, bf16* __restrict__ dst)
{
    __shared__ float2 B0[4][576], B1[4][576];
    const int b  = blockIdx.x >> 7;
    const int c0 = (blockIdx.x & 127) * 4;
    const ushort2* base = src + (long)b * 262144 + c0;
    const int t = threadIdx.x;

#pragma unroll
    for (int rr = 0; rr < 2; rr++) {
        const int row = t + rr * 256;
        uint4 raw = *(const uint4*)(base + (long)row * 512);
        const ushort2* pp = (const ushort2*)&raw;
        const int fo = FOFF(row);
#pragma unroll
        for (int j = 0; j < 4; j++) B0[j][fo] = c_load(pp + j);
    }
    __syncthreads();
    fft512_r8(B0[t >> 6], B1[t >> 6], t & 63, +1.f);
    const float sc = 1.0f / 512.0f;
#pragma unroll
    for (int rr = 0; rr < 2; rr++) {
        const int row = t + rr * 256;
        const int fo = FOFF(row);
        union { unsigned short u[4]; ushort4 q; } o;
#pragma unroll
        for (int j = 0; j < 4; j++) {
            float2 z = B1[j][fo];
            o.u[j] = f2bf(sqrtf(z.x * z.x + z.y * z.y) * sc);
        }
        *(ushort4*)(dst + (long)b * 262144 + (long)row * 512 + c0) = o.q;
    }
}

// ---------------------------------------------------------------------------
// attn v3.1: 4 (b,c) per block; float4 LDS reads in the scores loop.
// ---------------------------------------------------------------------------
__global__ __launch_bounds__(256) void attn_kernel(
    const ushort2* __restrict__ qf, const ushort2* __restrict__ kf,
    const ushort2* __restrict__ vf, const float* __restrict__ temp,
    bf16* __restrict__ out_f)
{
    __shared__ float2 QS[4][8][66];
    __shared__ float2 KS[4][8][66];
    __shared__ float2 ATT[4][8][9];

    const int li = threadIdx.x >> 6, lane = threadIdx.x & 63;
    const int bc = blockIdx.x * 4 + li;
    const long base = (long)bc * 512;

    float2 q[8], k[8], v[8];
#pragma unroll
    for (int h = 0; h < 8; h++) {
        q[h] = c_load(qf + base + h * 64 + lane);
        k[h] = c_load(kf + base + h * 64 + lane);
        v[h] = c_load(vf + base + h * 64 + lane);
    }

#pragma unroll
    for (int h = 0; h < 8; h++) {
        float pq = q[h].x * q[h].x + q[h].y * q[h].y;
        float pk = k[h].x * k[h].x + k[h].y * k[h].y;
#pragma unroll
        for (int o = 32; o > 0; o >>= 1) {
            pq += __shfl_xor(pq, o, 64);
            pk += __shfl_xor(pk, o, 64);
        }
        float iq = 1.0f / fmaxf(sqrtf(pq), 1e-12f);
        float ik = 1.0f / fmaxf(sqrtf(pk), 1e-12f);
        q[h].x *= iq; q[h].y *= iq;
        k[h].x *= ik; k[h].y *= ik;
        QS[li][h][lane] = q[h];
        KS[li][h][lane] = k[h];
    }
    __syncthreads();

    {
        const int h = lane >> 3, g = lane & 7;
        float ar = 0.f, ai = 0.f;
#pragma unroll 8
        for (int w = 0; w < 64; w += 2) {
            float4 aa = *(const float4*)&QS[li][h][w];
            float4 bb = *(const float4*)&KS[li][g][w];
            ar += aa.x * bb.x - aa.y * bb.y + aa.z * bb.z - aa.w * bb.w;
            ai += aa.x * bb.y + aa.y * bb.x + aa.z * bb.w + aa.w * bb.z;
        }
        float tm = temp[h];
        ATT[li][h][g] = make_float2(ar * tm, ai * tm);
    }
    __syncthreads();

    if (lane < 8) {
        const int h = lane;
        float mr = -1e30f, mi = -1e30f;
        for (int g = 0; g < 8; g++) {
            mr = fmaxf(mr, ATT[li][h][g].x);
            mi = fmaxf(mi, ATT[li][h][g].y);
        }
        float er[8], ei[8];
        float sr = 0.f, si = 0.f;
        for (int g = 0; g < 8; g++) {
            er[g] = __expf(ATT[li][h][g].x - mr); sr += er[g];
            ei[g] = __expf(ATT[li][h][g].y - mi); si += ei[g];
        }
        float isr = 1.f / sr, isi = 1.f / si;
        for (int g = 0; g < 8; g++)
            ATT[li][h][g] = make_float2(er[g] * isr, ei[g] * isi);
    }
    __syncthreads();

    float2 o[8];
#pragma unroll
    for (int h = 0; h < 8; h++) {
        float orr = 0.f, oi = 0.f;
#pragma unroll
        for (int g = 0; g < 8; g++) {
            float2 a = ATT[li][h][g], b = v[g];
            orr += a.x * b.x - a.y * b.y;
            oi  += a.x * b.y + a.y * b.x;
        }
        o[h] = make_float2(orr, oi);
    }

#pragma unroll
    for (int m = 32; m >= 1; m >>= 1) {
        float ang = (FFT_PI / (float)m) * (float)(lane & (m - 1));
        float sw, cw;
        __sincosf(ang, &sw, &cw);
        const bool low = (lane & m) == 0;
#pragma unroll
        for (int h = 0; h < 8; h++) {
            float px = __shfl_xor(o[h].x, m, 64);
            float py = __shfl_xor(o[h].y, m, 64);
            float nx, ny;
            if (low) {
                nx = o[h].x + px;
                ny = o[h].y + py;
            } else {
                float dx = px - o[h].x;
                float dy = py - o[h].y;
                nx = dx * cw - dy * sw;
                ny = dx * sw + dy * cw;
            }
            o[h].x = nx; o[h].y = ny;
        }
    }
    const int wr = brev6(lane);

    const float r2 = 0.70710678118654752f;
    const float W8x[8] = {1.f,  r2, 0.f, -r2, -1.f, -r2,  0.f,  r2};
    const float W8y[8] = {0.f,  r2, 1.f,  r2,  0.f, -r2, -1.f, -r2};
    unsigned short* stg = (unsigned short*)&QS[li][0][0];
#pragma unroll
    for (int kh = 0; kh < 8; kh++) {
        float sr = 0.f, si = 0.f;
#pragma unroll
        for (int n = 0; n < 8; n++) {
            const int idx = (n * kh) & 7;
            float wx = W8x[idx], wy = W8y[idx];
            sr += o[n].x * wx - o[n].y * wy;
            si += o[n].x * wy + o[n].y * wx;
        }
        stg[kh * 64 + wr] = f2bf(sqrtf(sr * sr + si * si) * (1.0f / 512.0f));
    }
    __syncthreads();
    uint4 ov = *(uint4*)(stg + lane * 8);
    *(uint4*)((unsigned short*)out_f + base + lane * 8) = ov;
}

// ---------------------------------------------------------------------------
extern "C" void kernel_launch(void* const* d_in, const int* in_sizes, int n_in,
                              void* d_out, int out_size, void* d_ws, size_t ws_size,
                              hipStream_t stream)
{
    const float* x     = (const float*)d_in[0];
    const float* W_in  = (const float*)d_in[1];
    const float* b_in  = (const float*)d_in[2];
    const float* W_q   = (const float*)d_in[3];
    const float* b_q   = (const float*)d_in[4];
    const float* W_k   = (const float*)d_in[5];
    const float* b_k   = (const float*)d_in[6];
    const float* W_v   = (const float*)d_in[7];
    const float* b_v   = (const float*)d_in[8];
    const float* temp  = (const float*)d_in[9];
    const float* W1a   = (const float*)d_in[10];
    const float* b1a   = (const float*)d_in[11];
    const float* gam   = (const float*)d_in[12];
    const float* bet   = (const float*)d_in[13];
    const float* mea   = (const float*)d_in[14];
    const float* var   = (const float*)d_in[15];
    const float* W1b   = (const float*)d_in[16];
    const float* b1b   = (const float*)d_in[17];
    const float* W_out = (const float*)d_in[18];
    const float* b_out = (const float*)d_in[19];

    // Workspace (165 MB):
    //   [  0, 16) conv2 bf16
    //   [ 16, 32) tepReal bf16 (written by col-FFT pass, read by g1 GEMM)
    //   [ 32, 64) q_f cplx-bf16 -> out_f bf16 (attn, in place)
    //   [ 64, 96) k_f -> g1 bf16 -> out_l bf16
    //   [ 96,128) v_f -> g2 bf16
    //   [128,160) tep cplx-bf16 (gated ifft in place)
    //   [160,165) transposed bf16 weights (Wt, 7 slots)
    char* wsb = (char*)d_ws;
    const long MB = 1024 * 1024;
    bf16*    conv2b  = (bf16*)wsb;
    bf16*    tepReal = (bf16*)(wsb + 16 * MB);
    ushort2* Qb    = (ushort2*)(wsb + 32 * MB);
    ushort2* Kb    = (ushort2*)(wsb + 64 * MB);
    ushort2* Vb    = (ushort2*)(wsb + 96 * MB);
    ushort2* Tb    = (ushort2*)(wsb + 128 * MB);
    bf16*    Wt    = (bf16*)(wsb + 160 * MB);
    bf16* WT_in  = Wt;
    bf16* WT_q   = Wt + 262144;
    bf16* WT_k   = Wt + 2 * 262144;
    bf16* WT_v   = Wt + 3 * 262144;
    bf16* WT_1a  = Wt + 4 * 262144;
    bf16* WT_1b  = Wt + 5 * 262144;
    bf16* WT_out = Wt + 6 * 262144;
    bf16* outF = (bf16*)Qb;
    bf16* g1b  = (bf16*)Kb;
    bf16* outL = (bf16*)Kb;
    bf16* g2b  = (bf16*)Vb;

    const dim3 ggrid(4, 128), gblk(256);
    const int BIG = 1 << 30;
    const int RB = 4096;

    // 0. all weight transposes in one dispatch (src order matches Wt slots:
    //    W_in, W_q, W_k, W_v, W1a, W1b, W_out)
    transpose_cvt_all<<<dim3(16, 32, 7), dim3(32, 8), 0, stream>>>(
        W_in, W_q, W_k, W_v, W1a, W1b, W_out, Wt);

    // 1. conv2 = x @ W_in + b_in -> bf16
    mfma_gemm<<<ggrid, gblk, 0, stream>>>(
        x, x, 1, 512, BIG, WT_in, 512, b_in, nullptr, nullptr,
        conv2b, nullptr, nullptr, BIG, 1, 512, 512,
        nullptr, nullptr, nullptr, nullptr);

    // 2. fused q/k/v projections
    mfma_gemm<<<dim3(12, 128), gblk, 0, stream>>>(
        conv2b, conv2b, 0, 512, BIG, WT_q, 512, b_q, b_k, b_v,
        Qb, Kb, Vb, 512, 2, 512, 512,
        nullptr, nullptr, nullptr, nullptr);

    // 3. row FFTs: Q,K,V in one dispatch; tep r2c from conv2
    fft8_rows_c2c3<<<3 * RB, 256, 0, stream>>>(Qb, -1.f);
    fft8_rows_r2c<<<RB, 256, 0, stream>>>(conv2b, Tb);

    // 4. col FFTs: Q,K,V,T in one dispatch (+ tepReal side output)
    fft8_cols_c2c4<<<4 * RB, 256, 0, stream>>>(Qb, tepReal, -1.f);

    // 5. attention -> out_f bf16 over Qb
    attn_kernel<<<RB, 256, 0, stream>>>(Qb, Kb, Vb, temp, outF);

    // 6. g1 = BN_ReLU(tepReal @ W1a + b1a) -> bf16 (fast bf16 A staging)
    mfma_gemm<<<ggrid, gblk, 0, stream>>>(
        tepReal, tepReal, 0, 512, BIG, WT_1a, 512, b1a, nullptr, nullptr,
        g1b, nullptr, nullptr, BIG, 3, 512, 512,
        mea, var, gam, bet);

    // 7. g2 = g1 @ W1b + b1b -> bf16
    mfma_gemm<<<ggrid, gblk, 0, stream>>>(
        g1b, g1b, 0, 512, BIG, WT_1b, 512, b1b, nullptr, nullptr,
        g2b, nullptr, nullptr, BIG, 1, 512, 512,
        nullptr, nullptr, nullptr, nullptr);

    // 8. gated ifft2 + abs -> out_l bf16 (over Kb)
    fft8_rows_gated<<<RB, 256, 0, stream>>>(g2b, Tb);
    fft8_cols_abs<<<4096, 256, 0, stream>>>(Tb, outL);

    // 9. d_out = [out_f | out_l] @ W_out + b_out + conv2 (K=1024, fused residual)
    mfma_gemm<<<ggrid, gblk, 0, stream>>>(
        outF, outL, 0, 512, 512, WT_out, 1024, b_out, nullptr, nullptr,
        d_out, nullptr, nullptr, BIG, 4, 512, 1024,
        (const float*)conv2b, nullptr, nullptr, nullptr);
}

// Round 9
// 569.519 us; speedup vs baseline: 5.1927x; 1.4727x over previous
//
#include <hip/hip_runtime.h>
#include <hip/hip_bf16.h>

#define FFT_PI 3.14159265358979323846f
#define FOFF(i) ((i) + ((i) >> 3))   // padded LDS offset (max 574 < 576)

typedef __hip_bfloat16 bf16;
typedef short bf8_t __attribute__((ext_vector_type(8)));
typedef float f4_t __attribute__((ext_vector_type(4)));

__device__ inline float bf2f(unsigned short u) {
    union { unsigned int i; float f; } v; v.i = ((unsigned int)u) << 16; return v.f;
}
__device__ inline unsigned short f2bf(float f) {
    bf16 h = __float2bfloat16(f);
    union { bf16 h; unsigned short u; } v; v.h = h; return v.u;
}
__device__ inline float2 c_load(const ushort2* p) {
    ushort2 u = *p;
    return make_float2(bf2f(u.x), bf2f(u.y));
}
__device__ inline int brev6(int t) {
    return ((t & 1) << 5) | ((t & 2) << 3) | ((t & 4) << 1) |
           ((t & 8) >> 1) | ((t & 16) >> 3) | ((t & 32) >> 5);
}
__device__ inline float2 cadd(float2 a, float2 b){ return make_float2(a.x+b.x, a.y+b.y); }
__device__ inline float2 csub(float2 a, float2 b){ return make_float2(a.x-b.x, a.y-b.y); }
__device__ inline float2 cmul(float2 a, float2 b){
    return make_float2(a.x*b.x - a.y*b.y, a.x*b.y + a.y*b.x);
}
__device__ inline float2 cmuli(float2 a, float s){ return make_float2(-s*a.y, s*a.x); }

// ---------------------------------------------------------------------------
// Merged transpose+convert for all 7 weights.
// ---------------------------------------------------------------------------
__global__ __launch_bounds__(256) void transpose_cvt_all(
    const float* __restrict__ s0, const float* __restrict__ s1,
    const float* __restrict__ s2, const float* __restrict__ s3,
    const float* __restrict__ s4, const float* __restrict__ s5,
    const float* __restrict__ s6, bf16* __restrict__ Wt)
{
    const int z = blockIdx.z;
    const int R = (z == 6) ? 1024 : 512;
    if (blockIdx.y * 32 >= R) return;
    const float* src = (z == 0) ? s0 : (z == 1) ? s1 : (z == 2) ? s2 :
                       (z == 3) ? s3 : (z == 4) ? s4 : (z == 5) ? s5 : s6;
    bf16* dst = Wt + (long)z * 262144;
    const int C = 512;

    __shared__ float tile[32][33];
    const int bx = blockIdx.x * 32;
    const int by = blockIdx.y * 32;
    const int tx = threadIdx.x, ty = threadIdx.y;
#pragma unroll
    for (int i = 0; i < 32; i += 8)
        tile[ty + i][tx] = src[(long)(by + ty + i) * C + bx + tx];
    __syncthreads();
#pragma unroll
    for (int i = 0; i < 32; i += 8)
        dst[(long)(bx + ty + i) * R + by + tx] = __float2bfloat16(tile[tx][ty + i]);
}

// ---------------------------------------------------------------------------
// MFMA bf16 GEMM (unchanged). Tile 128x128, BK=32, 4 waves.
// ---------------------------------------------------------------------------
__global__ __launch_bounds__(256) void mfma_gemm(
    const void* __restrict__ Av, const void* __restrict__ Av2,
    int a_type, int lda, int ksplit,
    const bf16* __restrict__ Bt, int ldb,
    const float* __restrict__ bias0, const float* __restrict__ bias1,
    const float* __restrict__ bias2,
    void* __restrict__ C0, void* __restrict__ C1, void* __restrict__ C2,
    int nper, int out_type, int ldc, int K,
    const float* __restrict__ e0, const float* __restrict__ e1,
    const float* __restrict__ e2, const float* __restrict__ e3)
{
    __shared__ short Asub[128 * 40];
    __shared__ short Bsub[128 * 40];

    const int tid = threadIdx.x;
    const int n0 = blockIdx.x * 128;
    const int m0 = blockIdx.y * 128;
    const int l  = tid & 63;
    const int wv = tid >> 6;
    const int wm = wv & 1, wn = wv >> 1;

    f4_t acc[4][4];
#pragma unroll
    for (int i = 0; i < 4; i++)
#pragma unroll
        for (int j = 0; j < 4; j++)
            acc[i][j] = (f4_t)0.f;

    const int srow = tid >> 2;
    const int sc8  = (tid & 3) * 8;

    for (int k0 = 0; k0 < K; k0 += 32) {
        const void* As = (k0 < ksplit) ? Av : Av2;
        const int kk = (k0 < ksplit) ? k0 : (k0 - ksplit);
#pragma unroll
        for (int p = 0; p < 2; p++) {
            const int row = srow + p * 64;
            bf8_t av;
            if (a_type == 0) {
                av = *(const bf8_t*)((const bf16*)As
                    + (long)(m0 + row) * lda + kk + sc8);
            } else if (a_type == 1) {
                const float4* src = (const float4*)((const float*)As
                    + (long)(m0 + row) * lda + kk + sc8);
                float4 u0 = src[0], u1 = src[1];
                av[0] = (short)f2bf(u0.x); av[1] = (short)f2bf(u0.y);
                av[2] = (short)f2bf(u0.z); av[3] = (short)f2bf(u0.w);
                av[4] = (short)f2bf(u1.x); av[5] = (short)f2bf(u1.y);
                av[6] = (short)f2bf(u1.z); av[7] = (short)f2bf(u1.w);
            } else {
                const ushort2* src = (const ushort2*)As
                    + (long)(m0 + row) * lda + kk + sc8;
#pragma unroll
                for (int j = 0; j < 8; j++) av[j] = (short)src[j].x;
            }
            *(bf8_t*)&Asub[row * 40 + sc8] = av;

            bf8_t bv = *(const bf8_t*)(Bt + (long)(n0 + row) * ldb + k0 + sc8);
            *(bf8_t*)&Bsub[row * 40 + sc8] = bv;
        }
        __syncthreads();

        bf8_t a_frag[4], b_frag[4];
        const int ko = (l >> 4) * 8;
        const int lr = l & 15;
#pragma unroll
        for (int fm = 0; fm < 4; fm++)
            a_frag[fm] = *(bf8_t*)&Asub[(wm * 64 + fm * 16 + lr) * 40 + ko];
#pragma unroll
        for (int fn = 0; fn < 4; fn++)
            b_frag[fn] = *(bf8_t*)&Bsub[(wn * 64 + fn * 16 + lr) * 40 + ko];
#pragma unroll
        for (int fm = 0; fm < 4; fm++)
#pragma unroll
            for (int fn = 0; fn < 4; fn++)
                acc[fm][fn] = __builtin_amdgcn_mfma_f32_16x16x32_bf16(
                    b_frag[fn], a_frag[fm], acc[fm][fn], 0, 0, 0);
        __syncthreads();
    }

    const int sel = n0 / nper;
    const int nb  = sel * nper;
    const float* biasl = (sel == 0) ? bias0 : ((sel == 1) ? bias1 : bias2);
    void* Cl = (sel == 0) ? C0 : ((sel == 1) ? C1 : C2);

    const int em = m0 + wm * 64 + (l & 15);
    const int en = n0 + wn * 64 + ((l >> 4) << 2);
#pragma unroll
    for (int fm = 0; fm < 4; fm++) {
        const long m = em + fm * 16;
        float bnm = 0.f, bnr = 1.f, bng = 1.f, bnb = 0.f;
        if (out_type == 3) {
            const int c = (int)(m & 511);
            bnm = e0[c];
            bnr = 1.0f / sqrtf(e1[c] + 1e-5f);
            bng = e2[c];
            bnb = e3[c];
        }
#pragma unroll
        for (int fn = 0; fn < 4; fn++) {
            const int n = en + fn * 16;
            const int nl = n - nb;
            f4_t v = acc[fm][fn];
            if (biasl) {
#pragma unroll
                for (int r = 0; r < 4; r++) v[r] += biasl[nl + r];
            }
            if (out_type == 0) {
                float4 o; o.x = v[0]; o.y = v[1]; o.z = v[2]; o.w = v[3];
                *(float4*)((float*)Cl + m * ldc + nl) = o;
            } else if (out_type == 1) {
                union { unsigned short u[4]; ushort4 q; } o;
#pragma unroll
                for (int r = 0; r < 4; r++) o.u[r] = f2bf(v[r]);
                *(ushort4*)((bf16*)Cl + m * ldc + nl) = o.q;
            } else if (out_type == 2) {
                union { ushort2 u2[4]; uint4 q; } o;
#pragma unroll
                for (int r = 0; r < 4; r++) { o.u2[r].x = f2bf(v[r]); o.u2[r].y = 0; }
                *(uint4*)((ushort2*)Cl + m * ldc + nl) = o.q;
            } else if (out_type == 3) {
                union { unsigned short u[4]; ushort4 q; } o;
#pragma unroll
                for (int r = 0; r < 4; r++)
                    o.u[r] = f2bf(fmaxf((v[r] - bnm) * bnr * bng + bnb, 0.f));
                *(ushort4*)((bf16*)Cl + m * ldc + nl) = o.q;
            } else {
                union { unsigned short u[4]; ushort4 q; } rsd;
                rsd.q = *(const ushort4*)((const unsigned short*)e0 + m * ldc + nl);
                float4 o;
                o.x = v[0] + bf2f(rsd.u[0]);
                o.y = v[1] + bf2f(rsd.u[1]);
                o.z = v[2] + bf2f(rsd.u[2]);
                o.w = v[3] + bf2f(rsd.u[3]);
                *(float4*)((float*)Cl + m * ldc + nl) = o;
            }
        }
    }
}

// ---------------------------------------------------------------------------
// Radix-8 512-point Stockham FFT (two-buffer form, used by row kernels).
// ---------------------------------------------------------------------------
__device__ inline void dft8(float2* x, float sgn)
{
    const float c45 = 0.70710678118654752f;
    float2 e0, e1, e2, e3, o0, o1, o2, o3;
    {
        float2 u0 = cadd(x[0], x[4]), u1 = csub(x[0], x[4]);
        float2 u2 = cadd(x[2], x[6]), u3 = cmuli(csub(x[2], x[6]), sgn);
        e0 = cadd(u0, u2); e1 = cadd(u1, u3); e2 = csub(u0, u2); e3 = csub(u1, u3);
    }
    {
        float2 u0 = cadd(x[1], x[5]), u1 = csub(x[1], x[5]);
        float2 u2 = cadd(x[3], x[7]), u3 = cmuli(csub(x[3], x[7]), sgn);
        o0 = cadd(u0, u2); o1 = cadd(u1, u3); o2 = csub(u0, u2); o3 = csub(u1, u3);
    }
    const float2 w1 = make_float2(c45, sgn * c45);
    const float2 w3 = make_float2(-c45, sgn * c45);
    o1 = cmul(o1, w1);
    o2 = cmuli(o2, sgn);
    o3 = cmul(o3, w3);
    x[0] = cadd(e0, o0); x[4] = csub(e0, o0);
    x[1] = cadd(e1, o1); x[5] = csub(e1, o1);
    x[2] = cadd(e2, o2); x[6] = csub(e2, o2);
    x[3] = cadd(e3, o3); x[7] = csub(e3, o3);
}

__device__ inline void fft512_r8(float2* bx0, float2* by0, int lane, float sign)
{
    float2* bx = bx0;
    float2* by = by0;
#pragma unroll
    for (int st = 0; st < 3; st++) {
        int n, m, sstr, p, q;
        if (st == 0)      { n = 512; m = 64; sstr = 1;  p = lane;      q = 0; }
        else if (st == 1) { n = 64;  m = 8;  sstr = 8;  p = lane >> 3; q = lane & 7; }
        else              { n = 8;   m = 1;  sstr = 64; p = 0;         q = lane; }
        float2 x[8];
#pragma unroll
        for (int r = 0; r < 8; r++) x[r] = bx[FOFF(q + sstr * (p + r * m))];
        dft8(x, sign);
        if (p) {
            float ang = sign * (2.0f * FFT_PI) * (float)p / (float)n;
            float sw, cw;
            __sincosf(ang, &sw, &cw);
            float2 w = make_float2(cw, sw), wk = w;
#pragma unroll
            for (int k = 1; k < 8; k++) { x[k] = cmul(x[k], wk); wk = cmul(wk, w); }
        }
#pragma unroll
        for (int k = 0; k < 8; k++) by[FOFF(q + sstr * (8 * p + k))] = x[k];
        __syncthreads();
        float2* t = bx; bx = by; by = t;
    }
}

// in-place row FFT on cplx-bf16, 4 lines/block, fused over 3 buffers (Q/K/V)
__global__ __launch_bounds__(256) void fft8_rows_c2c3(
    ushort2* __restrict__ data, float sign)
{
    __shared__ float2 B0[4][576], B1[4][576];
    const int buf = blockIdx.x >> 12;
    const int lb  = blockIdx.x & 4095;
    const int li = threadIdx.x >> 6, lane = threadIdx.x & 63;
    ushort2* s = data + (long)buf * 8388608 + ((long)lb * 4 + li) * 512;
    {
        uint4 r0 = *(const uint4*)(s + lane * 8);
        uint4 r1 = *(const uint4*)(s + lane * 8 + 4);
        float2* dst = &B0[li][9 * lane];
        const ushort2* pp = (const ushort2*)&r0;
#pragma unroll
        for (int j = 0; j < 4; j++) dst[j] = c_load(pp + j);
        pp = (const ushort2*)&r1;
#pragma unroll
        for (int j = 0; j < 4; j++) dst[4 + j] = c_load(pp + j);
    }
    __syncthreads();
    fft512_r8(B0[li], B1[li], lane, sign);
    {
        float2* src = &B1[li][9 * lane];
        union { ushort2 u[4]; uint4 q; } o0, o1;
#pragma unroll
        for (int j = 0; j < 4; j++) {
            float2 z = src[j]; o0.u[j].x = f2bf(z.x); o0.u[j].y = f2bf(z.y);
        }
#pragma unroll
        for (int j = 0; j < 4; j++) {
            float2 z = src[4 + j]; o1.u[j].x = f2bf(z.x); o1.u[j].y = f2bf(z.y);
        }
        *(uint4*)(s + lane * 8) = o0.q;
        *(uint4*)(s + lane * 8 + 4) = o1.q;
    }
}

// real-bf16 src -> cplx-bf16 dst, forward row FFT (tep)
__global__ __launch_bounds__(256) void fft8_rows_r2c(
    const bf16* __restrict__ srcb, ushort2* __restrict__ dst)
{
    __shared__ float2 B0[4][576], B1[4][576];
    const int li = threadIdx.x >> 6, lane = threadIdx.x & 63;
    const long line = (long)blockIdx.x * 4 + li;
    {
        uint4 raw = *(const uint4*)((const unsigned short*)srcb + line * 512 + lane * 8);
        const unsigned short* pp = (const unsigned short*)&raw;
        float2* d = &B0[li][9 * lane];
#pragma unroll
        for (int j = 0; j < 8; j++) d[j] = make_float2(bf2f(pp[j]), 0.f);
    }
    __syncthreads();
    fft512_r8(B0[li], B1[li], lane, -1.f);
    {
        ushort2* s = dst + line * 512;
        float2* src = &B1[li][9 * lane];
        union { ushort2 u[4]; uint4 q; } o0, o1;
#pragma unroll
        for (int j = 0; j < 4; j++) {
            float2 z = src[j]; o0.u[j].x = f2bf(z.x); o0.u[j].y = f2bf(z.y);
        }
#pragma unroll
        for (int j = 0; j < 4; j++) {
            float2 z = src[4 + j]; o1.u[j].x = f2bf(z.x); o1.u[j].y = f2bf(z.y);
        }
        *(uint4*)(s + lane * 8) = o0.q;
        *(uint4*)(s + lane * 8 + 4) = o1.q;
    }
}

// gated row inverse FFT: sigmoid(g2)*tep, ifft, scale 1/512, in place
__global__ __launch_bounds__(256) void fft8_rows_gated(
    const bf16* __restrict__ g2, ushort2* __restrict__ tep)
{
    __shared__ float2 B0[4][576], B1[4][576];
    const int li = threadIdx.x >> 6, lane = threadIdx.x & 63;
    const long line = (long)blockIdx.x * 4 + li;
    ushort2* s = tep + line * 512;
    {
        uint4 rg = *(const uint4*)((const unsigned short*)g2 + line * 512 + lane * 8);
        uint4 r0 = *(const uint4*)(s + lane * 8);
        uint4 r1 = *(const uint4*)(s + lane * 8 + 4);
        const unsigned short* gp = (const unsigned short*)&rg;
        float2* d = &B0[li][9 * lane];
        const ushort2* pp = (const ushort2*)&r0;
#pragma unroll
        for (int j = 0; j < 4; j++) {
            float sg = 1.0f / (1.0f + __expf(-bf2f(gp[j])));
            float2 z = c_load(pp + j);
            d[j] = make_float2(sg * z.x, sg * z.y);
        }
        pp = (const ushort2*)&r1;
#pragma unroll
        for (int j = 0; j < 4; j++) {
            float sg = 1.0f / (1.0f + __expf(-bf2f(gp[4 + j])));
            float2 z = c_load(pp + j);
            d[4 + j] = make_float2(sg * z.x, sg * z.y);
        }
    }
    __syncthreads();
    fft512_r8(B0[li], B1[li], lane, +1.f);
    {
        const float sc = 1.0f / 512.0f;
        float2* src = &B1[li][9 * lane];
        union { ushort2 u[4]; uint4 q; } o0, o1;
#pragma unroll
        for (int j = 0; j < 4; j++) {
            float2 z = src[j];
            o0.u[j].x = f2bf(z.x * sc); o0.u[j].y = f2bf(z.y * sc);
        }
#pragma unroll
        for (int j = 0; j < 4; j++) {
            float2 z = src[4 + j];
            o1.u[j].x = f2bf(z.x * sc); o1.u[j].y = f2bf(z.y * sc);
        }
        *(uint4*)(s + lane * 8) = o0.q;
        *(uint4*)(s + lane * 8 + 4) = o1.q;
    }
}

// ---------------------------------------------------------------------------
// Column FFT v2: 16 columns/block, single 64 KB LDS buffer, in-place stages
// (read-all -> barrier -> compute+write -> barrier; Stockham in/out index
// sets are permutations, so in-place is race-free). Fused over 4 buffers
// (Q/K/V/T); buf==3 writes real parts to tepReal.
// ---------------------------------------------------------------------------
__global__ __launch_bounds__(256) void fft8_cols16_c2c4(
    ushort2* __restrict__ data, bf16* __restrict__ tepReal, float sign)
{
    __shared__ float2 B[512][16];   // exactly 65536 B
    const int buf = blockIdx.x >> 10;
    const int rem = blockIdx.x & 1023;
    const int b   = rem >> 5;
    const int c0  = (rem & 31) * 16;
    ushort2* base = data + (long)buf * 8388608 + (long)b * 262144 + c0;
    const int t = threadIdx.x;
    const int lr = t >> 2;     // 0..63
    const int lq = t & 3;      // quad of 4 columns

#pragma unroll
    for (int it = 0; it < 8; it++) {
        const int row = it * 64 + lr;
        uint4 raw = *(const uint4*)(base + (long)row * 512 + lq * 4);
        const ushort2* pp = (const ushort2*)&raw;
#pragma unroll
        for (int j = 0; j < 4; j++) B[row][lq * 4 + j] = c_load(pp + j);
    }
    __syncthreads();

    const int col = t & 15;
    const int rb  = t >> 4;    // 0..15
#pragma unroll
    for (int st = 0; st < 3; st++) {
        int n, m, s;
        if (st == 0)      { n = 512; m = 64; s = 1;  }
        else if (st == 1) { n = 64;  m = 8;  s = 8;  }
        else              { n = 8;   m = 1;  s = 64; }
        float2 x[4][8];
        int ps[4], qs[4];
#pragma unroll
        for (int i = 0; i < 4; i++) {
            const int role = rb + 16 * i;
            int p, q;
            if (st == 0)      { p = role;      q = 0; }
            else if (st == 1) { p = role >> 3; q = role & 7; }
            else              { p = 0;         q = role; }
            ps[i] = p; qs[i] = q;
#pragma unroll
            for (int r = 0; r < 8; r++)
                x[i][r] = B[q + s * (p + r * m)][col];
        }
        __syncthreads();
#pragma unroll
        for (int i = 0; i < 4; i++) {
            dft8(x[i], sign);
            const int p = ps[i];
            if (p) {
                float ang = sign * (2.0f * FFT_PI) * (float)p / (float)n;
                float sw, cw;
                __sincosf(ang, &sw, &cw);
                float2 w = make_float2(cw, sw), wk = w;
#pragma unroll
                for (int k = 1; k < 8; k++) { x[i][k] = cmul(x[i][k], wk); wk = cmul(wk, w); }
            }
#pragma unroll
            for (int k = 0; k < 8; k++)
                B[qs[i] + s * (8 * p + k)][col] = x[i][k];
        }
        __syncthreads();
    }

#pragma unroll
    for (int it = 0; it < 8; it++) {
        const int row = it * 64 + lr;
        union { ushort2 u[4]; uint4 q4; } o;
        union { unsigned short u[4]; ushort4 q4; } orl;
#pragma unroll
        for (int j = 0; j < 4; j++) {
            float2 z = B[row][lq * 4 + j];
            o.u[j].x = f2bf(z.x); o.u[j].y = f2bf(z.y);
            orl.u[j] = o.u[j].x;
        }
        *(uint4*)(base + (long)row * 512 + lq * 4) = o.q4;
        if (buf == 3)
            *(ushort4*)(tepReal + (long)b * 262144 + (long)row * 512 + c0 + lq * 4) = orl.q4;
    }
}

// Column inverse FFT + abs -> bf16 real (scale 1/512), 16 columns/block.
__global__ __launch_bounds__(256) void fft8_cols16_abs(
    const ushort2* __restrict__ src, bf16* __restrict__ dst)
{
    __shared__ float2 B[512][16];
    const int b  = blockIdx.x >> 5;
    const int c0 = (blockIdx.x & 31) * 16;
    const ushort2* base = src + (long)b * 262144 + c0;
    const int t = threadIdx.x;
    const int lr = t >> 2;
    const int lq = t & 3;

#pragma unroll
    for (int it = 0; it < 8; it++) {
        const int row = it * 64 + lr;
        uint4 raw = *(const uint4*)(base + (long)row * 512 + lq * 4);
        const ushort2* pp = (const ushort2*)&raw;
#pragma unroll
        for (int j = 0; j < 4; j++) B[row][lq * 4 + j] = c_load(pp + j);
    }
    __syncthreads();

    const int col = t & 15;
    const int rb  = t >> 4;
#pragma unroll
    for (int st = 0; st < 3; st++) {
        int n, m, s;
        if (st == 0)      { n = 512; m = 64; s = 1;  }
        else if (st == 1) { n = 64;  m = 8;  s = 8;  }
        else              { n = 8;   m = 1;  s = 64; }
        float2 x[4][8];
        int ps[4], qs[4];
#pragma unroll
        for (int i = 0; i < 4; i++) {
            const int role = rb + 16 * i;
            int p, q;
            if (st == 0)      { p = role;      q = 0; }
            else if (st == 1) { p = role >> 3; q = role & 7; }
            else              { p = 0;         q = role; }
            ps[i] = p; qs[i] = q;
#pragma unroll
            for (int r = 0; r < 8; r++)
                x[i][r] = B[q + s * (p + r * m)][col];
        }
        __syncthreads();
#pragma unroll
        for (int i = 0; i < 4; i++) {
            dft8(x[i], +1.f);
            const int p = ps[i];
            if (p) {
                float ang = (2.0f * FFT_PI) * (float)p / (float)n;
                float sw, cw;
                __sincosf(ang, &sw, &cw);
                float2 w = make_float2(cw, sw), wk = w;
#pragma unroll
                for (int k = 1; k < 8; k++) { x[i][k] = cmul(x[i][k], wk); wk = cmul(wk, w); }
            }
#pragma unroll
            for (int k = 0; k < 8; k++)
                B[qs[i] + s * (8 * p + k)][col] = x[i][k];
        }
        __syncthreads();
    }

    const float sc = 1.0f / 512.0f;
#pragma unroll
    for (int it = 0; it < 8; it++) {
        const int row = it * 64 + lr;
        union { unsigned short u[4]; ushort4 q4; } o;
#pragma unroll
        for (int j = 0; j < 4; j++) {
            float2 z = B[row][lq * 4 + j];
            o.u[j] = f2bf(sqrtf(z.x * z.x + z.y * z.y) * sc);
        }
        *(ushort4*)(dst + (long)b * 262144 + (long)row * 512 + c0 + lq * 4) = o.q4;
    }
}

// ---------------------------------------------------------------------------
// attn v3.1 (unchanged from R8).
// ---------------------------------------------------------------------------
__global__ __launch_bounds__(256) void attn_kernel(
    const ushort2* __restrict__ qf, const ushort2* __restrict__ kf,
    const ushort2* __restrict__ vf, const float* __restrict__ temp,
    bf16* __restrict__ out_f)
{
    __shared__ float2 QS[4][8][66];
    __shared__ float2 KS[4][8][66];
    __shared__ float2 ATT[4][8][9];

    const int li = threadIdx.x >> 6, lane = threadIdx.x & 63;
    const int bc = blockIdx.x * 4 + li;
    const long base = (long)bc * 512;

    float2 q[8], k[8], v[8];
#pragma unroll
    for (int h = 0; h < 8; h++) {
        q[h] = c_load(qf + base + h * 64 + lane);
        k[h] = c_load(kf + base + h * 64 + lane);
        v[h] = c_load(vf + base + h * 64 + lane);
    }

#pragma unroll
    for (int h = 0; h < 8; h++) {
        float pq = q[h].x * q[h].x + q[h].y * q[h].y;
        float pk = k[h].x * k[h].x + k[h].y * k[h].y;
#pragma unroll
        for (int o = 32; o > 0; o >>= 1) {
            pq += __shfl_xor(pq, o, 64);
            pk += __shfl_xor(pk, o, 64);
        }
        float iq = 1.0f / fmaxf(sqrtf(pq), 1e-12f);
        float ik = 1.0f / fmaxf(sqrtf(pk), 1e-12f);
        q[h].x *= iq; q[h].y *= iq;
        k[h].x *= ik; k[h].y *= ik;
        QS[li][h][lane] = q[h];
        KS[li][h][lane] = k[h];
    }
    __syncthreads();

    {
        const int h = lane >> 3, g = lane & 7;
        float ar = 0.f, ai = 0.f;
#pragma unroll 8
        for (int w = 0; w < 64; w += 2) {
            float4 aa = *(const float4*)&QS[li][h][w];
            float4 bb = *(const float4*)&KS[li][g][w];
            ar += aa.x * bb.x - aa.y * bb.y + aa.z * bb.z - aa.w * bb.w;
            ai += aa.x * bb.y + aa.y * bb.x + aa.z * bb.w + aa.w * bb.z;
        }
        float tm = temp[h];
        ATT[li][h][g] = make_float2(ar * tm, ai * tm);
    }
    __syncthreads();

    if (lane < 8) {
        const int h = lane;
        float mr = -1e30f, mi = -1e30f;
        for (int g = 0; g < 8; g++) {
            mr = fmaxf(mr, ATT[li][h][g].x);
            mi = fmaxf(mi, ATT[li][h][g].y);
        }
        float er[8], ei[8];
        float sr = 0.f, si = 0.f;
        for (int g = 0; g < 8; g++) {
            er[g] = __expf(ATT[li][h][g].x - mr); sr += er[g];
            ei[g] = __expf(ATT[li][h][g].y - mi); si += ei[g];
        }
        float isr = 1.f / sr, isi = 1.f / si;
        for (int g = 0; g < 8; g++)
            ATT[li][h][g] = make_float2(er[g] * isr, ei[g] * isi);
    }
    __syncthreads();

    float2 o[8];
#pragma unroll
    for (int h = 0; h < 8; h++) {
        float orr = 0.f, oi = 0.f;
#pragma unroll
        for (int g = 0; g < 8; g++) {
            float2 a = ATT[li][h][g], b = v[g];
            orr += a.x * b.x - a.y * b.y;
            oi  += a.x * b.y + a.y * b.x;
        }
        o[h] = make_float2(orr, oi);
    }

#pragma unroll
    for (int m = 32; m >= 1; m >>= 1) {
        float ang = (FFT_PI / (float)m) * (float)(lane & (m - 1));
        float sw, cw;
        __sincosf(ang, &sw, &cw);
        const bool low = (lane & m) == 0;
#pragma unroll
        for (int h = 0; h < 8; h++) {
            float px = __shfl_xor(o[h].x, m, 64);
            float py = __shfl_xor(o[h].y, m, 64);
            float nx, ny;
            if (low) {
                nx = o[h].x + px;
                ny = o[h].y + py;
            } else {
                float dx = px - o[h].x;
                float dy = py - o[h].y;
                nx = dx * cw - dy * sw;
                ny = dx * sw + dy * cw;
            }
            o[h].x = nx; o[h].y = ny;
        }
    }
    const int wr = brev6(lane);

    const float r2 = 0.70710678118654752f;
    const float W8x[8] = {1.f,  r2, 0.f, -r2, -1.f, -r2,  0.f,  r2};
    const float W8y[8] = {0.f,  r2, 1.f,  r2,  0.f, -r2, -1.f, -r2};
    unsigned short* stg = (unsigned short*)&QS[li][0][0];
#pragma unroll
    for (int kh = 0; kh < 8; kh++) {
        float sr = 0.f, si = 0.f;
#pragma unroll
        for (int n = 0; n < 8; n++) {
            const int idx = (n * kh) & 7;
            float wx = W8x[idx], wy = W8y[idx];
            sr += o[n].x * wx - o[n].y * wy;
            si += o[n].x * wy + o[n].y * wx;
        }
        stg[kh * 64 + wr] = f2bf(sqrtf(sr * sr + si * si) * (1.0f / 512.0f));
    }
    __syncthreads();
    uint4 ov = *(uint4*)(stg + lane * 8);
    *(uint4*)((unsigned short*)out_f + base + lane * 8) = ov;
}

// ---------------------------------------------------------------------------
extern "C" void kernel_launch(void* const* d_in, const int* in_sizes, int n_in,
                              void* d_out, int out_size, void* d_ws, size_t ws_size,
                              hipStream_t stream)
{
    const float* x     = (const float*)d_in[0];
    const float* W_in  = (const float*)d_in[1];
    const float* b_in  = (const float*)d_in[2];
    const float* W_q   = (const float*)d_in[3];
    const float* b_q   = (const float*)d_in[4];
    const float* W_k   = (const float*)d_in[5];
    const float* b_k   = (const float*)d_in[6];
    const float* W_v   = (const float*)d_in[7];
    const float* b_v   = (const float*)d_in[8];
    const float* temp  = (const float*)d_in[9];
    const float* W1a   = (const float*)d_in[10];
    const float* b1a   = (const float*)d_in[11];
    const float* gam   = (const float*)d_in[12];
    const float* bet   = (const float*)d_in[13];
    const float* mea   = (const float*)d_in[14];
    const float* var   = (const float*)d_in[15];
    const float* W1b   = (const float*)d_in[16];
    const float* b1b   = (const float*)d_in[17];
    const float* W_out = (const float*)d_in[18];
    const float* b_out = (const float*)d_in[19];

    char* wsb = (char*)d_ws;
    const long MB = 1024 * 1024;
    bf16*    conv2b  = (bf16*)wsb;
    bf16*    tepReal = (bf16*)(wsb + 16 * MB);
    ushort2* Qb    = (ushort2*)(wsb + 32 * MB);
    ushort2* Kb    = (ushort2*)(wsb + 64 * MB);
    ushort2* Vb    = (ushort2*)(wsb + 96 * MB);
    ushort2* Tb    = (ushort2*)(wsb + 128 * MB);
    bf16*    Wt    = (bf16*)(wsb + 160 * MB);
    bf16* WT_in  = Wt;
    bf16* WT_q   = Wt + 262144;
    bf16* WT_1a  = Wt + 4 * 262144;
    bf16* WT_1b  = Wt + 5 * 262144;
    bf16* WT_out = Wt + 6 * 262144;
    bf16* outF = (bf16*)Qb;
    bf16* g1b  = (bf16*)Kb;
    bf16* outL = (bf16*)Kb;
    bf16* g2b  = (bf16*)Vb;

    const dim3 ggrid(4, 128), gblk(256);
    const int BIG = 1 << 30;
    const int RB = 4096;

    transpose_cvt_all<<<dim3(16, 32, 7), dim3(32, 8), 0, stream>>>(
        W_in, W_q, W_k, W_v, W1a, W1b, W_out, Wt);

    // 1. conv2 = x @ W_in + b_in -> bf16
    mfma_gemm<<<ggrid, gblk, 0, stream>>>(
        x, x, 1, 512, BIG, WT_in, 512, b_in, nullptr, nullptr,
        conv2b, nullptr, nullptr, BIG, 1, 512, 512,
        nullptr, nullptr, nullptr, nullptr);

    // 2. fused q/k/v projections
    mfma_gemm<<<dim3(12, 128), gblk, 0, stream>>>(
        conv2b, conv2b, 0, 512, BIG, WT_q, 512, b_q, b_k, b_v,
        Qb, Kb, Vb, 512, 2, 512, 512,
        nullptr, nullptr, nullptr, nullptr);

    // 3. row FFTs: Q,K,V fused; tep r2c from conv2
    fft8_rows_c2c3<<<3 * RB, 256, 0, stream>>>(Qb, -1.f);
    fft8_rows_r2c<<<RB, 256, 0, stream>>>(conv2b, Tb);

    // 4. col FFTs: Q,K,V,T fused, 16 cols/block (+ tepReal side output)
    fft8_cols16_c2c4<<<4096, 256, 0, stream>>>(Qb, tepReal, -1.f);

    // 5. attention -> out_f bf16 over Qb
    attn_kernel<<<RB, 256, 0, stream>>>(Qb, Kb, Vb, temp, outF);

    // 6. g1 = BN_ReLU(tepReal @ W1a + b1a) -> bf16
    mfma_gemm<<<ggrid, gblk, 0, stream>>>(
        tepReal, tepReal, 0, 512, BIG, WT_1a, 512, b1a, nullptr, nullptr,
        g1b, nullptr, nullptr, BIG, 3, 512, 512,
        mea, var, gam, bet);

    // 7. g2 = g1 @ W1b + b1b -> bf16
    mfma_gemm<<<ggrid, gblk, 0, stream>>>(
        g1b, g1b, 0, 512, BIG, WT_1b, 512, b1b, nullptr, nullptr,
        g2b, nullptr, nullptr, BIG, 1, 512, 512,
        nullptr, nullptr, nullptr, nullptr);

    // 8. gated ifft2 + abs -> out_l bf16 (over Kb)
    fft8_rows_gated<<<RB, 256, 0, stream>>>(g2b, Tb);
    fft8_cols16_abs<<<1024, 256, 0, stream>>>(Tb, outL);

    // 9. d_out = [out_f | out_l] @ W_out + b_out + conv2 (K=1024, fused residual)
    mfma_gemm<<<ggrid, gblk, 0, stream>>>(
        outF, outL, 0, 512, 512, WT_out, 1024, b_out, nullptr, nullptr,
        d_out, nullptr, nullptr, BIG, 4, 512, 1024,
        (const float*)conv2b, nullptr, nullptr, nullptr);
}

// Round 10
// 538.936 us; speedup vs baseline: 5.4873x; 1.0567x over previous
//
#include <hip/hip_runtime.h>
#include <hip/hip_bf16.h>

#define FFT_PI 3.14159265358979323846f
#define FOFF(i) ((i) + ((i) >> 3))   // padded LDS offset for row FFTs

typedef __hip_bfloat16 bf16;
typedef short bf8_t __attribute__((ext_vector_type(8)));
typedef float f4_t __attribute__((ext_vector_type(4)));

__device__ inline float bf2f(unsigned short u) {
    union { unsigned int i; float f; } v; v.i = ((unsigned int)u) << 16; return v.f;
}
__device__ inline unsigned short f2bf(float f) {
    bf16 h = __float2bfloat16(f);
    union { bf16 h; unsigned short u; } v; v.h = h; return v.u;
}
__device__ inline float2 c_load(const ushort2* p) {
    ushort2 u = *p;
    return make_float2(bf2f(u.x), bf2f(u.y));
}
__device__ inline int brev6(int t) {
    return ((t & 1) << 5) | ((t & 2) << 3) | ((t & 4) << 1) |
           ((t & 8) >> 1) | ((t & 16) >> 3) | ((t & 32) >> 5);
}
__device__ inline float2 cadd(float2 a, float2 b){ return make_float2(a.x+b.x, a.y+b.y); }
__device__ inline float2 csub(float2 a, float2 b){ return make_float2(a.x-b.x, a.y-b.y); }
__device__ inline float2 cmul(float2 a, float2 b){
    return make_float2(a.x*b.x - a.y*b.y, a.x*b.y + a.y*b.x);
}
__device__ inline float2 cmuli(float2 a, float s){ return make_float2(-s*a.y, s*a.x); }

// async global->LDS, 16 B per lane; LDS dest = base + lane*16 (HW contract)
__device__ inline void async_load16(const void* gp, void* lp) {
    __builtin_amdgcn_global_load_lds(
        (const __attribute__((address_space(1))) void*)gp,
        (__attribute__((address_space(3))) void*)lp, 16, 0, 0);
}

// ---------------------------------------------------------------------------
// Merged transpose+convert for all 7 weights.
// ---------------------------------------------------------------------------
__global__ __launch_bounds__(256) void transpose_cvt_all(
    const float* __restrict__ s0, const float* __restrict__ s1,
    const float* __restrict__ s2, const float* __restrict__ s3,
    const float* __restrict__ s4, const float* __restrict__ s5,
    const float* __restrict__ s6, bf16* __restrict__ Wt)
{
    const int z = blockIdx.z;
    const int R = (z == 6) ? 1024 : 512;
    if (blockIdx.y * 32 >= R) return;
    const float* src = (z == 0) ? s0 : (z == 1) ? s1 : (z == 2) ? s2 :
                       (z == 3) ? s3 : (z == 4) ? s4 : (z == 5) ? s5 : s6;
    bf16* dst = Wt + (long)z * 262144;
    const int C = 512;

    __shared__ float tile[32][33];
    const int bx = blockIdx.x * 32;
    const int by = blockIdx.y * 32;
    const int tx = threadIdx.x, ty = threadIdx.y;
#pragma unroll
    for (int i = 0; i < 32; i += 8)
        tile[ty + i][tx] = src[(long)(by + ty + i) * C + bx + tx];
    __syncthreads();
#pragma unroll
    for (int i = 0; i < 32; i += 8)
        dst[(long)(bx + ty + i) * R + by + tx] = __float2bfloat16(tile[tx][ty + i]);
}

// ---------------------------------------------------------------------------
// MFMA bf16 GEMM v2: tile 128x128, BK=32, 4 waves. Unpadded LDS [128][32]
// shorts; global_load_lds width-16 staging for bf16 A (a_type 0) and all B.
// a_type: 0 = bf16 [m][k] (async), 1 = f32 [m][k] (manual convert).
// Two A buffers via ksplit. Multi-output via nper/sel. out_type as before.
// ---------------------------------------------------------------------------
__global__ __launch_bounds__(256) void mfma_gemm(
    const void* __restrict__ Av, const void* __restrict__ Av2,
    int a_type, int lda, int ksplit,
    const bf16* __restrict__ Bt, int ldb,
    const float* __restrict__ bias0, const float* __restrict__ bias1,
    const float* __restrict__ bias2,
    void* __restrict__ C0, void* __restrict__ C1, void* __restrict__ C2,
    int nper, int out_type, int ldc, int K,
    const float* __restrict__ e0, const float* __restrict__ e1,
    const float* __restrict__ e2, const float* __restrict__ e3)
{
    __shared__ short Asub[128 * 32];   // unpadded, 8 KB
    __shared__ short Bsub[128 * 32];

    const int tid = threadIdx.x;
    const int n0 = blockIdx.x * 128;
    const int m0 = blockIdx.y * 128;
    const int l  = tid & 63;
    const int wv = tid >> 6;
    const int wm = wv & 1, wn = wv >> 1;

    f4_t acc[4][4];
#pragma unroll
    for (int i = 0; i < 4; i++)
#pragma unroll
        for (int j = 0; j < 4; j++)
            acc[i][j] = (f4_t)0.f;

    const int crow = l >> 2;        // row within 16-row chunk
    const int cpc  = (l & 3) * 8;   // k-piece (shorts)

    for (int k0 = 0; k0 < K; k0 += 32) {
        const void* As = (k0 < ksplit) ? Av : Av2;
        const int kk = (k0 < ksplit) ? k0 : (k0 - ksplit);

        if (a_type == 0) {
#pragma unroll
            for (int c = 0; c < 2; c++) {
                const int chunk = wv * 2 + c;
                const int row = chunk * 16 + crow;
                async_load16((const bf16*)As + (long)(m0 + row) * lda + kk + cpc,
                             &Asub[chunk * 512]);
                async_load16(Bt + (long)(n0 + row) * ldb + k0 + cpc,
                             &Bsub[chunk * 512]);
            }
        } else {
            // manual f32 -> bf16 staging (conv2 GEMM only)
            const int srow = tid >> 2;
            const int sc8  = (tid & 3) * 8;
#pragma unroll
            for (int p = 0; p < 2; p++) {
                const int row = srow + p * 64;
                const float4* src = (const float4*)((const float*)As
                    + (long)(m0 + row) * lda + kk + sc8);
                float4 u0 = src[0], u1 = src[1];
                bf8_t av;
                av[0] = (short)f2bf(u0.x); av[1] = (short)f2bf(u0.y);
                av[2] = (short)f2bf(u0.z); av[3] = (short)f2bf(u0.w);
                av[4] = (short)f2bf(u1.x); av[5] = (short)f2bf(u1.y);
                av[6] = (short)f2bf(u1.z); av[7] = (short)f2bf(u1.w);
                *(bf8_t*)&Asub[row * 32 + sc8] = av;
            }
#pragma unroll
            for (int c = 0; c < 2; c++) {
                const int chunk = wv * 2 + c;
                const int row = chunk * 16 + crow;
                async_load16(Bt + (long)(n0 + row) * ldb + k0 + cpc,
                             &Bsub[chunk * 512]);
            }
        }
        __syncthreads();

        bf8_t a_frag[4], b_frag[4];
        const int ko = (l >> 4) * 8;
        const int lr = l & 15;
#pragma unroll
        for (int fm = 0; fm < 4; fm++)
            a_frag[fm] = *(bf8_t*)&Asub[(wm * 64 + fm * 16 + lr) * 32 + ko];
#pragma unroll
        for (int fn = 0; fn < 4; fn++)
            b_frag[fn] = *(bf8_t*)&Bsub[(wn * 64 + fn * 16 + lr) * 32 + ko];
#pragma unroll
        for (int fm = 0; fm < 4; fm++)
#pragma unroll
            for (int fn = 0; fn < 4; fn++)
                acc[fm][fn] = __builtin_amdgcn_mfma_f32_16x16x32_bf16(
                    b_frag[fn], a_frag[fm], acc[fm][fn], 0, 0, 0);
        __syncthreads();
    }

    const int sel = n0 / nper;
    const int nb  = sel * nper;
    const float* biasl = (sel == 0) ? bias0 : ((sel == 1) ? bias1 : bias2);
    void* Cl = (sel == 0) ? C0 : ((sel == 1) ? C1 : C2);

    const int em = m0 + wm * 64 + (l & 15);
    const int en = n0 + wn * 64 + ((l >> 4) << 2);
#pragma unroll
    for (int fm = 0; fm < 4; fm++) {
        const long m = em + fm * 16;
        float bnm = 0.f, bnr = 1.f, bng = 1.f, bnb = 0.f;
        if (out_type == 3) {
            const int c = (int)(m & 511);
            bnm = e0[c];
            bnr = 1.0f / sqrtf(e1[c] + 1e-5f);
            bng = e2[c];
            bnb = e3[c];
        }
#pragma unroll
        for (int fn = 0; fn < 4; fn++) {
            const int n = en + fn * 16;
            const int nl = n - nb;
            f4_t v = acc[fm][fn];
            if (biasl) {
#pragma unroll
                for (int r = 0; r < 4; r++) v[r] += biasl[nl + r];
            }
            if (out_type == 0) {
                float4 o; o.x = v[0]; o.y = v[1]; o.z = v[2]; o.w = v[3];
                *(float4*)((float*)Cl + m * ldc + nl) = o;
            } else if (out_type == 1) {
                union { unsigned short u[4]; ushort4 q; } o;
#pragma unroll
                for (int r = 0; r < 4; r++) o.u[r] = f2bf(v[r]);
                *(ushort4*)((bf16*)Cl + m * ldc + nl) = o.q;
            } else if (out_type == 2) {
                union { ushort2 u2[4]; uint4 q; } o;
#pragma unroll
                for (int r = 0; r < 4; r++) { o.u2[r].x = f2bf(v[r]); o.u2[r].y = 0; }
                *(uint4*)((ushort2*)Cl + m * ldc + nl) = o.q;
            } else if (out_type == 3) {
                union { unsigned short u[4]; ushort4 q; } o;
#pragma unroll
                for (int r = 0; r < 4; r++)
                    o.u[r] = f2bf(fmaxf((v[r] - bnm) * bnr * bng + bnb, 0.f));
                *(ushort4*)((bf16*)Cl + m * ldc + nl) = o.q;
            } else {
                union { unsigned short u[4]; ushort4 q; } rsd;
                rsd.q = *(const ushort4*)((const unsigned short*)e0 + m * ldc + nl);
                float4 o;
                o.x = v[0] + bf2f(rsd.u[0]);
                o.y = v[1] + bf2f(rsd.u[1]);
                o.z = v[2] + bf2f(rsd.u[2]);
                o.w = v[3] + bf2f(rsd.u[3]);
                *(float4*)((float*)Cl + m * ldc + nl) = o;
            }
        }
    }
}

// ---------------------------------------------------------------------------
// Radix-8 512-point Stockham FFT (two-buffer, row kernels).
// ---------------------------------------------------------------------------
__device__ inline void dft8(float2* x, float sgn)
{
    const float c45 = 0.70710678118654752f;
    float2 e0, e1, e2, e3, o0, o1, o2, o3;
    {
        float2 u0 = cadd(x[0], x[4]), u1 = csub(x[0], x[4]);
        float2 u2 = cadd(x[2], x[6]), u3 = cmuli(csub(x[2], x[6]), sgn);
        e0 = cadd(u0, u2); e1 = cadd(u1, u3); e2 = csub(u0, u2); e3 = csub(u1, u3);
    }
    {
        float2 u0 = cadd(x[1], x[5]), u1 = csub(x[1], x[5]);
        float2 u2 = cadd(x[3], x[7]), u3 = cmuli(csub(x[3], x[7]), sgn);
        o0 = cadd(u0, u2); o1 = cadd(u1, u3); o2 = csub(u0, u2); o3 = csub(u1, u3);
    }
    const float2 w1 = make_float2(c45, sgn * c45);
    const float2 w3 = make_float2(-c45, sgn * c45);
    o1 = cmul(o1, w1);
    o2 = cmuli(o2, sgn);
    o3 = cmul(o3, w3);
    x[0] = cadd(e0, o0); x[4] = csub(e0, o0);
    x[1] = cadd(e1, o1); x[5] = csub(e1, o1);
    x[2] = cadd(e2, o2); x[6] = csub(e2, o2);
    x[3] = cadd(e3, o3); x[7] = csub(e3, o3);
}

__device__ inline void fft512_r8(float2* bx0, float2* by0, int lane, float sign)
{
    float2* bx = bx0;
    float2* by = by0;
#pragma unroll
    for (int st = 0; st < 3; st++) {
        int n, m, sstr, p, q;
        if (st == 0)      { n = 512; m = 64; sstr = 1;  p = lane;      q = 0; }
        else if (st == 1) { n = 64;  m = 8;  sstr = 8;  p = lane >> 3; q = lane & 7; }
        else              { n = 8;   m = 1;  sstr = 64; p = 0;         q = lane; }
        float2 x[8];
#pragma unroll
        for (int r = 0; r < 8; r++) x[r] = bx[FOFF(q + sstr * (p + r * m))];
        dft8(x, sign);
        if (p) {
            float ang = sign * (2.0f * FFT_PI) * (float)p / (float)n;
            float sw, cw;
            __sincosf(ang, &sw, &cw);
            float2 w = make_float2(cw, sw), wk = w;
#pragma unroll
            for (int k = 1; k < 8; k++) { x[k] = cmul(x[k], wk); wk = cmul(wk, w); }
        }
#pragma unroll
        for (int k = 0; k < 8; k++) by[FOFF(q + sstr * (8 * p + k))] = x[k];
        __syncthreads();
        float2* t = bx; bx = by; by = t;
    }
}

// All forward row FFTs in one dispatch: buf 0..2 = Q/K/V c2c in-place;
// buf 3 = r2c conv2 -> Tb. 4 lines/block.
__global__ __launch_bounds__(256) void fft8_rows_all(
    ushort2* __restrict__ qkv, const bf16* __restrict__ conv2,
    ushort2* __restrict__ tb)
{
    __shared__ float2 B0[4][576], B1[4][576];
    const int buf = blockIdx.x >> 12;
    const int lb  = blockIdx.x & 4095;
    const int li = threadIdx.x >> 6, lane = threadIdx.x & 63;
    const long line = (long)lb * 4 + li;

    if (buf < 3) {
        ushort2* s = qkv + (long)buf * 8388608 + line * 512;
        uint4 r0 = *(const uint4*)(s + lane * 8);
        uint4 r1 = *(const uint4*)(s + lane * 8 + 4);
        float2* dst = &B0[li][9 * lane];
        const ushort2* pp = (const ushort2*)&r0;
#pragma unroll
        for (int j = 0; j < 4; j++) dst[j] = c_load(pp + j);
        pp = (const ushort2*)&r1;
#pragma unroll
        for (int j = 0; j < 4; j++) dst[4 + j] = c_load(pp + j);
        __syncthreads();
        fft512_r8(B0[li], B1[li], lane, -1.f);
        float2* src = &B1[li][9 * lane];
        union { ushort2 u[4]; uint4 q; } o0, o1;
#pragma unroll
        for (int j = 0; j < 4; j++) {
            float2 z = src[j]; o0.u[j].x = f2bf(z.x); o0.u[j].y = f2bf(z.y);
        }
#pragma unroll
        for (int j = 0; j < 4; j++) {
            float2 z = src[4 + j]; o1.u[j].x = f2bf(z.x); o1.u[j].y = f2bf(z.y);
        }
        *(uint4*)(s + lane * 8) = o0.q;
        *(uint4*)(s + lane * 8 + 4) = o1.q;
    } else {
        uint4 raw = *(const uint4*)((const unsigned short*)conv2 + line * 512 + lane * 8);
        const unsigned short* pp = (const unsigned short*)&raw;
        float2* d = &B0[li][9 * lane];
#pragma unroll
        for (int j = 0; j < 8; j++) d[j] = make_float2(bf2f(pp[j]), 0.f);
        __syncthreads();
        fft512_r8(B0[li], B1[li], lane, -1.f);
        ushort2* s = tb + line * 512;
        float2* src = &B1[li][9 * lane];
        union { ushort2 u[4]; uint4 q; } o0, o1;
#pragma unroll
        for (int j = 0; j < 4; j++) {
            float2 z = src[j]; o0.u[j].x = f2bf(z.x); o0.u[j].y = f2bf(z.y);
        }
#pragma unroll
        for (int j = 0; j < 4; j++) {
            float2 z = src[4 + j]; o1.u[j].x = f2bf(z.x); o1.u[j].y = f2bf(z.y);
        }
        *(uint4*)(s + lane * 8) = o0.q;
        *(uint4*)(s + lane * 8 + 4) = o1.q;
    }
}

// gated row inverse FFT: sigmoid(g2)*tep, ifft, scale 1/512, in place
__global__ __launch_bounds__(256) void fft8_rows_gated(
    const bf16* __restrict__ g2, ushort2* __restrict__ tep)
{
    __shared__ float2 B0[4][576], B1[4][576];
    const int li = threadIdx.x >> 6, lane = threadIdx.x & 63;
    const long line = (long)blockIdx.x * 4 + li;
    ushort2* s = tep + line * 512;
    {
        uint4 rg = *(const uint4*)((const unsigned short*)g2 + line * 512 + lane * 8);
        uint4 r0 = *(const uint4*)(s + lane * 8);
        uint4 r1 = *(const uint4*)(s + lane * 8 + 4);
        const unsigned short* gp = (const unsigned short*)&rg;
        float2* d = &B0[li][9 * lane];
        const ushort2* pp = (const ushort2*)&r0;
#pragma unroll
        for (int j = 0; j < 4; j++) {
            float sg = 1.0f / (1.0f + __expf(-bf2f(gp[j])));
            float2 z = c_load(pp + j);
            d[j] = make_float2(sg * z.x, sg * z.y);
        }
        pp = (const ushort2*)&r1;
#pragma unroll
        for (int j = 0; j < 4; j++) {
            float sg = 1.0f / (1.0f + __expf(-bf2f(gp[4 + j])));
            float2 z = c_load(pp + j);
            d[4 + j] = make_float2(sg * z.x, sg * z.y);
        }
    }
    __syncthreads();
    fft512_r8(B0[li], B1[li], lane, +1.f);
    {
        const float sc = 1.0f / 512.0f;
        float2* src = &B1[li][9 * lane];
        union { ushort2 u[4]; uint4 q; } o0, o1;
#pragma unroll
        for (int j = 0; j < 4; j++) {
            float2 z = src[j];
            o0.u[j].x = f2bf(z.x * sc); o0.u[j].y = f2bf(z.y * sc);
        }
#pragma unroll
        for (int j = 0; j < 4; j++) {
            float2 z = src[4 + j];
            o1.u[j].x = f2bf(z.x * sc); o1.u[j].y = f2bf(z.y * sc);
        }
        *(uint4*)(s + lane * 8) = o0.q;
        *(uint4*)(s + lane * 8 + 4) = o1.q;
    }
}

// ---------------------------------------------------------------------------
// Column FFT: 16 columns/block, single 64 KB LDS, in-place stages (verified
// R9). Fused over 4 buffers (Q/K/V/T); buf==3 writes real parts to tepReal.
// ---------------------------------------------------------------------------
__global__ __launch_bounds__(256) void fft8_cols16_c2c4(
    ushort2* __restrict__ data, bf16* __restrict__ tepReal, float sign)
{
    __shared__ float2 B[512][16];
    const int buf = blockIdx.x >> 10;
    const int rem = blockIdx.x & 1023;
    const int b   = rem >> 5;
    const int c0  = (rem & 31) * 16;
    ushort2* base = data + (long)buf * 8388608 + (long)b * 262144 + c0;
    const int t = threadIdx.x;
    const int lr = t >> 2;
    const int lq = t & 3;

#pragma unroll
    for (int it = 0; it < 8; it++) {
        const int row = it * 64 + lr;
        uint4 raw = *(const uint4*)(base + (long)row * 512 + lq * 4);
        const ushort2* pp = (const ushort2*)&raw;
#pragma unroll
        for (int j = 0; j < 4; j++) B[row][lq * 4 + j] = c_load(pp + j);
    }
    __syncthreads();

    const int col = t & 15;
    const int rb  = t >> 4;
#pragma unroll
    for (int st = 0; st < 3; st++) {
        int n, m, s;
        if (st == 0)      { n = 512; m = 64; s = 1;  }
        else if (st == 1) { n = 64;  m = 8;  s = 8;  }
        else              { n = 8;   m = 1;  s = 64; }
        float2 x[4][8];
        int ps[4], qs[4];
#pragma unroll
        for (int i = 0; i < 4; i++) {
            const int role = rb + 16 * i;
            int p, q;
            if (st == 0)      { p = role;      q = 0; }
            else if (st == 1) { p = role >> 3; q = role & 7; }
            else              { p = 0;         q = role; }
            ps[i] = p; qs[i] = q;
#pragma unroll
            for (int r = 0; r < 8; r++)
                x[i][r] = B[q + s * (p + r * m)][col];
        }
        __syncthreads();
#pragma unroll
        for (int i = 0; i < 4; i++) {
            dft8(x[i], sign);
            const int p = ps[i];
            if (p) {
                float ang = sign * (2.0f * FFT_PI) * (float)p / (float)n;
                float sw, cw;
                __sincosf(ang, &sw, &cw);
                float2 w = make_float2(cw, sw), wk = w;
#pragma unroll
                for (int k = 1; k < 8; k++) { x[i][k] = cmul(x[i][k], wk); wk = cmul(wk, w); }
            }
#pragma unroll
            for (int k = 0; k < 8; k++)
                B[qs[i] + s * (8 * p + k)][col] = x[i][k];
        }
        __syncthreads();
    }

#pragma unroll
    for (int it = 0; it < 8; it++) {
        const int row = it * 64 + lr;
        union { ushort2 u[4]; uint4 q4; } o;
        union { unsigned short u[4]; ushort4 q4; } orl;
#pragma unroll
        for (int j = 0; j < 4; j++) {
            float2 z = B[row][lq * 4 + j];
            o.u[j].x = f2bf(z.x); o.u[j].y = f2bf(z.y);
            orl.u[j] = o.u[j].x;
        }
        *(uint4*)(base + (long)row * 512 + lq * 4) = o.q4;
        if (buf == 3)
            *(ushort4*)(tepReal + (long)b * 262144 + (long)row * 512 + c0 + lq * 4) = orl.q4;
    }
}

// Column inverse FFT + abs -> bf16 real (scale 1/512), 16 columns/block.
__global__ __launch_bounds__(256) void fft8_cols16_abs(
    const ushort2* __restrict__ src, bf16* __restrict__ dst)
{
    __shared__ float2 B[512][16];
    const int b  = blockIdx.x >> 5;
    const int c0 = (blockIdx.x & 31) * 16;
    const ushort2* base = src + (long)b * 262144 + c0;
    const int t = threadIdx.x;
    const int lr = t >> 2;
    const int lq = t & 3;

#pragma unroll
    for (int it = 0; it < 8; it++) {
        const int row = it * 64 + lr;
        uint4 raw = *(const uint4*)(base + (long)row * 512 + lq * 4);
        const ushort2* pp = (const ushort2*)&raw;
#pragma unroll
        for (int j = 0; j < 4; j++) B[row][lq * 4 + j] = c_load(pp + j);
    }
    __syncthreads();

    const int col = t & 15;
    const int rb  = t >> 4;
#pragma unroll
    for (int st = 0; st < 3; st++) {
        int n, m, s;
        if (st == 0)      { n = 512; m = 64; s = 1;  }
        else if (st == 1) { n = 64;  m = 8;  s = 8;  }
        else              { n = 8;   m = 1;  s = 64; }
        float2 x[4][8];
        int ps[4], qs[4];
#pragma unroll
        for (int i = 0; i < 4; i++) {
            const int role = rb + 16 * i;
            int p, q;
            if (st == 0)      { p = role;      q = 0; }
            else if (st == 1) { p = role >> 3; q = role & 7; }
            else              { p = 0;         q = role; }
            ps[i] = p; qs[i] = q;
#pragma unroll
            for (int r = 0; r < 8; r++)
                x[i][r] = B[q + s * (p + r * m)][col];
        }
        __syncthreads();
#pragma unroll
        for (int i = 0; i < 4; i++) {
            dft8(x[i], +1.f);
            const int p = ps[i];
            if (p) {
                float ang = (2.0f * FFT_PI) * (float)p / (float)n;
                float sw, cw;
                __sincosf(ang, &sw, &cw);
                float2 w = make_float2(cw, sw), wk = w;
#pragma unroll
                for (int k = 1; k < 8; k++) { x[i][k] = cmul(x[i][k], wk); wk = cmul(wk, w); }
            }
#pragma unroll
            for (int k = 0; k < 8; k++)
                B[qs[i] + s * (8 * p + k)][col] = x[i][k];
        }
        __syncthreads();
    }

    const float sc = 1.0f / 512.0f;
#pragma unroll
    for (int it = 0; it < 8; it++) {
        const int row = it * 64 + lr;
        union { unsigned short u[4]; ushort4 q4; } o;
#pragma unroll
        for (int j = 0; j < 4; j++) {
            float2 z = B[row][lq * 4 + j];
            o.u[j] = f2bf(sqrtf(z.x * z.x + z.y * z.y) * sc);
        }
        *(ushort4*)(dst + (long)b * 262144 + (long)row * 512 + c0 + lq * 4) = o.q4;
    }
}

// ---------------------------------------------------------------------------
// attn v3.2: 4 (b,c) per block; all-64-lane softmax (group-of-8 shfl).
// ---------------------------------------------------------------------------
__global__ __launch_bounds__(256) void attn_kernel(
    const ushort2* __restrict__ qf, const ushort2* __restrict__ kf,
    const ushort2* __restrict__ vf, const float* __restrict__ temp,
    bf16* __restrict__ out_f)
{
    __shared__ float2 QS[4][8][66];
    __shared__ float2 KS[4][8][66];
    __shared__ float2 ATT[4][8][9];

    const int li = threadIdx.x >> 6, lane = threadIdx.x & 63;
    const int bc = blockIdx.x * 4 + li;
    const long base = (long)bc * 512;

    float2 q[8], k[8], v[8];
#pragma unroll
    for (int h = 0; h < 8; h++) {
        q[h] = c_load(qf + base + h * 64 + lane);
        k[h] = c_load(kf + base + h * 64 + lane);
        v[h] = c_load(vf + base + h * 64 + lane);
    }

#pragma unroll
    for (int h = 0; h < 8; h++) {
        float pq = q[h].x * q[h].x + q[h].y * q[h].y;
        float pk = k[h].x * k[h].x + k[h].y * k[h].y;
#pragma unroll
        for (int o = 32; o > 0; o >>= 1) {
            pq += __shfl_xor(pq, o, 64);
            pk += __shfl_xor(pk, o, 64);
        }
        float iq = 1.0f / fmaxf(sqrtf(pq), 1e-12f);
        float ik = 1.0f / fmaxf(sqrtf(pk), 1e-12f);
        q[h].x *= iq; q[h].y *= iq;
        k[h].x *= ik; k[h].y *= ik;
        QS[li][h][lane] = q[h];
        KS[li][h][lane] = k[h];
    }
    __syncthreads();

    // scores + softmax, fully parallel: lane = (h = lane>>3, g = lane&7)
    {
        const int h = lane >> 3, g = lane & 7;
        float ar = 0.f, ai = 0.f;
#pragma unroll 8
        for (int w = 0; w < 64; w += 2) {
            float4 aa = *(const float4*)&QS[li][h][w];
            float4 bb = *(const float4*)&KS[li][g][w];
            ar += aa.x * bb.x - aa.y * bb.y + aa.z * bb.z - aa.w * bb.w;
            ai += aa.x * bb.y + aa.y * bb.x + aa.z * bb.w + aa.w * bb.z;
        }
        float tm = temp[h];
        ar *= tm; ai *= tm;
        // group-of-8 max (offsets 1,2,4 stay within the h-group)
        float mr = ar, mi = ai;
#pragma unroll
        for (int o = 1; o < 8; o <<= 1) {
            mr = fmaxf(mr, __shfl_xor(mr, o, 64));
            mi = fmaxf(mi, __shfl_xor(mi, o, 64));
        }
        float er = __expf(ar - mr), ei = __expf(ai - mi);
        float sr = er, si = ei;
#pragma unroll
        for (int o = 1; o < 8; o <<= 1) {
            sr += __shfl_xor(sr, o, 64);
            si += __shfl_xor(si, o, 64);
        }
        ATT[li][h][g] = make_float2(er / sr, ei / si);
    }
    __syncthreads();

    float2 o[8];
#pragma unroll
    for (int h = 0; h < 8; h++) {
        float orr = 0.f, oi = 0.f;
#pragma unroll
        for (int g = 0; g < 8; g++) {
            float2 a = ATT[li][h][g], b = v[g];
            orr += a.x * b.x - a.y * b.y;
            oi  += a.x * b.y + a.y * b.x;
        }
        o[h] = make_float2(orr, oi);
    }

#pragma unroll
    for (int m = 32; m >= 1; m >>= 1) {
        float ang = (FFT_PI / (float)m) * (float)(lane & (m - 1));
        float sw, cw;
        __sincosf(ang, &sw, &cw);
        const bool low = (lane & m) == 0;
#pragma unroll
        for (int h = 0; h < 8; h++) {
            float px = __shfl_xor(o[h].x, m, 64);
            float py = __shfl_xor(o[h].y, m, 64);
            float nx, ny;
            if (low) {
                nx = o[h].x + px;
                ny = o[h].y + py;
            } else {
                float dx = px - o[h].x;
                float dy = py - o[h].y;
                nx = dx * cw - dy * sw;
                ny = dx * sw + dy * cw;
            }
            o[h].x = nx; o[h].y = ny;
        }
    }
    const int wr = brev6(lane);

    const float r2 = 0.70710678118654752f;
    const float W8x[8] = {1.f,  r2, 0.f, -r2, -1.f, -r2,  0.f,  r2};
    const float W8y[8] = {0.f,  r2, 1.f,  r2,  0.f, -r2, -1.f, -r2};
    unsigned short* stg = (unsigned short*)&QS[li][0][0];
#pragma unroll
    for (int kh = 0; kh < 8; kh++) {
        float sr = 0.f, si = 0.f;
#pragma unroll
        for (int n = 0; n < 8; n++) {
            const int idx = (n * kh) & 7;
            float wx = W8x[idx], wy = W8y[idx];
            sr += o[n].x * wx - o[n].y * wy;
            si += o[n].x * wy + o[n].y * wx;
        }
        stg[kh * 64 + wr] = f2bf(sqrtf(sr * sr + si * si) * (1.0f / 512.0f));
    }
    __syncthreads();
    uint4 ov = *(uint4*)(stg + lane * 8);
    *(uint4*)((unsigned short*)out_f + base + lane * 8) = ov;
}

// ---------------------------------------------------------------------------
extern "C" void kernel_launch(void* const* d_in, const int* in_sizes, int n_in,
                              void* d_out, int out_size, void* d_ws, size_t ws_size,
                              hipStream_t stream)
{
    const float* x     = (const float*)d_in[0];
    const float* W_in  = (const float*)d_in[1];
    const float* b_in  = (const float*)d_in[2];
    const float* W_q   = (const float*)d_in[3];
    const float* b_q   = (const float*)d_in[4];
    const float* W_k   = (const float*)d_in[5];
    const float* b_k   = (const float*)d_in[6];
    const float* W_v   = (const float*)d_in[7];
    const float* b_v   = (const float*)d_in[8];
    const float* temp  = (const float*)d_in[9];
    const float* W1a   = (const float*)d_in[10];
    const float* b1a   = (const float*)d_in[11];
    const float* gam   = (const float*)d_in[12];
    const float* bet   = (const float*)d_in[13];
    const float* mea   = (const float*)d_in[14];
    const float* var   = (const float*)d_in[15];
    const float* W1b   = (const float*)d_in[16];
    const float* b1b   = (const float*)d_in[17];
    const float* W_out = (const float*)d_in[18];
    const float* b_out = (const float*)d_in[19];

    char* wsb = (char*)d_ws;
    const long MB = 1024 * 1024;
    bf16*    conv2b  = (bf16*)wsb;
    bf16*    tepReal = (bf16*)(wsb + 16 * MB);
    ushort2* Qb    = (ushort2*)(wsb + 32 * MB);
    ushort2* Kb    = (ushort2*)(wsb + 64 * MB);
    ushort2* Vb    = (ushort2*)(wsb + 96 * MB);
    ushort2* Tb    = (ushort2*)(wsb + 128 * MB);
    bf16*    Wt    = (bf16*)(wsb + 160 * MB);
    bf16* WT_in  = Wt;
    bf16* WT_q   = Wt + 262144;
    bf16* WT_1a  = Wt + 4 * 262144;
    bf16* WT_1b  = Wt + 5 * 262144;
    bf16* WT_out = Wt + 6 * 262144;
    bf16* outF = (bf16*)Qb;
    bf16* g1b  = (bf16*)Kb;
    bf16* outL = (bf16*)Kb;
    bf16* g2b  = (bf16*)Vb;

    const dim3 ggrid(4, 128), gblk(256);
    const int BIG = 1 << 30;
    const int RB = 4096;

    transpose_cvt_all<<<dim3(16, 32, 7), dim3(32, 8), 0, stream>>>(
        W_in, W_q, W_k, W_v, W1a, W1b, W_out, Wt);

    // 1. conv2 = x @ W_in + b_in -> bf16  (f32 A, manual staging)
    mfma_gemm<<<ggrid, gblk, 0, stream>>>(
        x, x, 1, 512, BIG, WT_in, 512, b_in, nullptr, nullptr,
        conv2b, nullptr, nullptr, BIG, 1, 512, 512,
        nullptr, nullptr, nullptr, nullptr);

    // 2. fused q/k/v projections (async staging)
    mfma_gemm<<<dim3(12, 128), gblk, 0, stream>>>(
        conv2b, conv2b, 0, 512, BIG, WT_q, 512, b_q, b_k, b_v,
        Qb, Kb, Vb, 512, 2, 512, 512,
        nullptr, nullptr, nullptr, nullptr);

    // 3. all row FFTs (Q/K/V c2c + tep r2c) in one dispatch
    fft8_rows_all<<<4 * RB, 256, 0, stream>>>(Qb, conv2b, Tb);

    // 4. col FFTs: Q,K,V,T fused, 16 cols/block (+ tepReal side output)
    fft8_cols16_c2c4<<<4096, 256, 0, stream>>>(Qb, tepReal, -1.f);

    // 5. attention -> out_f bf16 over Qb
    attn_kernel<<<RB, 256, 0, stream>>>(Qb, Kb, Vb, temp, outF);

    // 6. g1 = BN_ReLU(tepReal @ W1a + b1a) -> bf16
    mfma_gemm<<<ggrid, gblk, 0, stream>>>(
        tepReal, tepReal, 0, 512, BIG, WT_1a, 512, b1a, nullptr, nullptr,
        g1b, nullptr, nullptr, BIG, 3, 512, 512,
        mea, var, gam, bet);

    // 7. g2 = g1 @ W1b + b1b -> bf16
    mfma_gemm<<<ggrid, gblk, 0, stream>>>(
        g1b, g1b, 0, 512, BIG, WT_1b, 512, b1b, nullptr, nullptr,
        g2b, nullptr, nullptr, BIG, 1, 512, 512,
        nullptr, nullptr, nullptr, nullptr);

    // 8. gated ifft2 + abs -> out_l bf16 (over Kb)
    fft8_rows_gated<<<RB, 256, 0, stream>>>(g2b, Tb);
    fft8_cols16_abs<<<1024, 256, 0, stream>>>(Tb, outL);

    // 9. d_out = [out_f | out_l] @ W_out + b_out + conv2 (K=1024, fused residual)
    mfma_gemm<<<ggrid, gblk, 0, stream>>>(
        outF, outL, 0, 512, 512, WT_out, 1024, b_out, nullptr, nullptr,
        d_out, nullptr, nullptr, BIG, 4, 512, 1024,
        (const float*)conv2b, nullptr, nullptr, nullptr);
}